// Round 18
// baseline (1182.763 us; speedup 1.0000x reference)
//
#include <hip/hip_runtime.h>
#include <cstdint>
#include <cstddef>

// Informer ProbSparse decoder layer.
// GEMMs: split-once bf16 limbs + FUSED multi-limb bf16 GEMM (global_load_lds,
// per-K-step staging of all limbs; 6 pairings share staged tiles). XOR chunk
// swizzle (src-side, rule #21) kills the 8-way ds_read bank conflict; XCD
// swizzle for L2 locality. Q/K: 6 pairings (~f32); V/O/FFN: 1 (rne bf16).
// Attention: 3-kernel k-split. qks_m: XCD-affinity remap + LDS idx staging +
// launch_bounds(256,4) to unserialize gathers/reduces (round-18).
#define B_     4
#define L_     1024
#define DM_    1024
#define H_     16
#define DH_    64
#define U_     35
#define FF_    4096
#define MROWS_ 4096
#define IDXN_  35840
#define KS_    4

typedef __attribute__((ext_vector_type(8))) short bf16x8;
typedef __attribute__((ext_vector_type(4))) float f32x4;

// ---------------- Threefry-2x32-20 (exact JAX semantics) ----------------
__host__ __device__ inline void tf2x32(uint32_t k0, uint32_t k1,
                                       uint32_t x0, uint32_t x1,
                                       uint32_t& y0, uint32_t& y1) {
  const uint32_t ks2 = k0 ^ k1 ^ 0x1BD11BDAu;
  uint32_t v0 = x0 + k0, v1 = x1 + k1;
#define ROTL_(x,d) (((x)<<(d))|((x)>>(32-(d))))
#define RND_(r) { v0 += v1; v1 = ROTL_(v1,(r)); v1 ^= v0; }
  RND_(13) RND_(15) RND_(26) RND_(6)   v0 += k1;  v1 += ks2 + 1u;
  RND_(17) RND_(29) RND_(16) RND_(24)  v0 += ks2; v1 += k0  + 2u;
  RND_(13) RND_(15) RND_(26) RND_(6)   v0 += k0;  v1 += k1  + 3u;
  RND_(17) RND_(29) RND_(16) RND_(24)  v0 += k1;  v1 += ks2 + 4u;
  RND_(13) RND_(15) RND_(26) RND_(6)   v0 += ks2; v1 += k0  + 5u;
#undef RND_
#undef ROTL_
  y0 = v0; y1 = v1;
}

__global__ void idx_kernel(uint32_t k0, uint32_t k1, int* __restrict__ idx) {
  const int i = blockIdx.x * 256 + threadIdx.x;
  if (i >= IDXN_) return;
  uint32_t y0, y1;
  tf2x32(k0, k1, 0u, (uint32_t)i, y0, y1);
  idx[i] = (int)((y0 ^ y1) & 1023u);
}

// ---------------- bf16 helpers --------------------------------------------
__device__ __forceinline__ uint32_t f32bits(float x) {
  union { float f; uint32_t u; } c; c.f = x; return c.u;
}
__device__ __forceinline__ float bitsf32(uint32_t u) {
  union { uint32_t u; float f; } c; c.u = u; return c.f;
}
__device__ __forceinline__ uint32_t bf16rne(float x) {
  const uint32_t u = f32bits(x);
  return (u + 0x7FFFu + ((u >> 16) & 1u)) >> 16;
}
__device__ __forceinline__ float bf16tof(uint32_t h) { return bitsf32(h << 16); }

__device__ __forceinline__ void split3(float x, uint32_t& h, uint32_t& m, uint32_t& l) {
  h = bf16rne(x); const float r  = x - bf16tof(h);
  m = bf16rne(r); const float r2 = r - bf16tof(m);
  l = bf16rne(r2);
}

// ---------------- async global -> LDS (16B per lane) ----------------------
__device__ __forceinline__ void gload16(const void* g, void* l) {
  __builtin_amdgcn_global_load_lds(
      (const __attribute__((address_space(1))) void*)g,
      (__attribute__((address_space(3))) void*)l, 16, 0, 0);
}

// ---------------- transpose-split: W (KxN f32) -> W^T limbs (NxK bf16) ----
template<int LIMBS>
__global__ __launch_bounds__(256) void tsplit_kernel(
    const float* __restrict__ W, short* __restrict__ Th,
    short* __restrict__ Tm, short* __restrict__ Tl, int K, int N)
{
  __shared__ float tile[64][65];
  const int n0 = blockIdx.x * 64, k0 = blockIdx.y * 64;
  const int t = threadIdx.x;
  const int r = t >> 2, c0 = (t & 3) * 16;
  const float* src = W + (size_t)(k0 + r) * N + n0 + c0;
  const float4 v0 = *(const float4*)src;
  const float4 v1 = *(const float4*)(src + 4);
  const float4 v2 = *(const float4*)(src + 8);
  const float4 v3 = *(const float4*)(src + 12);
  float* tr = &tile[r][c0];
  tr[0]=v0.x; tr[1]=v0.y; tr[2]=v0.z; tr[3]=v0.w;
  tr[4]=v1.x; tr[5]=v1.y; tr[6]=v1.z; tr[7]=v1.w;
  tr[8]=v2.x; tr[9]=v2.y; tr[10]=v2.z; tr[11]=v2.w;
  tr[12]=v3.x; tr[13]=v3.y; tr[14]=v3.z; tr[15]=v3.w;
  __syncthreads();
  uint32_t ph[8], pm[8], pl[8];
#pragma unroll
  for (int j = 0; j < 16; j += 2) {
    uint32_t h0,m0,l0,h1,m1,l1;
    split3(tile[c0 + j][r], h0, m0, l0);
    split3(tile[c0 + j + 1][r], h1, m1, l1);
    ph[j>>1] = h0 | (h1 << 16);
    pm[j>>1] = m0 | (m1 << 16);
    pl[j>>1] = l0 | (l1 << 16);
  }
  const size_t ob = (size_t)(n0 + r) * K + k0 + c0;
  *(uint4*)(Th + ob)     = make_uint4(ph[0], ph[1], ph[2], ph[3]);
  *(uint4*)(Th + ob + 8) = make_uint4(ph[4], ph[5], ph[6], ph[7]);
  if (LIMBS == 3) {
    *(uint4*)(Tm + ob)     = make_uint4(pm[0], pm[1], pm[2], pm[3]);
    *(uint4*)(Tm + ob + 8) = make_uint4(pm[4], pm[5], pm[6], pm[7]);
    *(uint4*)(Tl + ob)     = make_uint4(pl[0], pl[1], pl[2], pl[3]);
    *(uint4*)(Tl + ob + 8) = make_uint4(pl[4], pl[5], pl[6], pl[7]);
  }
}

// ---------------- row split: X (f32) -> limbs (bf16), elementwise ---------
template<int LIMBS>
__global__ void rsplit_kernel(const float* __restrict__ X, short* __restrict__ Th,
                              short* __restrict__ Tm, short* __restrict__ Tl, int n8)
{
  const int i = blockIdx.x * 256 + threadIdx.x;
  if (i >= n8) return;
  const float4 a = ((const float4*)X)[2*i], b = ((const float4*)X)[2*i+1];
  const float v[8] = {a.x,a.y,a.z,a.w,b.x,b.y,b.z,b.w};
  uint32_t ph[4], pm[4], pl[4];
#pragma unroll
  for (int j = 0; j < 4; ++j) {
    uint32_t h0,m0,l0,h1,m1,l1;
    split3(v[2*j], h0, m0, l0);
    split3(v[2*j+1], h1, m1, l1);
    ph[j] = h0 | (h1 << 16); pm[j] = m0 | (m1 << 16); pl[j] = l0 | (l1 << 16);
  }
  ((uint4*)Th)[i] = make_uint4(ph[0], ph[1], ph[2], ph[3]);
  if (LIMBS == 3) {
    ((uint4*)Tm)[i] = make_uint4(pm[0], pm[1], pm[2], pm[3]);
    ((uint4*)Tl)[i] = make_uint4(pl[0], pl[1], pl[2], pl[3]);
  }
}

// ---------------- fused multi-limb bf16 GEMM (round-16 verified) ----------
struct FJob {
  const short* A[3];
  const short* B[3];
  const float* bias;
  float* C;       // nullable
  short* Ch;      // nullable: rne-bf16 of output
  int relu;
};
struct FJobs { FJob j[3]; };

template<int NL>
__global__ __launch_bounds__(256, 2) void gemm_fused(FJobs jobs, int K, int N)
{
  __shared__ short As[NL][4096] __attribute__((aligned(16)));
  __shared__ short Bs[NL][4096] __attribute__((aligned(16)));
  const int z = blockIdx.z;
  const int nwg  = gridDim.x * gridDim.y;
  const int flat = blockIdx.y * gridDim.x + blockIdx.x;
  const int swz  = (flat & 7) * (nwg >> 3) + (flat >> 3);
  const int bn = (swz % gridDim.x) * 128;
  const int bm = (swz / gridDim.x) * 128;

  const int t = threadIdx.x, lane = t & 63;
  const int wid = t >> 6, wr = wid >> 1, wc = wid & 1;
  const int l15 = lane & 15, kg = lane >> 4;
  const int srow = t >> 2;
  const int sc   = ((t & 3) ^ ((srow + (srow >> 2)) & 3)) * 8;

  int aoff[4], boff[4];
#pragma unroll
  for (int m = 0; m < 4; ++m) {
    const int ra = wr * 64 + m * 16 + l15;
    aoff[m] = ra * 32 + ((kg ^ ((ra + (ra >> 2)) & 3)) << 3);
    const int rb = wc * 64 + m * 16 + l15;
    boff[m] = rb * 32 + ((kg ^ ((rb + (rb >> 2)) & 3)) << 3);
  }

  f32x4 acc[4][4];
#pragma unroll
  for (int m = 0; m < 4; ++m)
#pragma unroll
    for (int n = 0; n < 4; ++n) acc[m][n] = (f32x4){0.f,0.f,0.f,0.f};

  const size_t aofs0 = (size_t)(bm + srow) * K + sc;
  const size_t bofs0 = (size_t)(bn + srow) * K + sc;
  const size_t half  = (size_t)64 * K;

  for (int kk = 0; kk < K; kk += 32) {
    __syncthreads();
#pragma unroll
    for (int l = 0; l < NL; ++l) {
      gload16(jobs.j[z].A[l] + aofs0 + kk,        &As[l][t * 8]);
      gload16(jobs.j[z].A[l] + aofs0 + half + kk, &As[l][2048 + t * 8]);
      gload16(jobs.j[z].B[l] + bofs0 + kk,        &Bs[l][t * 8]);
      gload16(jobs.j[z].B[l] + bofs0 + half + kk, &Bs[l][2048 + t * 8]);
    }
    __syncthreads();
    if (NL == 1) {
      bf16x8 a[4], b[4];
#pragma unroll
      for (int m = 0; m < 4; ++m) a[m] = *(const bf16x8*)&As[0][aoff[m]];
#pragma unroll
      for (int n = 0; n < 4; ++n) b[n] = *(const bf16x8*)&Bs[0][boff[n]];
#pragma unroll
      for (int m = 0; m < 4; ++m)
#pragma unroll
        for (int n = 0; n < 4; ++n)
          acc[m][n] = __builtin_amdgcn_mfma_f32_16x16x32_bf16(a[m], b[n], acc[m][n], 0, 0, 0);
    } else {
      bf16x8 a0[4], a1[4], a2[4], b[4];
#pragma unroll
      for (int m = 0; m < 4; ++m) {
        a0[m] = *(const bf16x8*)&As[0][aoff[m]];
        a1[m] = *(const bf16x8*)&As[1][aoff[m]];
        a2[m] = *(const bf16x8*)&As[2][aoff[m]];
      }
#pragma unroll
      for (int n = 0; n < 4; ++n) b[n] = *(const bf16x8*)&Bs[0][boff[n]];
#pragma unroll
      for (int m = 0; m < 4; ++m)
#pragma unroll
        for (int n = 0; n < 4; ++n) {
          acc[m][n] = __builtin_amdgcn_mfma_f32_16x16x32_bf16(a0[m], b[n], acc[m][n], 0, 0, 0);
          acc[m][n] = __builtin_amdgcn_mfma_f32_16x16x32_bf16(a1[m], b[n], acc[m][n], 0, 0, 0);
          acc[m][n] = __builtin_amdgcn_mfma_f32_16x16x32_bf16(a2[m], b[n], acc[m][n], 0, 0, 0);
        }
#pragma unroll
      for (int n = 0; n < 4; ++n) b[n] = *(const bf16x8*)&Bs[1][boff[n]];
#pragma unroll
      for (int m = 0; m < 4; ++m)
#pragma unroll
        for (int n = 0; n < 4; ++n) {
          acc[m][n] = __builtin_amdgcn_mfma_f32_16x16x32_bf16(a0[m], b[n], acc[m][n], 0, 0, 0);
          acc[m][n] = __builtin_amdgcn_mfma_f32_16x16x32_bf16(a1[m], b[n], acc[m][n], 0, 0, 0);
        }
#pragma unroll
      for (int n = 0; n < 4; ++n) b[n] = *(const bf16x8*)&Bs[2][boff[n]];
#pragma unroll
      for (int m = 0; m < 4; ++m)
#pragma unroll
        for (int n = 0; n < 4; ++n)
          acc[m][n] = __builtin_amdgcn_mfma_f32_16x16x32_bf16(a0[m], b[n], acc[m][n], 0, 0, 0);
    }
  }

  const float* bias = jobs.j[z].bias;
  float* C  = jobs.j[z].C;
  short* Ch = jobs.j[z].Ch;
  const int relu = jobs.j[z].relu;
  float bv[4];
#pragma unroll
  for (int n = 0; n < 4; ++n) bv[n] = bias[bn + wc*64 + n*16 + l15];
#pragma unroll
  for (int m = 0; m < 4; ++m) {
    const int row0 = bm + wr*64 + m*16 + kg*4;
#pragma unroll
    for (int n = 0; n < 4; ++n) {
      const int col = bn + wc*64 + n*16 + l15;
#pragma unroll
      for (int q = 0; q < 4; ++q) {
        float o = acc[m][n][q] + bv[n];
        if (relu) o = fmaxf(o, 0.f);
        const size_t off = (size_t)(row0 + q) * N + col;
        if (C)  C[off]  = o;
        if (Ch) Ch[off] = (short)bf16rne(o);
      }
    }
  }
}

// ---------------- sampled QK^T -> M scores --------------------------------
// Round-17 post-mortem: FETCH dropped 73->17MB (XCD remap works) but dur
// unchanged 155us -> per-wave SERIALIZATION, not memory: VGPR=40 batches the
// 35 gathers (repeated ~300cyc L2 latency) and blocks ILP across the 36
// shuffle chains; idx->readfirstlane->gather added vmcnt waits per sample.
// Fix: (1) stage block's 4x35 indices in LDS (one coalesced burst; per-s
// reads become LDS broadcasts, no readfirstlane); (2) launch_bounds(256,4)
// -> 128 VGPR cap so all 35 kv stay in flight and chains interleave.
__global__ __launch_bounds__(256, 4) void qks_m_kernel(
    const float* __restrict__ Q, const float* __restrict__ K,
    const int* __restrict__ idx, float* __restrict__ Mout)
{
  __shared__ int sidx[4 * U_];
  const int p = blockIdx.x;                       // 0..16383
  const int g = (p & 7) + ((p >> 11) << 3);       // bh group -> XCD g%8
  const int j = (p & 2047) >> 3;                  // block within group
  const int l0 = j * 4;
  const int tid = threadIdx.x;
  if (tid < 4 * U_) sidx[tid] = idx[l0 * U_ + tid];
  __syncthreads();

  const int w = tid >> 6, lane = tid & 63;
  const int l = l0 + w;
  const int h  = g & (H_ - 1);
  const int b  = g >> 4;
  const size_t base = (size_t)(b * L_) * DM_ + h * DH_ + lane;
  const float q = Q[base + (size_t)l * DM_];
  const int* ip = &sidx[w * U_];

  float kv[U_];
#pragma unroll
  for (int s = 0; s < U_; ++s)
    kv[s] = K[base + (size_t)ip[s] * DM_];

  float ksum = 0.f;
#pragma unroll
  for (int s = 0; s < U_; ++s) ksum += kv[s];

  float sm = q * ksum;
#pragma unroll
  for (int off = 32; off > 0; off >>= 1) sm += __shfl_xor(sm, off, 64);

  float mx = -__builtin_inff();
#pragma unroll
  for (int s = 0; s < U_; ++s) {
    float p2 = q * kv[s];
#pragma unroll
    for (int off = 32; off > 0; off >>= 1) p2 += __shfl_xor(p2, off, 64);
    mx = fmaxf(mx, p2);
  }
  if (lane == 0) Mout[g * L_ + l] = mx - sm * (1.0f / 1024.0f);
}

// ---------------- top-35 indices per (b,h) --------------------------------
__global__ __launch_bounds__(256) void topk_kernel(
    const float* __restrict__ M, int* __restrict__ Mtop)
{
  const int bh  = blockIdx.x;
  const int tid = threadIdx.x;
  __shared__ float vals[L_];
  __shared__ float rv[256];
  __shared__ int   ri[256];
  for (int i = tid; i < L_; i += 256) vals[i] = M[(size_t)bh * L_ + i];
  __syncthreads();
  for (int t = 0; t < U_; ++t) {
    float best = -__builtin_inff();
    int   bi   = L_;
    for (int i = tid; i < L_; i += 256) {
      const float v = vals[i];
      if (v > best) { best = v; bi = i; }
    }
    rv[tid] = best; ri[tid] = bi;
    __syncthreads();
    for (int s = 128; s > 0; s >>= 1) {
      if (tid < s) {
        if (rv[tid+s] > rv[tid] || (rv[tid+s] == rv[tid] && ri[tid+s] < ri[tid])) {
          rv[tid] = rv[tid+s]; ri[tid] = ri[tid+s];
        }
      }
      __syncthreads();
    }
    if (tid == 0) { Mtop[bh * U_ + t] = ri[0]; vals[ri[0]] = -__builtin_inff(); }
    __syncthreads();
  }
}

// ---------------- attention: 3-kernel k-split (round-13 verified) ---------
template<int UBASE, int UCNT>
__device__ __forceinline__ void score_group(
    const float* __restrict__ kp, const float* qs, const int* rowsL,
    uint32_t* __restrict__ prow, const int k, const int masked)
{
  float s[UCNT];
#pragma unroll
  for (int ug = 0; ug < UCNT; ++ug) s[ug] = 0.f;
#pragma unroll
  for (int dc = 0; dc < 64; dc += 16) {
    const float4 k0 = *(const float4*)(kp + dc);
    const float4 k1 = *(const float4*)(kp + dc + 4);
    const float4 k2 = *(const float4*)(kp + dc + 8);
    const float4 k3 = *(const float4*)(kp + dc + 12);
#pragma unroll
    for (int ug = 0; ug < UCNT; ++ug) {
      const float4* qp = (const float4*)&qs[(UBASE + ug) * 64 + dc];
      const float4 q0 = qp[0], q1 = qp[1], q2 = qp[2], q3 = qp[3];
      float acc = s[ug];
      acc = fmaf(q0.x, k0.x, acc); acc = fmaf(q0.y, k0.y, acc);
      acc = fmaf(q0.z, k0.z, acc); acc = fmaf(q0.w, k0.w, acc);
      acc = fmaf(q1.x, k1.x, acc); acc = fmaf(q1.y, k1.y, acc);
      acc = fmaf(q1.z, k1.z, acc); acc = fmaf(q1.w, k1.w, acc);
      acc = fmaf(q2.x, k2.x, acc); acc = fmaf(q2.y, k2.y, acc);
      acc = fmaf(q2.z, k2.z, acc); acc = fmaf(q2.w, k2.w, acc);
      acc = fmaf(q3.x, k3.x, acc); acc = fmaf(q3.y, k3.y, acc);
      acc = fmaf(q3.z, k3.z, acc); acc = fmaf(q3.w, k3.w, acc);
      s[ug] = acc;
    }
  }
#pragma unroll
  for (int ug = 0; ug < UCNT; ++ug) {
    float v = s[ug] * 0.125f;
    if (masked && k > rowsL[UBASE + ug]) v = -__builtin_inff();
    s[ug] = expf(v);
  }
#pragma unroll
  for (int j = 0; j < UCNT / 2; ++j)
    prow[UBASE / 2 + j] = bf16rne(s[2 * j]) | (bf16rne(s[2 * j + 1]) << 16);
  if (UCNT & 1)
    prow[UBASE / 2 + UCNT / 2] = bf16rne(s[UCNT - 1]);
}

__global__ __launch_bounds__(256) void attn_score(
    const float* __restrict__ Q, const float* __restrict__ K,
    const int* __restrict__ Mtop, uint32_t* __restrict__ Pg, int masked)
{
  __shared__ float qs[U_ * DH_];
  __shared__ int   rowsL[U_ + 1];
  const int bh = blockIdx.x >> 2, ks = blockIdx.x & 3;
  const int h = bh & (H_ - 1), b = bh >> 4;
  const int tid = threadIdx.x;
  const size_t kvbase = (size_t)(b * L_) * DM_ + h * DH_;

  if (tid < U_) rowsL[tid] = Mtop[bh * U_ + tid];
  __syncthreads();
  for (int i = tid; i < U_ * DH_; i += 256)
    qs[i] = Q[kvbase + (size_t)rowsL[i >> 6] * DM_ + (i & 63)];
  __syncthreads();

  const int k = ks * 256 + tid;
  const float* kp = K + kvbase + (size_t)k * DM_;
  uint32_t* prow = Pg + (size_t)bh * (L_ * 18) + (size_t)k * 18;
  score_group<0, 12>(kp, qs, rowsL, prow, k, masked);
  score_group<12, 12>(kp, qs, rowsL, prow, k, masked);
  score_group<24, 11>(kp, qs, rowsL, prow, k, masked);
}

__global__ __launch_bounds__(256) void attn_pv(
    const float* __restrict__ V, const uint32_t* __restrict__ Pg,
    float* __restrict__ Opart, float* __restrict__ Dpart)
{
  __shared__ uint32_t Pl[256 * 18];
  const int bh = blockIdx.x >> 2, ks = blockIdx.x & 3;
  const int h = bh & (H_ - 1), b = bh >> 4;
  const int tid = threadIdx.x, lane = tid & 63, wid = tid >> 6;
  const size_t kvbase = (size_t)(b * L_) * DM_ + h * DH_;

  const uint32_t* ps = Pg + (size_t)bh * (L_ * 18) + (size_t)(ks * 256) * 18;
  for (int i = tid; i < 256 * 18; i += 256) Pl[i] = ps[i];
  __syncthreads();

  float acc[9], dd[9];
#pragma unroll
  for (int j = 0; j < 9; ++j) { acc[j] = 0.f; dd[j] = 0.f; }

  const float* vp = V + kvbase + (size_t)(ks * 256) * DM_ + lane;
  const int widh = wid >> 1;
  const int hi   = wid & 1;
#pragma unroll 4
  for (int kk = 0; kk < 256; ++kk) {
    const float v0 = vp[(size_t)kk * DM_];
    const uint32_t* pr = &Pl[kk * 18];
#pragma unroll
    for (int j = 0; j < 9; ++j) {
      if (wid + 4 * j < U_) {
        const uint32_t w = pr[widh + 2 * j];
        const float p = hi ? bitsf32(w & 0xFFFF0000u) : bitsf32(w << 16);
        acc[j] = fmaf(p, v0, acc[j]);
        dd[j] += p;
      }
    }
  }
  const int pb = (ks * 64 + bh) * U_;
#pragma unroll
  for (int j = 0; j < 9; ++j) {
    const int u = wid + 4 * j;
    if (u < U_) {
      Opart[(size_t)(pb + u) * 64 + lane] = acc[j];
      if (lane == 0) Dpart[pb + u] = dd[j];
    }
  }
}

__global__ void attn_reduce(const float* __restrict__ Opart,
                            const float* __restrict__ Dpart,
                            float* __restrict__ ctx_rows)
{
  const int bhu = blockIdx.x;
  const int bh = bhu / U_, u = bhu % U_;
  const int lane = threadIdx.x;
  float o = 0.f, dd = 0.f;
#pragma unroll
  for (int ks = 0; ks < KS_; ++ks) {
    o  += Opart[(size_t)((ks * 64 + bh) * U_ + u) * 64 + lane];
    dd += Dpart[(ks * 64 + bh) * U_ + u];
  }
  ctx_rows[(size_t)bhu * 64 + lane] = o / dd;
}

// ---------------- cumsum / vmean / fill / scatter -------------------------
__global__ __launch_bounds__(256) void cumsum_kernel(
    const float* __restrict__ V, float* __restrict__ C)
{
  const int bh = blockIdx.x;
  const int h = bh & (H_ - 1), b = bh >> 4;
  const int d = threadIdx.x & 63, qq = threadIdx.x >> 6;
  __shared__ float chs[4][DH_];
  const size_t base = (size_t)b * L_ * DM_ + h * DH_ + d;
  float acc = 0.f;
  const int l0 = qq * 256;
  for (int l = l0; l < l0 + 256; ++l) acc += V[base + (size_t)l * DM_];
  chs[qq][d] = acc;
  __syncthreads();
  float off = 0.f;
  for (int j = 0; j < qq; ++j) off += chs[j][d];
  acc = off;
  for (int l = l0; l < l0 + 256; ++l) {
    acc += V[base + (size_t)l * DM_];
    C[base + (size_t)l * DM_] = acc;
  }
}

__global__ __launch_bounds__(256) void vmean_kernel(
    const float* __restrict__ V, float* __restrict__ vm)
{
  const int bh = blockIdx.x;
  const int h = bh & (H_ - 1), b = bh >> 4;
  const int d = threadIdx.x & 63, qq = threadIdx.x >> 6;
  __shared__ float chs[4][DH_];
  const size_t base = (size_t)b * L_ * DM_ + h * DH_ + d;
  float acc = 0.f;
  for (int l = qq * 256; l < qq * 256 + 256; ++l) acc += V[base + (size_t)l * DM_];
  chs[qq][d] = acc;
  __syncthreads();
  if (qq == 0)
    vm[bh * DH_ + d] = (chs[0][d] + chs[1][d] + chs[2][d] + chs[3][d]) * (1.0f / 1024.0f);
}

__global__ void fill_kernel(const float* __restrict__ vm, float* __restrict__ C)
{
  const size_t i = (size_t)blockIdx.x * 256 + threadIdx.x;
  const int d = (int)(i & 63);
  const int h = (int)((i >> 6) & (H_ - 1));
  const int b = (int)(i >> 20);
  C[i] = vm[(b * H_ + h) * DH_ + d];
}

__global__ void scatter_kernel(const float* __restrict__ ctx_rows,
                               const int* __restrict__ Mtop, float* __restrict__ C)
{
  const int bhu = blockIdx.x;
  const int u  = bhu % U_;
  const int bh = bhu / U_;
  const int h = bh & (H_ - 1), b = bh >> 4;
  const int row = Mtop[bh * U_ + u];
  C[(size_t)(b * L_ + row) * DM_ + h * DH_ + threadIdx.x] =
      ctx_rows[(size_t)bhu * DH_ + threadIdx.x];
}

// ---------------- LayerNorm(xa + xb), optional limb outputs ---------------
__global__ __launch_bounds__(256) void ln_kernel(
    const float* __restrict__ xa, const float* __restrict__ xb,
    const float* __restrict__ g, const float* __restrict__ bt,
    float* __restrict__ out, short* __restrict__ oh,
    short* __restrict__ om, short* __restrict__ ol)
{
  const int row = blockIdx.x;
  const int tid = threadIdx.x;
  __shared__ float v[DM_];
  __shared__ float red[256];
  float s = 0.f;
  for (int i = tid; i < DM_; i += 256) {
    const float t = xa[(size_t)row * DM_ + i] + xb[(size_t)row * DM_ + i];
    v[i] = t; s += t;
  }
  red[tid] = s; __syncthreads();
  for (int st = 128; st > 0; st >>= 1) { if (tid < st) red[tid] += red[tid+st]; __syncthreads(); }
  const float mean = red[0] * (1.0f / DM_);
  __syncthreads();
  float s2 = 0.f;
  for (int i = tid; i < DM_; i += 256) { const float dd = v[i] - mean; s2 += dd * dd; }
  red[tid] = s2; __syncthreads();
  for (int st = 128; st > 0; st >>= 1) { if (tid < st) red[tid] += red[tid+st]; __syncthreads(); }
  const float rstd = rsqrtf(red[0] * (1.0f / DM_) + 1e-5f);
  __syncthreads();
  for (int i = tid; i < DM_; i += 256) {
    const size_t idx = (size_t)row * DM_ + i;
    const float o = (v[i] - mean) * rstd * g[i] + bt[i];
    out[idx] = o;
    if (oh) {
      const uint32_t h = bf16rne(o);
      oh[idx] = (short)h;
      if (om) {
        const float r = o - bf16tof(h);
        const uint32_t m = bf16rne(r);
        om[idx] = (short)m;
        ol[idx] = (short)bf16rne(r - bf16tof(m));
      }
    }
  }
}

// ---------------- host orchestration --------------------------------------
extern "C" void kernel_launch(void* const* d_in, const int* in_sizes, int n_in,
                              void* d_out, int out_size, void* d_ws, size_t ws_size,
                              hipStream_t stream)
{
  (void)in_sizes; (void)n_in; (void)out_size; (void)ws_size;
  const float* x    = (const float*)d_in[0];
  const float* enc  = (const float*)d_in[1];
  const float* saWq = (const float*)d_in[2];  const float* sabq = (const float*)d_in[3];
  const float* saWk = (const float*)d_in[4];  const float* sabk = (const float*)d_in[5];
  const float* saWv = (const float*)d_in[6];  const float* sabv = (const float*)d_in[7];
  const float* saWo = (const float*)d_in[8];  const float* sabo = (const float*)d_in[9];
  const float* caWq = (const float*)d_in[10]; const float* cabq = (const float*)d_in[11];
  const float* caWk = (const float*)d_in[12]; const float* cabk = (const float*)d_in[13];
  const float* caWv = (const float*)d_in[14]; const float* cabv = (const float*)d_in[15];
  const float* caWo = (const float*)d_in[16]; const float* cabo = (const float*)d_in[17];
  const float* fW1  = (const float*)d_in[18]; const float* fb1  = (const float*)d_in[19];
  const float* fW2  = (const float*)d_in[20]; const float* fb2  = (const float*)d_in[21];
  const float* l1g  = (const float*)d_in[22]; const float* l1b  = (const float*)d_in[23];
  const float* l2g  = (const float*)d_in[24]; const float* l2b  = (const float*)d_in[25];
  const float* l3g  = (const float*)d_in[26]; const float* l3b  = (const float*)d_in[27];

  float* ws = (float*)d_ws;
  const size_t SL = (size_t)MROWS_ * DM_;       // 4M floats
  float* bufQ = ws;
  float* bufK = ws + SL;
  float* bufV = ws + 2 * SL;
  float* bufC = ws + 3 * SL;
  float* xcur = ws + 4 * SL;
  float* tmp  = ws + 5 * SL;
  float* smallp = ws + 6 * SL;
  int*   idxb = (int*)smallp;
  float* Mbuf = smallp + 36864;
  int*   Mtop = (int*)(smallp + 36864 + 65536);
  float* ctxr = smallp + 36864 + 65536 + 2304;
  float* vm   = ctxr + 143360;

  // attention scratch overlaid on bufC (dead until cumsum/fill):
  uint32_t* Pg    = (uint32_t*)bufC;
  float*    Opart = bufC + 1179648;
  float*    Dpart = Opart + (size_t)KS_ * 64 * U_ * 64;

  const size_t M1 = 1024u * 1024u;
  short* wreg = (short*)(ws + 6 * SL + 262144);
  short* areg = wreg + 8 * M1;
  short* Wqh = wreg;          short* Wqm = wreg + 1*M1; short* Wql = wreg + 2*M1;
  short* Wkh = wreg + 3*M1;   short* Wkm = wreg + 4*M1; short* Wkl = wreg + 5*M1;
  short* Wvh = wreg + 6*M1;   short* Woh = wreg + 7*M1;
  short* f1h = wreg;          short* f2h = wreg + 4*M1;
  short* xh = areg;           short* xm = areg + 4*M1;  short* xl = areg + 8*M1;
  short* eh = areg + 12*M1;   short* em = areg + 16*M1; short* el = areg + 20*M1;
  short* bCh = areg + 12*M1;
  short* hidh = (short*)bufQ;

  // --- JAX partitionable-threefry key ladder (verified round 3) ---
  uint32_t k1a, k1b, k2a, k2b;
  tf2x32(0u, 42u, 0u, 0u, k1a, k1b);
  tf2x32(0u, 42u, 0u, 1u, k2a, k2b);
  uint32_t kb1a, kb1b, kb2a, kb2b;
  tf2x32(k1a, k1b, 0u, 1u, kb1a, kb1b);
  tf2x32(k2a, k2b, 0u, 1u, kb2a, kb2b);

  const dim3 thr(256);
  const int gIdx = (IDXN_ + 255) / 256;
  const int n8 = (int)(SL / 8);
  const dim3 gT(16, 16);

  // ============ self attention (masked) ============
  tsplit_kernel<3><<<gT, thr, 0, stream>>>(saWq, Wqh, Wqm, Wql, DM_, DM_);
  tsplit_kernel<3><<<gT, thr, 0, stream>>>(saWk, Wkh, Wkm, Wkl, DM_, DM_);
  tsplit_kernel<1><<<gT, thr, 0, stream>>>(saWv, Wvh, nullptr, nullptr, DM_, DM_);
  tsplit_kernel<1><<<gT, thr, 0, stream>>>(saWo, Woh, nullptr, nullptr, DM_, DM_);
  rsplit_kernel<3><<<n8 / 256, thr, 0, stream>>>(x, xh, xm, xl, n8);
  {
    FJobs J = {};
    J.j[0] = { {xh, xm, xl}, {Wqh, Wqm, Wql}, sabq, bufQ, nullptr, 0 };
    J.j[1] = { {xh, xm, xl}, {Wkh, Wkm, Wkl}, sabk, bufK, nullptr, 0 };
    gemm_fused<3><<<dim3(8, 32, 2), thr, 0, stream>>>(J, DM_, DM_);
  }
  {
    FJobs J = {};
    J.j[0] = { {xh, nullptr, nullptr}, {Wvh, nullptr, nullptr}, sabv, bufV, nullptr, 0 };
    gemm_fused<1><<<dim3(8, 32, 1), thr, 0, stream>>>(J, DM_, DM_);
  }
  idx_kernel<<<gIdx, thr, 0, stream>>>(kb1a, kb1b, idxb);
  qks_m_kernel<<<(B_ * H_ * L_) / 4, thr, 0, stream>>>(bufQ, bufK, idxb, Mbuf);
  topk_kernel<<<B_ * H_, thr, 0, stream>>>(Mbuf, Mtop);
  attn_score<<<B_ * H_ * KS_, thr, 0, stream>>>(bufQ, bufK, Mtop, Pg, 1);
  attn_pv<<<B_ * H_ * KS_, thr, 0, stream>>>(bufV, Pg, Opart, Dpart);
  attn_reduce<<<B_ * H_ * U_, dim3(64), 0, stream>>>(Opart, Dpart, ctxr);
  cumsum_kernel<<<B_ * H_, thr, 0, stream>>>(bufV, bufC);
  scatter_kernel<<<B_ * H_ * U_, dim3(64), 0, stream>>>(ctxr, Mtop, bufC);
  rsplit_kernel<1><<<n8 / 256, thr, 0, stream>>>(bufC, bCh, nullptr, nullptr, n8);
  {
    FJobs J = {};
    J.j[0] = { {bCh, nullptr, nullptr}, {Woh, nullptr, nullptr}, sabo, tmp, nullptr, 0 };
    gemm_fused<1><<<dim3(8, 32, 1), thr, 0, stream>>>(J, DM_, DM_);
  }
  ln_kernel<<<MROWS_, thr, 0, stream>>>(x, tmp, l1g, l1b, xcur, xh, xm, xl);

  // ============ cross attention (unmasked) ============
  tsplit_kernel<3><<<gT, thr, 0, stream>>>(caWq, Wqh, Wqm, Wql, DM_, DM_);
  tsplit_kernel<3><<<gT, thr, 0, stream>>>(caWk, Wkh, Wkm, Wkl, DM_, DM_);
  tsplit_kernel<1><<<gT, thr, 0, stream>>>(caWv, Wvh, nullptr, nullptr, DM_, DM_);
  tsplit_kernel<1><<<gT, thr, 0, stream>>>(caWo, Woh, nullptr, nullptr, DM_, DM_);
  rsplit_kernel<3><<<n8 / 256, thr, 0, stream>>>(enc, eh, em, el, n8);
  {
    FJobs J = {};
    J.j[0] = { {xh, xm, xl}, {Wqh, Wqm, Wql}, cabq, bufQ, nullptr, 0 };
    J.j[1] = { {eh, em, el}, {Wkh, Wkm, Wkl}, cabk, bufK, nullptr, 0 };
    gemm_fused<3><<<dim3(8, 32, 2), thr, 0, stream>>>(J, DM_, DM_);
  }
  {
    FJobs J = {};
    J.j[0] = { {eh, nullptr, nullptr}, {Wvh, nullptr, nullptr}, cabv, bufV, nullptr, 0 };
    gemm_fused<1><<<dim3(8, 32, 1), thr, 0, stream>>>(J, DM_, DM_);
  }
  idx_kernel<<<gIdx, thr, 0, stream>>>(kb2a, kb2b, idxb);
  qks_m_kernel<<<(B_ * H_ * L_) / 4, thr, 0, stream>>>(bufQ, bufK, idxb, Mbuf);
  topk_kernel<<<B_ * H_, thr, 0, stream>>>(Mbuf, Mtop);
  attn_score<<<B_ * H_ * KS_, thr, 0, stream>>>(bufQ, bufK, Mtop, Pg, 0);
  attn_pv<<<B_ * H_ * KS_, thr, 0, stream>>>(bufV, Pg, Opart, Dpart);
  attn_reduce<<<B_ * H_ * U_, dim3(64), 0, stream>>>(Opart, Dpart, ctxr);
  vmean_kernel<<<B_ * H_, thr, 0, stream>>>(bufV, vm);
  fill_kernel<<<(int)(SL / 256), thr, 0, stream>>>(vm, bufC);
  scatter_kernel<<<B_ * H_ * U_, dim3(64), 0, stream>>>(ctxr, Mtop, bufC);
  rsplit_kernel<1><<<n8 / 256, thr, 0, stream>>>(bufC, bCh, nullptr, nullptr, n8);
  {
    FJobs J = {};
    J.j[0] = { {bCh, nullptr, nullptr}, {Woh, nullptr, nullptr}, cabo, tmp, nullptr, 0 };
    gemm_fused<1><<<dim3(8, 32, 1), thr, 0, stream>>>(J, DM_, DM_);
  }
  ln_kernel<<<MROWS_, thr, 0, stream>>>(xcur, tmp, l2g, l2b, xcur, xh, nullptr, nullptr);

  // ============ FFN ============
  tsplit_kernel<1><<<dim3(64, 16), thr, 0, stream>>>(fW1, f1h, nullptr, nullptr, DM_, FF_);
  tsplit_kernel<1><<<dim3(16, 64), thr, 0, stream>>>(fW2, f2h, nullptr, nullptr, FF_, DM_);
  {
    FJobs J = {};
    J.j[0] = { {xh, nullptr, nullptr}, {f1h, nullptr, nullptr}, fb1, nullptr, hidh, 1 };
    gemm_fused<1><<<dim3(32, 32, 1), thr, 0, stream>>>(J, DM_, FF_);
  }
  {
    FJobs J = {};
    J.j[0] = { {hidh, nullptr, nullptr}, {f2h, nullptr, nullptr}, fb2, tmp, nullptr, 0 };
    gemm_fused<1><<<dim3(8, 32, 1), thr, 0, stream>>>(J, FF_, DM_);
  }
  ln_kernel<<<MROWS_, thr, 0, stream>>>(xcur, tmp, l3g, l3b, (float*)d_out,
                                        nullptr, nullptr, nullptr);
}

// Round 19
// 1113.606 us; speedup vs baseline: 1.0621x; 1.0621x over previous
//
#include <hip/hip_runtime.h>
#include <cstdint>
#include <cstddef>

// Informer ProbSparse decoder layer.
// GEMMs: split-once bf16 limbs + FUSED multi-limb bf16 GEMM (global_load_lds,
// per-K-step staging of all limbs; 6 pairings share staged tiles). XOR chunk
// swizzle (src-side, rule #21) kills the 8-way ds_read bank conflict; XCD
// swizzle for L2 locality. Q/K: 6 pairings (~f32); V/O/FFN: 1 (rne bf16).
// Attention: 3-kernel k-split. qks_m: thread-per-(l,s-quarter), shuffle-free
// (round-19: the 216 shuffles/thread were DS-pipe bound at ~155us).
#define B_     4
#define L_     1024
#define DM_    1024
#define H_     16
#define DH_    64
#define U_     35
#define FF_    4096
#define MROWS_ 4096
#define IDXN_  35840
#define KS_    4

typedef __attribute__((ext_vector_type(8))) short bf16x8;
typedef __attribute__((ext_vector_type(4))) float f32x4;

// ---------------- Threefry-2x32-20 (exact JAX semantics) ----------------
__host__ __device__ inline void tf2x32(uint32_t k0, uint32_t k1,
                                       uint32_t x0, uint32_t x1,
                                       uint32_t& y0, uint32_t& y1) {
  const uint32_t ks2 = k0 ^ k1 ^ 0x1BD11BDAu;
  uint32_t v0 = x0 + k0, v1 = x1 + k1;
#define ROTL_(x,d) (((x)<<(d))|((x)>>(32-(d))))
#define RND_(r) { v0 += v1; v1 = ROTL_(v1,(r)); v1 ^= v0; }
  RND_(13) RND_(15) RND_(26) RND_(6)   v0 += k1;  v1 += ks2 + 1u;
  RND_(17) RND_(29) RND_(16) RND_(24)  v0 += ks2; v1 += k0  + 2u;
  RND_(13) RND_(15) RND_(26) RND_(6)   v0 += k0;  v1 += k1  + 3u;
  RND_(17) RND_(29) RND_(16) RND_(24)  v0 += k1;  v1 += ks2 + 4u;
  RND_(13) RND_(15) RND_(26) RND_(6)   v0 += ks2; v1 += k0  + 5u;
#undef RND_
#undef ROTL_
  y0 = v0; y1 = v1;
}

__global__ void idx_kernel(uint32_t k0, uint32_t k1, int* __restrict__ idx) {
  const int i = blockIdx.x * 256 + threadIdx.x;
  if (i >= IDXN_) return;
  uint32_t y0, y1;
  tf2x32(k0, k1, 0u, (uint32_t)i, y0, y1);
  idx[i] = (int)((y0 ^ y1) & 1023u);
}

// ---------------- bf16 helpers --------------------------------------------
__device__ __forceinline__ uint32_t f32bits(float x) {
  union { float f; uint32_t u; } c; c.f = x; return c.u;
}
__device__ __forceinline__ float bitsf32(uint32_t u) {
  union { uint32_t u; float f; } c; c.u = u; return c.f;
}
__device__ __forceinline__ uint32_t bf16rne(float x) {
  const uint32_t u = f32bits(x);
  return (u + 0x7FFFu + ((u >> 16) & 1u)) >> 16;
}
__device__ __forceinline__ float bf16tof(uint32_t h) { return bitsf32(h << 16); }

__device__ __forceinline__ void split3(float x, uint32_t& h, uint32_t& m, uint32_t& l) {
  h = bf16rne(x); const float r  = x - bf16tof(h);
  m = bf16rne(r); const float r2 = r - bf16tof(m);
  l = bf16rne(r2);
}

// ---------------- async global -> LDS (16B per lane) ----------------------
__device__ __forceinline__ void gload16(const void* g, void* l) {
  __builtin_amdgcn_global_load_lds(
      (const __attribute__((address_space(1))) void*)g,
      (__attribute__((address_space(3))) void*)l, 16, 0, 0);
}

// ---------------- transpose-split: W (KxN f32) -> W^T limbs (NxK bf16) ----
template<int LIMBS>
__global__ __launch_bounds__(256) void tsplit_kernel(
    const float* __restrict__ W, short* __restrict__ Th,
    short* __restrict__ Tm, short* __restrict__ Tl, int K, int N)
{
  __shared__ float tile[64][65];
  const int n0 = blockIdx.x * 64, k0 = blockIdx.y * 64;
  const int t = threadIdx.x;
  const int r = t >> 2, c0 = (t & 3) * 16;
  const float* src = W + (size_t)(k0 + r) * N + n0 + c0;
  const float4 v0 = *(const float4*)src;
  const float4 v1 = *(const float4*)(src + 4);
  const float4 v2 = *(const float4*)(src + 8);
  const float4 v3 = *(const float4*)(src + 12);
  float* tr = &tile[r][c0];
  tr[0]=v0.x; tr[1]=v0.y; tr[2]=v0.z; tr[3]=v0.w;
  tr[4]=v1.x; tr[5]=v1.y; tr[6]=v1.z; tr[7]=v1.w;
  tr[8]=v2.x; tr[9]=v2.y; tr[10]=v2.z; tr[11]=v2.w;
  tr[12]=v3.x; tr[13]=v3.y; tr[14]=v3.z; tr[15]=v3.w;
  __syncthreads();
  uint32_t ph[8], pm[8], pl[8];
#pragma unroll
  for (int j = 0; j < 16; j += 2) {
    uint32_t h0,m0,l0,h1,m1,l1;
    split3(tile[c0 + j][r], h0, m0, l0);
    split3(tile[c0 + j + 1][r], h1, m1, l1);
    ph[j>>1] = h0 | (h1 << 16);
    pm[j>>1] = m0 | (m1 << 16);
    pl[j>>1] = l0 | (l1 << 16);
  }
  const size_t ob = (size_t)(n0 + r) * K + k0 + c0;
  *(uint4*)(Th + ob)     = make_uint4(ph[0], ph[1], ph[2], ph[3]);
  *(uint4*)(Th + ob + 8) = make_uint4(ph[4], ph[5], ph[6], ph[7]);
  if (LIMBS == 3) {
    *(uint4*)(Tm + ob)     = make_uint4(pm[0], pm[1], pm[2], pm[3]);
    *(uint4*)(Tm + ob + 8) = make_uint4(pm[4], pm[5], pm[6], pm[7]);
    *(uint4*)(Tl + ob)     = make_uint4(pl[0], pl[1], pl[2], pl[3]);
    *(uint4*)(Tl + ob + 8) = make_uint4(pl[4], pl[5], pl[6], pl[7]);
  }
}

// ---------------- row split: X (f32) -> limbs (bf16), elementwise ---------
template<int LIMBS>
__global__ void rsplit_kernel(const float* __restrict__ X, short* __restrict__ Th,
                              short* __restrict__ Tm, short* __restrict__ Tl, int n8)
{
  const int i = blockIdx.x * 256 + threadIdx.x;
  if (i >= n8) return;
  const float4 a = ((const float4*)X)[2*i], b = ((const float4*)X)[2*i+1];
  const float v[8] = {a.x,a.y,a.z,a.w,b.x,b.y,b.z,b.w};
  uint32_t ph[4], pm[4], pl[4];
#pragma unroll
  for (int j = 0; j < 4; ++j) {
    uint32_t h0,m0,l0,h1,m1,l1;
    split3(v[2*j], h0, m0, l0);
    split3(v[2*j+1], h1, m1, l1);
    ph[j] = h0 | (h1 << 16); pm[j] = m0 | (m1 << 16); pl[j] = l0 | (l1 << 16);
  }
  ((uint4*)Th)[i] = make_uint4(ph[0], ph[1], ph[2], ph[3]);
  if (LIMBS == 3) {
    ((uint4*)Tm)[i] = make_uint4(pm[0], pm[1], pm[2], pm[3]);
    ((uint4*)Tl)[i] = make_uint4(pl[0], pl[1], pl[2], pl[3]);
  }
}

// ---------------- fused multi-limb bf16 GEMM (round-16 verified) ----------
struct FJob {
  const short* A[3];
  const short* B[3];
  const float* bias;
  float* C;       // nullable
  short* Ch;      // nullable: rne-bf16 of output
  int relu;
};
struct FJobs { FJob j[3]; };

template<int NL>
__global__ __launch_bounds__(256, 2) void gemm_fused(FJobs jobs, int K, int N)
{
  __shared__ short As[NL][4096] __attribute__((aligned(16)));
  __shared__ short Bs[NL][4096] __attribute__((aligned(16)));
  const int z = blockIdx.z;
  const int nwg  = gridDim.x * gridDim.y;
  const int flat = blockIdx.y * gridDim.x + blockIdx.x;
  const int swz  = (flat & 7) * (nwg >> 3) + (flat >> 3);
  const int bn = (swz % gridDim.x) * 128;
  const int bm = (swz / gridDim.x) * 128;

  const int t = threadIdx.x, lane = t & 63;
  const int wid = t >> 6, wr = wid >> 1, wc = wid & 1;
  const int l15 = lane & 15, kg = lane >> 4;
  const int srow = t >> 2;
  const int sc   = ((t & 3) ^ ((srow + (srow >> 2)) & 3)) * 8;

  int aoff[4], boff[4];
#pragma unroll
  for (int m = 0; m < 4; ++m) {
    const int ra = wr * 64 + m * 16 + l15;
    aoff[m] = ra * 32 + ((kg ^ ((ra + (ra >> 2)) & 3)) << 3);
    const int rb = wc * 64 + m * 16 + l15;
    boff[m] = rb * 32 + ((kg ^ ((rb + (rb >> 2)) & 3)) << 3);
  }

  f32x4 acc[4][4];
#pragma unroll
  for (int m = 0; m < 4; ++m)
#pragma unroll
    for (int n = 0; n < 4; ++n) acc[m][n] = (f32x4){0.f,0.f,0.f,0.f};

  const size_t aofs0 = (size_t)(bm + srow) * K + sc;
  const size_t bofs0 = (size_t)(bn + srow) * K + sc;
  const size_t half  = (size_t)64 * K;

  for (int kk = 0; kk < K; kk += 32) {
    __syncthreads();
#pragma unroll
    for (int l = 0; l < NL; ++l) {
      gload16(jobs.j[z].A[l] + aofs0 + kk,        &As[l][t * 8]);
      gload16(jobs.j[z].A[l] + aofs0 + half + kk, &As[l][2048 + t * 8]);
      gload16(jobs.j[z].B[l] + bofs0 + kk,        &Bs[l][t * 8]);
      gload16(jobs.j[z].B[l] + bofs0 + half + kk, &Bs[l][2048 + t * 8]);
    }
    __syncthreads();
    if (NL == 1) {
      bf16x8 a[4], b[4];
#pragma unroll
      for (int m = 0; m < 4; ++m) a[m] = *(const bf16x8*)&As[0][aoff[m]];
#pragma unroll
      for (int n = 0; n < 4; ++n) b[n] = *(const bf16x8*)&Bs[0][boff[n]];
#pragma unroll
      for (int m = 0; m < 4; ++m)
#pragma unroll
        for (int n = 0; n < 4; ++n)
          acc[m][n] = __builtin_amdgcn_mfma_f32_16x16x32_bf16(a[m], b[n], acc[m][n], 0, 0, 0);
    } else {
      bf16x8 a0[4], a1[4], a2[4], b[4];
#pragma unroll
      for (int m = 0; m < 4; ++m) {
        a0[m] = *(const bf16x8*)&As[0][aoff[m]];
        a1[m] = *(const bf16x8*)&As[1][aoff[m]];
        a2[m] = *(const bf16x8*)&As[2][aoff[m]];
      }
#pragma unroll
      for (int n = 0; n < 4; ++n) b[n] = *(const bf16x8*)&Bs[0][boff[n]];
#pragma unroll
      for (int m = 0; m < 4; ++m)
#pragma unroll
        for (int n = 0; n < 4; ++n) {
          acc[m][n] = __builtin_amdgcn_mfma_f32_16x16x32_bf16(a0[m], b[n], acc[m][n], 0, 0, 0);
          acc[m][n] = __builtin_amdgcn_mfma_f32_16x16x32_bf16(a1[m], b[n], acc[m][n], 0, 0, 0);
          acc[m][n] = __builtin_amdgcn_mfma_f32_16x16x32_bf16(a2[m], b[n], acc[m][n], 0, 0, 0);
        }
#pragma unroll
      for (int n = 0; n < 4; ++n) b[n] = *(const bf16x8*)&Bs[1][boff[n]];
#pragma unroll
      for (int m = 0; m < 4; ++m)
#pragma unroll
        for (int n = 0; n < 4; ++n) {
          acc[m][n] = __builtin_amdgcn_mfma_f32_16x16x32_bf16(a0[m], b[n], acc[m][n], 0, 0, 0);
          acc[m][n] = __builtin_amdgcn_mfma_f32_16x16x32_bf16(a1[m], b[n], acc[m][n], 0, 0, 0);
        }
#pragma unroll
      for (int n = 0; n < 4; ++n) b[n] = *(const bf16x8*)&Bs[2][boff[n]];
#pragma unroll
      for (int m = 0; m < 4; ++m)
#pragma unroll
        for (int n = 0; n < 4; ++n)
          acc[m][n] = __builtin_amdgcn_mfma_f32_16x16x32_bf16(a0[m], b[n], acc[m][n], 0, 0, 0);
    }
  }

  const float* bias = jobs.j[z].bias;
  float* C  = jobs.j[z].C;
  short* Ch = jobs.j[z].Ch;
  const int relu = jobs.j[z].relu;
  float bv[4];
#pragma unroll
  for (int n = 0; n < 4; ++n) bv[n] = bias[bn + wc*64 + n*16 + l15];
#pragma unroll
  for (int m = 0; m < 4; ++m) {
    const int row0 = bm + wr*64 + m*16 + kg*4;
#pragma unroll
    for (int n = 0; n < 4; ++n) {
      const int col = bn + wc*64 + n*16 + l15;
#pragma unroll
      for (int q = 0; q < 4; ++q) {
        float o = acc[m][n][q] + bv[n];
        if (relu) o = fmaxf(o, 0.f);
        const size_t off = (size_t)(row0 + q) * N + col;
        if (C)  C[off]  = o;
        if (Ch) Ch[off] = (short)bf16rne(o);
      }
    }
  }
}

// ---------------- sampled QK^T -> M scores --------------------------------
// Round-18 post-mortem: all wave-per-l variants sit at 155-163us because the
// 36 butterfly reductions (216 shuffles/thread) are DS-PIPE BOUND:
// 216 x 256 waves/CU x ~5cyc ~= 140us. Fix: thread-per-(l, s-quarter) --
// Q row in 16 float4 regs, full 64-dim dot IN-THREAD (zero per-s shuffles),
// 2-step shfl_xor merges the 4 quarters (8 DS ops total vs 216).
// Grid 1024 x 256 (64 l/block); XCD-affinity map keeps K gathers L2-resident
// (verified round 17: FETCH 73->17MB).
__global__ __launch_bounds__(256, 2) void qks_m_kernel(
    const float* __restrict__ Q, const float* __restrict__ K,
    const int* __restrict__ idx, float* __restrict__ Mout)
{
  __shared__ int sidx[64 * U_];
  const int p = blockIdx.x;                       // 0..1023
  const int g  = (p & 7) + (((p >> 3) & 7) << 3); // bh group -> XCD g%8
  const int q16 = p >> 6;                         // 0..15
  const int l0 = q16 * 64;
  const int tid = threadIdx.x;
  for (int i = tid; i < 64 * U_; i += 256) sidx[i] = idx[l0 * U_ + i];
  __syncthreads();

  const int ll = tid >> 2, sq = tid & 3;
  const int l = l0 + ll;
  const int h = g & (H_ - 1), b = g >> 4;
  const size_t rowb = (size_t)(b * L_) * DM_ + h * DH_;
  const float4* q4 = (const float4*)(Q + rowb + (size_t)l * DM_);
  float4 qv[16];
#pragma unroll
  for (int i = 0; i < 16; ++i) qv[i] = q4[i];

  const int* ip = &sidx[ll * U_];
  const int s0 = sq * 9;
  const int s1 = (sq == 3) ? U_ : (s0 + 9);
  float mx = -__builtin_inff();
  float sm = 0.f;
  for (int s = s0; s < s1; ++s) {
    const float4* k4 = (const float4*)(K + rowb + (size_t)ip[s] * DM_);
    float a0 = 0.f, a1 = 0.f, a2 = 0.f, a3 = 0.f;
#pragma unroll
    for (int i = 0; i < 16; i += 4) {
      const float4 k0 = k4[i], k1 = k4[i+1], k2 = k4[i+2], k3 = k4[i+3];
      a0 = fmaf(qv[i].x,   k0.x, a0); a0 = fmaf(qv[i].y,   k0.y, a0);
      a0 = fmaf(qv[i].z,   k0.z, a0); a0 = fmaf(qv[i].w,   k0.w, a0);
      a1 = fmaf(qv[i+1].x, k1.x, a1); a1 = fmaf(qv[i+1].y, k1.y, a1);
      a1 = fmaf(qv[i+1].z, k1.z, a1); a1 = fmaf(qv[i+1].w, k1.w, a1);
      a2 = fmaf(qv[i+2].x, k2.x, a2); a2 = fmaf(qv[i+2].y, k2.y, a2);
      a2 = fmaf(qv[i+2].z, k2.z, a2); a2 = fmaf(qv[i+2].w, k2.w, a2);
      a3 = fmaf(qv[i+3].x, k3.x, a3); a3 = fmaf(qv[i+3].y, k3.y, a3);
      a3 = fmaf(qv[i+3].z, k3.z, a3); a3 = fmaf(qv[i+3].w, k3.w, a3);
    }
    const float p2 = (a0 + a1) + (a2 + a3);
    mx = fmaxf(mx, p2);
    sm += p2;
  }
  // merge the 4 s-quarters (lanes 4i..4i+3 hold the same l)
  mx = fmaxf(mx, __shfl_xor(mx, 1, 64));
  mx = fmaxf(mx, __shfl_xor(mx, 2, 64));
  sm += __shfl_xor(sm, 1, 64);
  sm += __shfl_xor(sm, 2, 64);
  if (sq == 0) Mout[g * L_ + l] = mx - sm * (1.0f / 1024.0f);
}

// ---------------- top-35 indices per (b,h) --------------------------------
__global__ __launch_bounds__(256) void topk_kernel(
    const float* __restrict__ M, int* __restrict__ Mtop)
{
  const int bh  = blockIdx.x;
  const int tid = threadIdx.x;
  __shared__ float vals[L_];
  __shared__ float rv[256];
  __shared__ int   ri[256];
  for (int i = tid; i < L_; i += 256) vals[i] = M[(size_t)bh * L_ + i];
  __syncthreads();
  for (int t = 0; t < U_; ++t) {
    float best = -__builtin_inff();
    int   bi   = L_;
    for (int i = tid; i < L_; i += 256) {
      const float v = vals[i];
      if (v > best) { best = v; bi = i; }
    }
    rv[tid] = best; ri[tid] = bi;
    __syncthreads();
    for (int s = 128; s > 0; s >>= 1) {
      if (tid < s) {
        if (rv[tid+s] > rv[tid] || (rv[tid+s] == rv[tid] && ri[tid+s] < ri[tid])) {
          rv[tid] = rv[tid+s]; ri[tid] = ri[tid+s];
        }
      }
      __syncthreads();
    }
    if (tid == 0) { Mtop[bh * U_ + t] = ri[0]; vals[ri[0]] = -__builtin_inff(); }
    __syncthreads();
  }
}

// ---------------- attention: 3-kernel k-split (round-13 verified) ---------
template<int UBASE, int UCNT>
__device__ __forceinline__ void score_group(
    const float* __restrict__ kp, const float* qs, const int* rowsL,
    uint32_t* __restrict__ prow, const int k, const int masked)
{
  float s[UCNT];
#pragma unroll
  for (int ug = 0; ug < UCNT; ++ug) s[ug] = 0.f;
#pragma unroll
  for (int dc = 0; dc < 64; dc += 16) {
    const float4 k0 = *(const float4*)(kp + dc);
    const float4 k1 = *(const float4*)(kp + dc + 4);
    const float4 k2 = *(const float4*)(kp + dc + 8);
    const float4 k3 = *(const float4*)(kp + dc + 12);
#pragma unroll
    for (int ug = 0; ug < UCNT; ++ug) {
      const float4* qp = (const float4*)&qs[(UBASE + ug) * 64 + dc];
      const float4 q0 = qp[0], q1 = qp[1], q2 = qp[2], q3 = qp[3];
      float acc = s[ug];
      acc = fmaf(q0.x, k0.x, acc); acc = fmaf(q0.y, k0.y, acc);
      acc = fmaf(q0.z, k0.z, acc); acc = fmaf(q0.w, k0.w, acc);
      acc = fmaf(q1.x, k1.x, acc); acc = fmaf(q1.y, k1.y, acc);
      acc = fmaf(q1.z, k1.z, acc); acc = fmaf(q1.w, k1.w, acc);
      acc = fmaf(q2.x, k2.x, acc); acc = fmaf(q2.y, k2.y, acc);
      acc = fmaf(q2.z, k2.z, acc); acc = fmaf(q2.w, k2.w, acc);
      acc = fmaf(q3.x, k3.x, acc); acc = fmaf(q3.y, k3.y, acc);
      acc = fmaf(q3.z, k3.z, acc); acc = fmaf(q3.w, k3.w, acc);
      s[ug] = acc;
    }
  }
#pragma unroll
  for (int ug = 0; ug < UCNT; ++ug) {
    float v = s[ug] * 0.125f;
    if (masked && k > rowsL[UBASE + ug]) v = -__builtin_inff();
    s[ug] = expf(v);
  }
#pragma unroll
  for (int j = 0; j < UCNT / 2; ++j)
    prow[UBASE / 2 + j] = bf16rne(s[2 * j]) | (bf16rne(s[2 * j + 1]) << 16);
  if (UCNT & 1)
    prow[UBASE / 2 + UCNT / 2] = bf16rne(s[UCNT - 1]);
}

__global__ __launch_bounds__(256) void attn_score(
    const float* __restrict__ Q, const float* __restrict__ K,
    const int* __restrict__ Mtop, uint32_t* __restrict__ Pg, int masked)
{
  __shared__ float qs[U_ * DH_];
  __shared__ int   rowsL[U_ + 1];
  const int bh = blockIdx.x >> 2, ks = blockIdx.x & 3;
  const int h = bh & (H_ - 1), b = bh >> 4;
  const int tid = threadIdx.x;
  const size_t kvbase = (size_t)(b * L_) * DM_ + h * DH_;

  if (tid < U_) rowsL[tid] = Mtop[bh * U_ + tid];
  __syncthreads();
  for (int i = tid; i < U_ * DH_; i += 256)
    qs[i] = Q[kvbase + (size_t)rowsL[i >> 6] * DM_ + (i & 63)];
  __syncthreads();

  const int k = ks * 256 + tid;
  const float* kp = K + kvbase + (size_t)k * DM_;
  uint32_t* prow = Pg + (size_t)bh * (L_ * 18) + (size_t)k * 18;
  score_group<0, 12>(kp, qs, rowsL, prow, k, masked);
  score_group<12, 12>(kp, qs, rowsL, prow, k, masked);
  score_group<24, 11>(kp, qs, rowsL, prow, k, masked);
}

__global__ __launch_bounds__(256) void attn_pv(
    const float* __restrict__ V, const uint32_t* __restrict__ Pg,
    float* __restrict__ Opart, float* __restrict__ Dpart)
{
  __shared__ uint32_t Pl[256 * 18];
  const int bh = blockIdx.x >> 2, ks = blockIdx.x & 3;
  const int h = bh & (H_ - 1), b = bh >> 4;
  const int tid = threadIdx.x, lane = tid & 63, wid = tid >> 6;
  const size_t kvbase = (size_t)(b * L_) * DM_ + h * DH_;

  const uint32_t* ps = Pg + (size_t)bh * (L_ * 18) + (size_t)(ks * 256) * 18;
  for (int i = tid; i < 256 * 18; i += 256) Pl[i] = ps[i];
  __syncthreads();

  float acc[9], dd[9];
#pragma unroll
  for (int j = 0; j < 9; ++j) { acc[j] = 0.f; dd[j] = 0.f; }

  const float* vp = V + kvbase + (size_t)(ks * 256) * DM_ + lane;
  const int widh = wid >> 1;
  const int hi   = wid & 1;
#pragma unroll 4
  for (int kk = 0; kk < 256; ++kk) {
    const float v0 = vp[(size_t)kk * DM_];
    const uint32_t* pr = &Pl[kk * 18];
#pragma unroll
    for (int j = 0; j < 9; ++j) {
      if (wid + 4 * j < U_) {
        const uint32_t w = pr[widh + 2 * j];
        const float p = hi ? bitsf32(w & 0xFFFF0000u) : bitsf32(w << 16);
        acc[j] = fmaf(p, v0, acc[j]);
        dd[j] += p;
      }
    }
  }
  const int pb = (ks * 64 + bh) * U_;
#pragma unroll
  for (int j = 0; j < 9; ++j) {
    const int u = wid + 4 * j;
    if (u < U_) {
      Opart[(size_t)(pb + u) * 64 + lane] = acc[j];
      if (lane == 0) Dpart[pb + u] = dd[j];
    }
  }
}

__global__ void attn_reduce(const float* __restrict__ Opart,
                            const float* __restrict__ Dpart,
                            float* __restrict__ ctx_rows)
{
  const int bhu = blockIdx.x;
  const int bh = bhu / U_, u = bhu % U_;
  const int lane = threadIdx.x;
  float o = 0.f, dd = 0.f;
#pragma unroll
  for (int ks = 0; ks < KS_; ++ks) {
    o  += Opart[(size_t)((ks * 64 + bh) * U_ + u) * 64 + lane];
    dd += Dpart[(ks * 64 + bh) * U_ + u];
  }
  ctx_rows[(size_t)bhu * 64 + lane] = o / dd;
}

// ---------------- cumsum / vmean / fill / scatter -------------------------
__global__ __launch_bounds__(256) void cumsum_kernel(
    const float* __restrict__ V, float* __restrict__ C)
{
  const int bh = blockIdx.x;
  const int h = bh & (H_ - 1), b = bh >> 4;
  const int d = threadIdx.x & 63, qq = threadIdx.x >> 6;
  __shared__ float chs[4][DH_];
  const size_t base = (size_t)b * L_ * DM_ + h * DH_ + d;
  float acc = 0.f;
  const int l0 = qq * 256;
  for (int l = l0; l < l0 + 256; ++l) acc += V[base + (size_t)l * DM_];
  chs[qq][d] = acc;
  __syncthreads();
  float off = 0.f;
  for (int j = 0; j < qq; ++j) off += chs[j][d];
  acc = off;
  for (int l = l0; l < l0 + 256; ++l) {
    acc += V[base + (size_t)l * DM_];
    C[base + (size_t)l * DM_] = acc;
  }
}

__global__ __launch_bounds__(256) void vmean_kernel(
    const float* __restrict__ V, float* __restrict__ vm)
{
  const int bh = blockIdx.x;
  const int h = bh & (H_ - 1), b = bh >> 4;
  const int d = threadIdx.x & 63, qq = threadIdx.x >> 6;
  __shared__ float chs[4][DH_];
  const size_t base = (size_t)b * L_ * DM_ + h * DH_ + d;
  float acc = 0.f;
  for (int l = qq * 256; l < qq * 256 + 256; ++l) acc += V[base + (size_t)l * DM_];
  chs[qq][d] = acc;
  __syncthreads();
  if (qq == 0)
    vm[bh * DH_ + d] = (chs[0][d] + chs[1][d] + chs[2][d] + chs[3][d]) * (1.0f / 1024.0f);
}

__global__ void fill_kernel(const float* __restrict__ vm, float* __restrict__ C)
{
  const size_t i = (size_t)blockIdx.x * 256 + threadIdx.x;
  const int d = (int)(i & 63);
  const int h = (int)((i >> 6) & (H_ - 1));
  const int b = (int)(i >> 20);
  C[i] = vm[(b * H_ + h) * DH_ + d];
}

__global__ void scatter_kernel(const float* __restrict__ ctx_rows,
                               const int* __restrict__ Mtop, float* __restrict__ C)
{
  const int bhu = blockIdx.x;
  const int u  = bhu % U_;
  const int bh = bhu / U_;
  const int h = bh & (H_ - 1), b = bh >> 4;
  const int row = Mtop[bh * U_ + u];
  C[(size_t)(b * L_ + row) * DM_ + h * DH_ + threadIdx.x] =
      ctx_rows[(size_t)bhu * DH_ + threadIdx.x];
}

// ---------------- LayerNorm(xa + xb), optional limb outputs ---------------
__global__ __launch_bounds__(256) void ln_kernel(
    const float* __restrict__ xa, const float* __restrict__ xb,
    const float* __restrict__ g, const float* __restrict__ bt,
    float* __restrict__ out, short* __restrict__ oh,
    short* __restrict__ om, short* __restrict__ ol)
{
  const int row = blockIdx.x;
  const int tid = threadIdx.x;
  __shared__ float v[DM_];
  __shared__ float red[256];
  float s = 0.f;
  for (int i = tid; i < DM_; i += 256) {
    const float t = xa[(size_t)row * DM_ + i] + xb[(size_t)row * DM_ + i];
    v[i] = t; s += t;
  }
  red[tid] = s; __syncthreads();
  for (int st = 128; st > 0; st >>= 1) { if (tid < st) red[tid] += red[tid+st]; __syncthreads(); }
  const float mean = red[0] * (1.0f / DM_);
  __syncthreads();
  float s2 = 0.f;
  for (int i = tid; i < DM_; i += 256) { const float dd = v[i] - mean; s2 += dd * dd; }
  red[tid] = s2; __syncthreads();
  for (int st = 128; st > 0; st >>= 1) { if (tid < st) red[tid] += red[tid+st]; __syncthreads(); }
  const float rstd = rsqrtf(red[0] * (1.0f / DM_) + 1e-5f);
  __syncthreads();
  for (int i = tid; i < DM_; i += 256) {
    const size_t idx = (size_t)row * DM_ + i;
    const float o = (v[i] - mean) * rstd * g[i] + bt[i];
    out[idx] = o;
    if (oh) {
      const uint32_t h = bf16rne(o);
      oh[idx] = (short)h;
      if (om) {
        const float r = o - bf16tof(h);
        const uint32_t m = bf16rne(r);
        om[idx] = (short)m;
        ol[idx] = (short)bf16rne(r - bf16tof(m));
      }
    }
  }
}

// ---------------- host orchestration --------------------------------------
extern "C" void kernel_launch(void* const* d_in, const int* in_sizes, int n_in,
                              void* d_out, int out_size, void* d_ws, size_t ws_size,
                              hipStream_t stream)
{
  (void)in_sizes; (void)n_in; (void)out_size; (void)ws_size;
  const float* x    = (const float*)d_in[0];
  const float* enc  = (const float*)d_in[1];
  const float* saWq = (const float*)d_in[2];  const float* sabq = (const float*)d_in[3];
  const float* saWk = (const float*)d_in[4];  const float* sabk = (const float*)d_in[5];
  const float* saWv = (const float*)d_in[6];  const float* sabv = (const float*)d_in[7];
  const float* saWo = (const float*)d_in[8];  const float* sabo = (const float*)d_in[9];
  const float* caWq = (const float*)d_in[10]; const float* cabq = (const float*)d_in[11];
  const float* caWk = (const float*)d_in[12]; const float* cabk = (const float*)d_in[13];
  const float* caWv = (const float*)d_in[14]; const float* cabv = (const float*)d_in[15];
  const float* caWo = (const float*)d_in[16]; const float* cabo = (const float*)d_in[17];
  const float* fW1  = (const float*)d_in[18]; const float* fb1  = (const float*)d_in[19];
  const float* fW2  = (const float*)d_in[20]; const float* fb2  = (const float*)d_in[21];
  const float* l1g  = (const float*)d_in[22]; const float* l1b  = (const float*)d_in[23];
  const float* l2g  = (const float*)d_in[24]; const float* l2b  = (const float*)d_in[25];
  const float* l3g  = (const float*)d_in[26]; const float* l3b  = (const float*)d_in[27];

  float* ws = (float*)d_ws;
  const size_t SL = (size_t)MROWS_ * DM_;       // 4M floats
  float* bufQ = ws;
  float* bufK = ws + SL;
  float* bufV = ws + 2 * SL;
  float* bufC = ws + 3 * SL;
  float* xcur = ws + 4 * SL;
  float* tmp  = ws + 5 * SL;
  float* smallp = ws + 6 * SL;
  int*   idxb = (int*)smallp;
  float* Mbuf = smallp + 36864;
  int*   Mtop = (int*)(smallp + 36864 + 65536);
  float* ctxr = smallp + 36864 + 65536 + 2304;
  float* vm   = ctxr + 143360;

  // attention scratch overlaid on bufC (dead until cumsum/fill):
  uint32_t* Pg    = (uint32_t*)bufC;
  float*    Opart = bufC + 1179648;
  float*    Dpart = Opart + (size_t)KS_ * 64 * U_ * 64;

  const size_t M1 = 1024u * 1024u;
  short* wreg = (short*)(ws + 6 * SL + 262144);
  short* areg = wreg + 8 * M1;
  short* Wqh = wreg;          short* Wqm = wreg + 1*M1; short* Wql = wreg + 2*M1;
  short* Wkh = wreg + 3*M1;   short* Wkm = wreg + 4*M1; short* Wkl = wreg + 5*M1;
  short* Wvh = wreg + 6*M1;   short* Woh = wreg + 7*M1;
  short* f1h = wreg;          short* f2h = wreg + 4*M1;
  short* xh = areg;           short* xm = areg + 4*M1;  short* xl = areg + 8*M1;
  short* eh = areg + 12*M1;   short* em = areg + 16*M1; short* el = areg + 20*M1;
  short* bCh = areg + 12*M1;
  short* hidh = (short*)bufQ;

  // --- JAX partitionable-threefry key ladder (verified round 3) ---
  uint32_t k1a, k1b, k2a, k2b;
  tf2x32(0u, 42u, 0u, 0u, k1a, k1b);
  tf2x32(0u, 42u, 0u, 1u, k2a, k2b);
  uint32_t kb1a, kb1b, kb2a, kb2b;
  tf2x32(k1a, k1b, 0u, 1u, kb1a, kb1b);
  tf2x32(k2a, k2b, 0u, 1u, kb2a, kb2b);

  const dim3 thr(256);
  const int gIdx = (IDXN_ + 255) / 256;
  const int n8 = (int)(SL / 8);
  const dim3 gT(16, 16);

  // ============ self attention (masked) ============
  tsplit_kernel<3><<<gT, thr, 0, stream>>>(saWq, Wqh, Wqm, Wql, DM_, DM_);
  tsplit_kernel<3><<<gT, thr, 0, stream>>>(saWk, Wkh, Wkm, Wkl, DM_, DM_);
  tsplit_kernel<1><<<gT, thr, 0, stream>>>(saWv, Wvh, nullptr, nullptr, DM_, DM_);
  tsplit_kernel<1><<<gT, thr, 0, stream>>>(saWo, Woh, nullptr, nullptr, DM_, DM_);
  rsplit_kernel<3><<<n8 / 256, thr, 0, stream>>>(x, xh, xm, xl, n8);
  {
    FJobs J = {};
    J.j[0] = { {xh, xm, xl}, {Wqh, Wqm, Wql}, sabq, bufQ, nullptr, 0 };
    J.j[1] = { {xh, xm, xl}, {Wkh, Wkm, Wkl}, sabk, bufK, nullptr, 0 };
    gemm_fused<3><<<dim3(8, 32, 2), thr, 0, stream>>>(J, DM_, DM_);
  }
  {
    FJobs J = {};
    J.j[0] = { {xh, nullptr, nullptr}, {Wvh, nullptr, nullptr}, sabv, bufV, nullptr, 0 };
    gemm_fused<1><<<dim3(8, 32, 1), thr, 0, stream>>>(J, DM_, DM_);
  }
  idx_kernel<<<gIdx, thr, 0, stream>>>(kb1a, kb1b, idxb);
  qks_m_kernel<<<1024, thr, 0, stream>>>(bufQ, bufK, idxb, Mbuf);
  topk_kernel<<<B_ * H_, thr, 0, stream>>>(Mbuf, Mtop);
  attn_score<<<B_ * H_ * KS_, thr, 0, stream>>>(bufQ, bufK, Mtop, Pg, 1);
  attn_pv<<<B_ * H_ * KS_, thr, 0, stream>>>(bufV, Pg, Opart, Dpart);
  attn_reduce<<<B_ * H_ * U_, dim3(64), 0, stream>>>(Opart, Dpart, ctxr);
  cumsum_kernel<<<B_ * H_, thr, 0, stream>>>(bufV, bufC);
  scatter_kernel<<<B_ * H_ * U_, dim3(64), 0, stream>>>(ctxr, Mtop, bufC);
  rsplit_kernel<1><<<n8 / 256, thr, 0, stream>>>(bufC, bCh, nullptr, nullptr, n8);
  {
    FJobs J = {};
    J.j[0] = { {bCh, nullptr, nullptr}, {Woh, nullptr, nullptr}, sabo, tmp, nullptr, 0 };
    gemm_fused<1><<<dim3(8, 32, 1), thr, 0, stream>>>(J, DM_, DM_);
  }
  ln_kernel<<<MROWS_, thr, 0, stream>>>(x, tmp, l1g, l1b, xcur, xh, xm, xl);

  // ============ cross attention (unmasked) ============
  tsplit_kernel<3><<<gT, thr, 0, stream>>>(caWq, Wqh, Wqm, Wql, DM_, DM_);
  tsplit_kernel<3><<<gT, thr, 0, stream>>>(caWk, Wkh, Wkm, Wkl, DM_, DM_);
  tsplit_kernel<1><<<gT, thr, 0, stream>>>(caWv, Wvh, nullptr, nullptr, DM_, DM_);
  tsplit_kernel<1><<<gT, thr, 0, stream>>>(caWo, Woh, nullptr, nullptr, DM_, DM_);
  rsplit_kernel<3><<<n8 / 256, thr, 0, stream>>>(enc, eh, em, el, n8);
  {
    FJobs J = {};
    J.j[0] = { {xh, xm, xl}, {Wqh, Wqm, Wql}, cabq, bufQ, nullptr, 0 };
    J.j[1] = { {eh, em, el}, {Wkh, Wkm, Wkl}, cabk, bufK, nullptr, 0 };
    gemm_fused<3><<<dim3(8, 32, 2), thr, 0, stream>>>(J, DM_, DM_);
  }
  {
    FJobs J = {};
    J.j[0] = { {eh, nullptr, nullptr}, {Wvh, nullptr, nullptr}, cabv, bufV, nullptr, 0 };
    gemm_fused<1><<<dim3(8, 32, 1), thr, 0, stream>>>(J, DM_, DM_);
  }
  idx_kernel<<<gIdx, thr, 0, stream>>>(kb2a, kb2b, idxb);
  qks_m_kernel<<<1024, thr, 0, stream>>>(bufQ, bufK, idxb, Mbuf);
  topk_kernel<<<B_ * H_, thr, 0, stream>>>(Mbuf, Mtop);
  attn_score<<<B_ * H_ * KS_, thr, 0, stream>>>(bufQ, bufK, Mtop, Pg, 0);
  attn_pv<<<B_ * H_ * KS_, thr, 0, stream>>>(bufV, Pg, Opart, Dpart);
  attn_reduce<<<B_ * H_ * U_, dim3(64), 0, stream>>>(Opart, Dpart, ctxr);
  vmean_kernel<<<B_ * H_, thr, 0, stream>>>(bufV, vm);
  fill_kernel<<<(int)(SL / 256), thr, 0, stream>>>(vm, bufC);
  scatter_kernel<<<B_ * H_ * U_, dim3(64), 0, stream>>>(ctxr, Mtop, bufC);
  rsplit_kernel<1><<<n8 / 256, thr, 0, stream>>>(bufC, bCh, nullptr, nullptr, n8);
  {
    FJobs J = {};
    J.j[0] = { {bCh, nullptr, nullptr}, {Woh, nullptr, nullptr}, cabo, tmp, nullptr, 0 };
    gemm_fused<1><<<dim3(8, 32, 1), thr, 0, stream>>>(J, DM_, DM_);
  }
  ln_kernel<<<MROWS_, thr, 0, stream>>>(xcur, tmp, l2g, l2b, xcur, xh, nullptr, nullptr);

  // ============ FFN ============
  tsplit_kernel<1><<<dim3(64, 16), thr, 0, stream>>>(fW1, f1h, nullptr, nullptr, DM_, FF_);
  tsplit_kernel<1><<<dim3(16, 64), thr, 0, stream>>>(fW2, f2h, nullptr, nullptr, FF_, DM_);
  {
    FJobs J = {};
    J.j[0] = { {xh, nullptr, nullptr}, {f1h, nullptr, nullptr}, fb1, nullptr, hidh, 1 };
    gemm_fused<1><<<dim3(32, 32, 1), thr, 0, stream>>>(J, DM_, FF_);
  }
  {
    FJobs J = {};
    J.j[0] = { {hidh, nullptr, nullptr}, {f2h, nullptr, nullptr}, fb2, tmp, nullptr, 0 };
    gemm_fused<1><<<dim3(8, 32, 1), thr, 0, stream>>>(J, FF_, DM_);
  }
  ln_kernel<<<MROWS_, thr, 0, stream>>>(xcur, tmp, l3g, l3b, (float*)d_out,
                                        nullptr, nullptr, nullptr);
}

// Round 20
// 939.227 us; speedup vs baseline: 1.2593x; 1.1857x over previous
//
#include <hip/hip_runtime.h>
#include <cstdint>
#include <cstddef>

// Informer ProbSparse decoder layer.
// GEMMs: split-once bf16 limbs + FUSED multi-limb bf16 GEMM (global_load_lds,
// per-K-step staging of all limbs; 6 pairings share staged tiles). XOR chunk
// swizzle (src-side, rule #21) kills the 8-way ds_read bank conflict; XCD
// swizzle for L2 locality. Q/K: 6 pairings (~f32); V/O/FFN: 1 (rne bf16).
// Attention: 3-kernel k-split. qks_m: 4-lane-cooperative rows (round-20:
// round-19's per-thread rows hit 64 scattered lines/instr -> TA-bound).
#define B_     4
#define L_     1024
#define DM_    1024
#define H_     16
#define DH_    64
#define U_     35
#define FF_    4096
#define MROWS_ 4096
#define IDXN_  35840
#define KS_    4

typedef __attribute__((ext_vector_type(8))) short bf16x8;
typedef __attribute__((ext_vector_type(4))) float f32x4;

// ---------------- Threefry-2x32-20 (exact JAX semantics) ----------------
__host__ __device__ inline void tf2x32(uint32_t k0, uint32_t k1,
                                       uint32_t x0, uint32_t x1,
                                       uint32_t& y0, uint32_t& y1) {
  const uint32_t ks2 = k0 ^ k1 ^ 0x1BD11BDAu;
  uint32_t v0 = x0 + k0, v1 = x1 + k1;
#define ROTL_(x,d) (((x)<<(d))|((x)>>(32-(d))))
#define RND_(r) { v0 += v1; v1 = ROTL_(v1,(r)); v1 ^= v0; }
  RND_(13) RND_(15) RND_(26) RND_(6)   v0 += k1;  v1 += ks2 + 1u;
  RND_(17) RND_(29) RND_(16) RND_(24)  v0 += ks2; v1 += k0  + 2u;
  RND_(13) RND_(15) RND_(26) RND_(6)   v0 += k0;  v1 += k1  + 3u;
  RND_(17) RND_(29) RND_(16) RND_(24)  v0 += k1;  v1 += ks2 + 4u;
  RND_(13) RND_(15) RND_(26) RND_(6)   v0 += ks2; v1 += k0  + 5u;
#undef RND_
#undef ROTL_
  y0 = v0; y1 = v1;
}

__global__ void idx_kernel(uint32_t k0, uint32_t k1, int* __restrict__ idx) {
  const int i = blockIdx.x * 256 + threadIdx.x;
  if (i >= IDXN_) return;
  uint32_t y0, y1;
  tf2x32(k0, k1, 0u, (uint32_t)i, y0, y1);
  idx[i] = (int)((y0 ^ y1) & 1023u);
}

// ---------------- bf16 helpers --------------------------------------------
__device__ __forceinline__ uint32_t f32bits(float x) {
  union { float f; uint32_t u; } c; c.f = x; return c.u;
}
__device__ __forceinline__ float bitsf32(uint32_t u) {
  union { uint32_t u; float f; } c; c.u = u; return c.f;
}
__device__ __forceinline__ uint32_t bf16rne(float x) {
  const uint32_t u = f32bits(x);
  return (u + 0x7FFFu + ((u >> 16) & 1u)) >> 16;
}
__device__ __forceinline__ float bf16tof(uint32_t h) { return bitsf32(h << 16); }

__device__ __forceinline__ void split3(float x, uint32_t& h, uint32_t& m, uint32_t& l) {
  h = bf16rne(x); const float r  = x - bf16tof(h);
  m = bf16rne(r); const float r2 = r - bf16tof(m);
  l = bf16rne(r2);
}

// ---------------- async global -> LDS (16B per lane) ----------------------
__device__ __forceinline__ void gload16(const void* g, void* l) {
  __builtin_amdgcn_global_load_lds(
      (const __attribute__((address_space(1))) void*)g,
      (__attribute__((address_space(3))) void*)l, 16, 0, 0);
}

// ---------------- transpose-split: W (KxN f32) -> W^T limbs (NxK bf16) ----
template<int LIMBS>
__global__ __launch_bounds__(256) void tsplit_kernel(
    const float* __restrict__ W, short* __restrict__ Th,
    short* __restrict__ Tm, short* __restrict__ Tl, int K, int N)
{
  __shared__ float tile[64][65];
  const int n0 = blockIdx.x * 64, k0 = blockIdx.y * 64;
  const int t = threadIdx.x;
  const int r = t >> 2, c0 = (t & 3) * 16;
  const float* src = W + (size_t)(k0 + r) * N + n0 + c0;
  const float4 v0 = *(const float4*)src;
  const float4 v1 = *(const float4*)(src + 4);
  const float4 v2 = *(const float4*)(src + 8);
  const float4 v3 = *(const float4*)(src + 12);
  float* tr = &tile[r][c0];
  tr[0]=v0.x; tr[1]=v0.y; tr[2]=v0.z; tr[3]=v0.w;
  tr[4]=v1.x; tr[5]=v1.y; tr[6]=v1.z; tr[7]=v1.w;
  tr[8]=v2.x; tr[9]=v2.y; tr[10]=v2.z; tr[11]=v2.w;
  tr[12]=v3.x; tr[13]=v3.y; tr[14]=v3.z; tr[15]=v3.w;
  __syncthreads();
  uint32_t ph[8], pm[8], pl[8];
#pragma unroll
  for (int j = 0; j < 16; j += 2) {
    uint32_t h0,m0,l0,h1,m1,l1;
    split3(tile[c0 + j][r], h0, m0, l0);
    split3(tile[c0 + j + 1][r], h1, m1, l1);
    ph[j>>1] = h0 | (h1 << 16);
    pm[j>>1] = m0 | (m1 << 16);
    pl[j>>1] = l0 | (l1 << 16);
  }
  const size_t ob = (size_t)(n0 + r) * K + k0 + c0;
  *(uint4*)(Th + ob)     = make_uint4(ph[0], ph[1], ph[2], ph[3]);
  *(uint4*)(Th + ob + 8) = make_uint4(ph[4], ph[5], ph[6], ph[7]);
  if (LIMBS == 3) {
    *(uint4*)(Tm + ob)     = make_uint4(pm[0], pm[1], pm[2], pm[3]);
    *(uint4*)(Tm + ob + 8) = make_uint4(pm[4], pm[5], pm[6], pm[7]);
    *(uint4*)(Tl + ob)     = make_uint4(pl[0], pl[1], pl[2], pl[3]);
    *(uint4*)(Tl + ob + 8) = make_uint4(pl[4], pl[5], pl[6], pl[7]);
  }
}

// ---------------- row split: X (f32) -> limbs (bf16), elementwise ---------
template<int LIMBS>
__global__ void rsplit_kernel(const float* __restrict__ X, short* __restrict__ Th,
                              short* __restrict__ Tm, short* __restrict__ Tl, int n8)
{
  const int i = blockIdx.x * 256 + threadIdx.x;
  if (i >= n8) return;
  const float4 a = ((const float4*)X)[2*i], b = ((const float4*)X)[2*i+1];
  const float v[8] = {a.x,a.y,a.z,a.w,b.x,b.y,b.z,b.w};
  uint32_t ph[4], pm[4], pl[4];
#pragma unroll
  for (int j = 0; j < 4; ++j) {
    uint32_t h0,m0,l0,h1,m1,l1;
    split3(v[2*j], h0, m0, l0);
    split3(v[2*j+1], h1, m1, l1);
    ph[j] = h0 | (h1 << 16); pm[j] = m0 | (m1 << 16); pl[j] = l0 | (l1 << 16);
  }
  ((uint4*)Th)[i] = make_uint4(ph[0], ph[1], ph[2], ph[3]);
  if (LIMBS == 3) {
    ((uint4*)Tm)[i] = make_uint4(pm[0], pm[1], pm[2], pm[3]);
    ((uint4*)Tl)[i] = make_uint4(pl[0], pl[1], pl[2], pl[3]);
  }
}

// ---------------- fused multi-limb bf16 GEMM (round-16 verified) ----------
struct FJob {
  const short* A[3];
  const short* B[3];
  const float* bias;
  float* C;       // nullable
  short* Ch;      // nullable: rne-bf16 of output
  int relu;
};
struct FJobs { FJob j[3]; };

template<int NL>
__global__ __launch_bounds__(256, 2) void gemm_fused(FJobs jobs, int K, int N)
{
  __shared__ short As[NL][4096] __attribute__((aligned(16)));
  __shared__ short Bs[NL][4096] __attribute__((aligned(16)));
  const int z = blockIdx.z;
  const int nwg  = gridDim.x * gridDim.y;
  const int flat = blockIdx.y * gridDim.x + blockIdx.x;
  const int swz  = (flat & 7) * (nwg >> 3) + (flat >> 3);
  const int bn = (swz % gridDim.x) * 128;
  const int bm = (swz / gridDim.x) * 128;

  const int t = threadIdx.x, lane = t & 63;
  const int wid = t >> 6, wr = wid >> 1, wc = wid & 1;
  const int l15 = lane & 15, kg = lane >> 4;
  const int srow = t >> 2;
  const int sc   = ((t & 3) ^ ((srow + (srow >> 2)) & 3)) * 8;

  int aoff[4], boff[4];
#pragma unroll
  for (int m = 0; m < 4; ++m) {
    const int ra = wr * 64 + m * 16 + l15;
    aoff[m] = ra * 32 + ((kg ^ ((ra + (ra >> 2)) & 3)) << 3);
    const int rb = wc * 64 + m * 16 + l15;
    boff[m] = rb * 32 + ((kg ^ ((rb + (rb >> 2)) & 3)) << 3);
  }

  f32x4 acc[4][4];
#pragma unroll
  for (int m = 0; m < 4; ++m)
#pragma unroll
    for (int n = 0; n < 4; ++n) acc[m][n] = (f32x4){0.f,0.f,0.f,0.f};

  const size_t aofs0 = (size_t)(bm + srow) * K + sc;
  const size_t bofs0 = (size_t)(bn + srow) * K + sc;
  const size_t half  = (size_t)64 * K;

  for (int kk = 0; kk < K; kk += 32) {
    __syncthreads();
#pragma unroll
    for (int l = 0; l < NL; ++l) {
      gload16(jobs.j[z].A[l] + aofs0 + kk,        &As[l][t * 8]);
      gload16(jobs.j[z].A[l] + aofs0 + half + kk, &As[l][2048 + t * 8]);
      gload16(jobs.j[z].B[l] + bofs0 + kk,        &Bs[l][t * 8]);
      gload16(jobs.j[z].B[l] + bofs0 + half + kk, &Bs[l][2048 + t * 8]);
    }
    __syncthreads();
    if (NL == 1) {
      bf16x8 a[4], b[4];
#pragma unroll
      for (int m = 0; m < 4; ++m) a[m] = *(const bf16x8*)&As[0][aoff[m]];
#pragma unroll
      for (int n = 0; n < 4; ++n) b[n] = *(const bf16x8*)&Bs[0][boff[n]];
#pragma unroll
      for (int m = 0; m < 4; ++m)
#pragma unroll
        for (int n = 0; n < 4; ++n)
          acc[m][n] = __builtin_amdgcn_mfma_f32_16x16x32_bf16(a[m], b[n], acc[m][n], 0, 0, 0);
    } else {
      bf16x8 a0[4], a1[4], a2[4], b[4];
#pragma unroll
      for (int m = 0; m < 4; ++m) {
        a0[m] = *(const bf16x8*)&As[0][aoff[m]];
        a1[m] = *(const bf16x8*)&As[1][aoff[m]];
        a2[m] = *(const bf16x8*)&As[2][aoff[m]];
      }
#pragma unroll
      for (int n = 0; n < 4; ++n) b[n] = *(const bf16x8*)&Bs[0][boff[n]];
#pragma unroll
      for (int m = 0; m < 4; ++m)
#pragma unroll
        for (int n = 0; n < 4; ++n) {
          acc[m][n] = __builtin_amdgcn_mfma_f32_16x16x32_bf16(a0[m], b[n], acc[m][n], 0, 0, 0);
          acc[m][n] = __builtin_amdgcn_mfma_f32_16x16x32_bf16(a1[m], b[n], acc[m][n], 0, 0, 0);
          acc[m][n] = __builtin_amdgcn_mfma_f32_16x16x32_bf16(a2[m], b[n], acc[m][n], 0, 0, 0);
        }
#pragma unroll
      for (int n = 0; n < 4; ++n) b[n] = *(const bf16x8*)&Bs[1][boff[n]];
#pragma unroll
      for (int m = 0; m < 4; ++m)
#pragma unroll
        for (int n = 0; n < 4; ++n) {
          acc[m][n] = __builtin_amdgcn_mfma_f32_16x16x32_bf16(a0[m], b[n], acc[m][n], 0, 0, 0);
          acc[m][n] = __builtin_amdgcn_mfma_f32_16x16x32_bf16(a1[m], b[n], acc[m][n], 0, 0, 0);
        }
#pragma unroll
      for (int n = 0; n < 4; ++n) b[n] = *(const bf16x8*)&Bs[2][boff[n]];
#pragma unroll
      for (int m = 0; m < 4; ++m)
#pragma unroll
        for (int n = 0; n < 4; ++n)
          acc[m][n] = __builtin_amdgcn_mfma_f32_16x16x32_bf16(a0[m], b[n], acc[m][n], 0, 0, 0);
    }
  }

  const float* bias = jobs.j[z].bias;
  float* C  = jobs.j[z].C;
  short* Ch = jobs.j[z].Ch;
  const int relu = jobs.j[z].relu;
  float bv[4];
#pragma unroll
  for (int n = 0; n < 4; ++n) bv[n] = bias[bn + wc*64 + n*16 + l15];
#pragma unroll
  for (int m = 0; m < 4; ++m) {
    const int row0 = bm + wr*64 + m*16 + kg*4;
#pragma unroll
    for (int n = 0; n < 4; ++n) {
      const int col = bn + wc*64 + n*16 + l15;
#pragma unroll
      for (int q = 0; q < 4; ++q) {
        float o = acc[m][n][q] + bv[n];
        if (relu) o = fmaxf(o, 0.f);
        const size_t off = (size_t)(row0 + q) * N + col;
        if (C)  C[off]  = o;
        if (Ch) Ch[off] = (short)bf16rne(o);
      }
    }
  }
}

// ---------------- sampled QK^T -> M scores --------------------------------
// Round-19 post-mortem: 121us, VALUBusy 5% -> TA request-rate bound: each
// float4 load's 64 lanes hit 64 DIFFERENT K rows (lanes of a 4-group own
// different samples) = 64 scattered lines/instr, serialized ~1/cyc in the
// address unit (144 x 64 x 16 waves/CU ~= 61us floor). Fix: lane q of each
// 4-group owns d-quarter q of the SAME row -> 4 lanes read contiguous 64B
// (1 line/group, 16 lines/instr, 4x fewer requests). Per-sample 16-elem dot
// in-thread + 2 shuffles to merge (70 DS ops/thread; only 4096 waves now so
// DS cost ~2us, unlike the 65536-wave regime of rounds 10-18).
__global__ __launch_bounds__(256, 2) void qks_m_kernel(
    const float* __restrict__ Q, const float* __restrict__ K,
    const int* __restrict__ idx, float* __restrict__ Mout)
{
  __shared__ int sidx[64 * U_];
  const int p = blockIdx.x;                       // 0..1023
  const int g  = (p & 7) + (((p >> 3) & 7) << 3); // bh group -> XCD g%8
  const int q16 = p >> 6;                         // 0..15
  const int l0 = q16 * 64;
  const int tid = threadIdx.x;
  for (int i = tid; i < 64 * U_; i += 256) sidx[i] = idx[l0 * U_ + i];
  __syncthreads();

  const int ll = tid >> 2, dq = tid & 3;          // dq = d-quarter (16 floats)
  const int l = l0 + ll;
  const int h = g & (H_ - 1), b = g >> 4;
  const size_t rowb = (size_t)(b * L_) * DM_ + h * DH_;
  const float* qrow = Q + rowb + (size_t)l * DM_ + dq * 4;
  float4 qv[4];
#pragma unroll
  for (int jj = 0; jj < 4; ++jj) qv[jj] = *(const float4*)(qrow + jj * 16);

  const int* ip = &sidx[ll * U_];
  float mx = -__builtin_inff();
  float sm = 0.f;
#pragma unroll 5
  for (int s = 0; s < U_; ++s) {
    const float* krow = K + rowb + (size_t)ip[s] * DM_ + dq * 4;
    const float4 k0 = *(const float4*)(krow);
    const float4 k1 = *(const float4*)(krow + 16);
    const float4 k2 = *(const float4*)(krow + 32);
    const float4 k3 = *(const float4*)(krow + 48);
    float a0 = 0.f, a1 = 0.f, a2 = 0.f, a3 = 0.f;
    a0 = fmaf(qv[0].x, k0.x, a0); a0 = fmaf(qv[0].y, k0.y, a0);
    a0 = fmaf(qv[0].z, k0.z, a0); a0 = fmaf(qv[0].w, k0.w, a0);
    a1 = fmaf(qv[1].x, k1.x, a1); a1 = fmaf(qv[1].y, k1.y, a1);
    a1 = fmaf(qv[1].z, k1.z, a1); a1 = fmaf(qv[1].w, k1.w, a1);
    a2 = fmaf(qv[2].x, k2.x, a2); a2 = fmaf(qv[2].y, k2.y, a2);
    a2 = fmaf(qv[2].z, k2.z, a2); a2 = fmaf(qv[2].w, k2.w, a2);
    a3 = fmaf(qv[3].x, k3.x, a3); a3 = fmaf(qv[3].y, k3.y, a3);
    a3 = fmaf(qv[3].z, k3.z, a3); a3 = fmaf(qv[3].w, k3.w, a3);
    float a = (a0 + a1) + (a2 + a3);
    a += __shfl_xor(a, 1, 64);
    a += __shfl_xor(a, 2, 64);                    // full 64-dim dot, all 4 lanes
    mx = fmaxf(mx, a);
    sm += a;
  }
  if (dq == 0) Mout[g * L_ + l] = mx - sm * (1.0f / 1024.0f);
}

// ---------------- top-35 indices per (b,h) --------------------------------
__global__ __launch_bounds__(256) void topk_kernel(
    const float* __restrict__ M, int* __restrict__ Mtop)
{
  const int bh  = blockIdx.x;
  const int tid = threadIdx.x;
  __shared__ float vals[L_];
  __shared__ float rv[256];
  __shared__ int   ri[256];
  for (int i = tid; i < L_; i += 256) vals[i] = M[(size_t)bh * L_ + i];
  __syncthreads();
  for (int t = 0; t < U_; ++t) {
    float best = -__builtin_inff();
    int   bi   = L_;
    for (int i = tid; i < L_; i += 256) {
      const float v = vals[i];
      if (v > best) { best = v; bi = i; }
    }
    rv[tid] = best; ri[tid] = bi;
    __syncthreads();
    for (int s = 128; s > 0; s >>= 1) {
      if (tid < s) {
        if (rv[tid+s] > rv[tid] || (rv[tid+s] == rv[tid] && ri[tid+s] < ri[tid])) {
          rv[tid] = rv[tid+s]; ri[tid] = ri[tid+s];
        }
      }
      __syncthreads();
    }
    if (tid == 0) { Mtop[bh * U_ + t] = ri[0]; vals[ri[0]] = -__builtin_inff(); }
    __syncthreads();
  }
}

// ---------------- attention: 3-kernel k-split (round-13 verified) ---------
template<int UBASE, int UCNT>
__device__ __forceinline__ void score_group(
    const float* __restrict__ kp, const float* qs, const int* rowsL,
    uint32_t* __restrict__ prow, const int k, const int masked)
{
  float s[UCNT];
#pragma unroll
  for (int ug = 0; ug < UCNT; ++ug) s[ug] = 0.f;
#pragma unroll
  for (int dc = 0; dc < 64; dc += 16) {
    const float4 k0 = *(const float4*)(kp + dc);
    const float4 k1 = *(const float4*)(kp + dc + 4);
    const float4 k2 = *(const float4*)(kp + dc + 8);
    const float4 k3 = *(const float4*)(kp + dc + 12);
#pragma unroll
    for (int ug = 0; ug < UCNT; ++ug) {
      const float4* qp = (const float4*)&qs[(UBASE + ug) * 64 + dc];
      const float4 q0 = qp[0], q1 = qp[1], q2 = qp[2], q3 = qp[3];
      float acc = s[ug];
      acc = fmaf(q0.x, k0.x, acc); acc = fmaf(q0.y, k0.y, acc);
      acc = fmaf(q0.z, k0.z, acc); acc = fmaf(q0.w, k0.w, acc);
      acc = fmaf(q1.x, k1.x, acc); acc = fmaf(q1.y, k1.y, acc);
      acc = fmaf(q1.z, k1.z, acc); acc = fmaf(q1.w, k1.w, acc);
      acc = fmaf(q2.x, k2.x, acc); acc = fmaf(q2.y, k2.y, acc);
      acc = fmaf(q2.z, k2.z, acc); acc = fmaf(q2.w, k2.w, acc);
      acc = fmaf(q3.x, k3.x, acc); acc = fmaf(q3.y, k3.y, acc);
      acc = fmaf(q3.z, k3.z, acc); acc = fmaf(q3.w, k3.w, acc);
      s[ug] = acc;
    }
  }
#pragma unroll
  for (int ug = 0; ug < UCNT; ++ug) {
    float v = s[ug] * 0.125f;
    if (masked && k > rowsL[UBASE + ug]) v = -__builtin_inff();
    s[ug] = expf(v);
  }
#pragma unroll
  for (int j = 0; j < UCNT / 2; ++j)
    prow[UBASE / 2 + j] = bf16rne(s[2 * j]) | (bf16rne(s[2 * j + 1]) << 16);
  if (UCNT & 1)
    prow[UBASE / 2 + UCNT / 2] = bf16rne(s[UCNT - 1]);
}

__global__ __launch_bounds__(256) void attn_score(
    const float* __restrict__ Q, const float* __restrict__ K,
    const int* __restrict__ Mtop, uint32_t* __restrict__ Pg, int masked)
{
  __shared__ float qs[U_ * DH_];
  __shared__ int   rowsL[U_ + 1];
  const int bh = blockIdx.x >> 2, ks = blockIdx.x & 3;
  const int h = bh & (H_ - 1), b = bh >> 4;
  const int tid = threadIdx.x;
  const size_t kvbase = (size_t)(b * L_) * DM_ + h * DH_;

  if (tid < U_) rowsL[tid] = Mtop[bh * U_ + tid];
  __syncthreads();
  for (int i = tid; i < U_ * DH_; i += 256)
    qs[i] = Q[kvbase + (size_t)rowsL[i >> 6] * DM_ + (i & 63)];
  __syncthreads();

  const int k = ks * 256 + tid;
  const float* kp = K + kvbase + (size_t)k * DM_;
  uint32_t* prow = Pg + (size_t)bh * (L_ * 18) + (size_t)k * 18;
  score_group<0, 12>(kp, qs, rowsL, prow, k, masked);
  score_group<12, 12>(kp, qs, rowsL, prow, k, masked);
  score_group<24, 11>(kp, qs, rowsL, prow, k, masked);
}

__global__ __launch_bounds__(256) void attn_pv(
    const float* __restrict__ V, const uint32_t* __restrict__ Pg,
    float* __restrict__ Opart, float* __restrict__ Dpart)
{
  __shared__ uint32_t Pl[256 * 18];
  const int bh = blockIdx.x >> 2, ks = blockIdx.x & 3;
  const int h = bh & (H_ - 1), b = bh >> 4;
  const int tid = threadIdx.x, lane = tid & 63, wid = tid >> 6;
  const size_t kvbase = (size_t)(b * L_) * DM_ + h * DH_;

  const uint32_t* ps = Pg + (size_t)bh * (L_ * 18) + (size_t)(ks * 256) * 18;
  for (int i = tid; i < 256 * 18; i += 256) Pl[i] = ps[i];
  __syncthreads();

  float acc[9], dd[9];
#pragma unroll
  for (int j = 0; j < 9; ++j) { acc[j] = 0.f; dd[j] = 0.f; }

  const float* vp = V + kvbase + (size_t)(ks * 256) * DM_ + lane;
  const int widh = wid >> 1;
  const int hi   = wid & 1;
#pragma unroll 4
  for (int kk = 0; kk < 256; ++kk) {
    const float v0 = vp[(size_t)kk * DM_];
    const uint32_t* pr = &Pl[kk * 18];
#pragma unroll
    for (int j = 0; j < 9; ++j) {
      if (wid + 4 * j < U_) {
        const uint32_t w = pr[widh + 2 * j];
        const float p = hi ? bitsf32(w & 0xFFFF0000u) : bitsf32(w << 16);
        acc[j] = fmaf(p, v0, acc[j]);
        dd[j] += p;
      }
    }
  }
  const int pb = (ks * 64 + bh) * U_;
#pragma unroll
  for (int j = 0; j < 9; ++j) {
    const int u = wid + 4 * j;
    if (u < U_) {
      Opart[(size_t)(pb + u) * 64 + lane] = acc[j];
      if (lane == 0) Dpart[pb + u] = dd[j];
    }
  }
}

__global__ void attn_reduce(const float* __restrict__ Opart,
                            const float* __restrict__ Dpart,
                            float* __restrict__ ctx_rows)
{
  const int bhu = blockIdx.x;
  const int bh = bhu / U_, u = bhu % U_;
  const int lane = threadIdx.x;
  float o = 0.f, dd = 0.f;
#pragma unroll
  for (int ks = 0; ks < KS_; ++ks) {
    o  += Opart[(size_t)((ks * 64 + bh) * U_ + u) * 64 + lane];
    dd += Dpart[(ks * 64 + bh) * U_ + u];
  }
  ctx_rows[(size_t)bhu * 64 + lane] = o / dd;
}

// ---------------- cumsum / vmean / fill / scatter -------------------------
__global__ __launch_bounds__(256) void cumsum_kernel(
    const float* __restrict__ V, float* __restrict__ C)
{
  const int bh = blockIdx.x;
  const int h = bh & (H_ - 1), b = bh >> 4;
  const int d = threadIdx.x & 63, qq = threadIdx.x >> 6;
  __shared__ float chs[4][DH_];
  const size_t base = (size_t)b * L_ * DM_ + h * DH_ + d;
  float acc = 0.f;
  const int l0 = qq * 256;
  for (int l = l0; l < l0 + 256; ++l) acc += V[base + (size_t)l * DM_];
  chs[qq][d] = acc;
  __syncthreads();
  float off = 0.f;
  for (int j = 0; j < qq; ++j) off += chs[j][d];
  acc = off;
  for (int l = l0; l < l0 + 256; ++l) {
    acc += V[base + (size_t)l * DM_];
    C[base + (size_t)l * DM_] = acc;
  }
}

__global__ __launch_bounds__(256) void vmean_kernel(
    const float* __restrict__ V, float* __restrict__ vm)
{
  const int bh = blockIdx.x;
  const int h = bh & (H_ - 1), b = bh >> 4;
  const int d = threadIdx.x & 63, qq = threadIdx.x >> 6;
  __shared__ float chs[4][DH_];
  const size_t base = (size_t)b * L_ * DM_ + h * DH_ + d;
  float acc = 0.f;
  for (int l = qq * 256; l < qq * 256 + 256; ++l) acc += V[base + (size_t)l * DM_];
  chs[qq][d] = acc;
  __syncthreads();
  if (qq == 0)
    vm[bh * DH_ + d] = (chs[0][d] + chs[1][d] + chs[2][d] + chs[3][d]) * (1.0f / 1024.0f);
}

__global__ void fill_kernel(const float* __restrict__ vm, float* __restrict__ C)
{
  const size_t i = (size_t)blockIdx.x * 256 + threadIdx.x;
  const int d = (int)(i & 63);
  const int h = (int)((i >> 6) & (H_ - 1));
  const int b = (int)(i >> 20);
  C[i] = vm[(b * H_ + h) * DH_ + d];
}

__global__ void scatter_kernel(const float* __restrict__ ctx_rows,
                               const int* __restrict__ Mtop, float* __restrict__ C)
{
  const int bhu = blockIdx.x;
  const int u  = bhu % U_;
  const int bh = bhu / U_;
  const int h = bh & (H_ - 1), b = bh >> 4;
  const int row = Mtop[bh * U_ + u];
  C[(size_t)(b * L_ + row) * DM_ + h * DH_ + threadIdx.x] =
      ctx_rows[(size_t)bhu * DH_ + threadIdx.x];
}

// ---------------- LayerNorm(xa + xb), optional limb outputs ---------------
__global__ __launch_bounds__(256) void ln_kernel(
    const float* __restrict__ xa, const float* __restrict__ xb,
    const float* __restrict__ g, const float* __restrict__ bt,
    float* __restrict__ out, short* __restrict__ oh,
    short* __restrict__ om, short* __restrict__ ol)
{
  const int row = blockIdx.x;
  const int tid = threadIdx.x;
  __shared__ float v[DM_];
  __shared__ float red[256];
  float s = 0.f;
  for (int i = tid; i < DM_; i += 256) {
    const float t = xa[(size_t)row * DM_ + i] + xb[(size_t)row * DM_ + i];
    v[i] = t; s += t;
  }
  red[tid] = s; __syncthreads();
  for (int st = 128; st > 0; st >>= 1) { if (tid < st) red[tid] += red[tid+st]; __syncthreads(); }
  const float mean = red[0] * (1.0f / DM_);
  __syncthreads();
  float s2 = 0.f;
  for (int i = tid; i < DM_; i += 256) { const float dd = v[i] - mean; s2 += dd * dd; }
  red[tid] = s2; __syncthreads();
  for (int st = 128; st > 0; st >>= 1) { if (tid < st) red[tid] += red[tid+st]; __syncthreads(); }
  const float rstd = rsqrtf(red[0] * (1.0f / DM_) + 1e-5f);
  __syncthreads();
  for (int i = tid; i < DM_; i += 256) {
    const size_t idx = (size_t)row * DM_ + i;
    const float o = (v[i] - mean) * rstd * g[i] + bt[i];
    out[idx] = o;
    if (oh) {
      const uint32_t h = bf16rne(o);
      oh[idx] = (short)h;
      if (om) {
        const float r = o - bf16tof(h);
        const uint32_t m = bf16rne(r);
        om[idx] = (short)m;
        ol[idx] = (short)bf16rne(r - bf16tof(m));
      }
    }
  }
}

// ---------------- host orchestration --------------------------------------
extern "C" void kernel_launch(void* const* d_in, const int* in_sizes, int n_in,
                              void* d_out, int out_size, void* d_ws, size_t ws_size,
                              hipStream_t stream)
{
  (void)in_sizes; (void)n_in; (void)out_size; (void)ws_size;
  const float* x    = (const float*)d_in[0];
  const float* enc  = (const float*)d_in[1];
  const float* saWq = (const float*)d_in[2];  const float* sabq = (const float*)d_in[3];
  const float* saWk = (const float*)d_in[4];  const float* sabk = (const float*)d_in[5];
  const float* saWv = (const float*)d_in[6];  const float* sabv = (const float*)d_in[7];
  const float* saWo = (const float*)d_in[8];  const float* sabo = (const float*)d_in[9];
  const float* caWq = (const float*)d_in[10]; const float* cabq = (const float*)d_in[11];
  const float* caWk = (const float*)d_in[12]; const float* cabk = (const float*)d_in[13];
  const float* caWv = (const float*)d_in[14]; const float* cabv = (const float*)d_in[15];
  const float* caWo = (const float*)d_in[16]; const float* cabo = (const float*)d_in[17];
  const float* fW1  = (const float*)d_in[18]; const float* fb1  = (const float*)d_in[19];
  const float* fW2  = (const float*)d_in[20]; const float* fb2  = (const float*)d_in[21];
  const float* l1g  = (const float*)d_in[22]; const float* l1b  = (const float*)d_in[23];
  const float* l2g  = (const float*)d_in[24]; const float* l2b  = (const float*)d_in[25];
  const float* l3g  = (const float*)d_in[26]; const float* l3b  = (const float*)d_in[27];

  float* ws = (float*)d_ws;
  const size_t SL = (size_t)MROWS_ * DM_;       // 4M floats
  float* bufQ = ws;
  float* bufK = ws + SL;
  float* bufV = ws + 2 * SL;
  float* bufC = ws + 3 * SL;
  float* xcur = ws + 4 * SL;
  float* tmp  = ws + 5 * SL;
  float* smallp = ws + 6 * SL;
  int*   idxb = (int*)smallp;
  float* Mbuf = smallp + 36864;
  int*   Mtop = (int*)(smallp + 36864 + 65536);
  float* ctxr = smallp + 36864 + 65536 + 2304;
  float* vm   = ctxr + 143360;

  // attention scratch overlaid on bufC (dead until cumsum/fill):
  uint32_t* Pg    = (uint32_t*)bufC;
  float*    Opart = bufC + 1179648;
  float*    Dpart = Opart + (size_t)KS_ * 64 * U_ * 64;

  const size_t M1 = 1024u * 1024u;
  short* wreg = (short*)(ws + 6 * SL + 262144);
  short* areg = wreg + 8 * M1;
  short* Wqh = wreg;          short* Wqm = wreg + 1*M1; short* Wql = wreg + 2*M1;
  short* Wkh = wreg + 3*M1;   short* Wkm = wreg + 4*M1; short* Wkl = wreg + 5*M1;
  short* Wvh = wreg + 6*M1;   short* Woh = wreg + 7*M1;
  short* f1h = wreg;          short* f2h = wreg + 4*M1;
  short* xh = areg;           short* xm = areg + 4*M1;  short* xl = areg + 8*M1;
  short* eh = areg + 12*M1;   short* em = areg + 16*M1; short* el = areg + 20*M1;
  short* bCh = areg + 12*M1;
  short* hidh = (short*)bufQ;

  // --- JAX partitionable-threefry key ladder (verified round 3) ---
  uint32_t k1a, k1b, k2a, k2b;
  tf2x32(0u, 42u, 0u, 0u, k1a, k1b);
  tf2x32(0u, 42u, 0u, 1u, k2a, k2b);
  uint32_t kb1a, kb1b, kb2a, kb2b;
  tf2x32(k1a, k1b, 0u, 1u, kb1a, kb1b);
  tf2x32(k2a, k2b, 0u, 1u, kb2a, kb2b);

  const dim3 thr(256);
  const int gIdx = (IDXN_ + 255) / 256;
  const int n8 = (int)(SL / 8);
  const dim3 gT(16, 16);

  // ============ self attention (masked) ============
  tsplit_kernel<3><<<gT, thr, 0, stream>>>(saWq, Wqh, Wqm, Wql, DM_, DM_);
  tsplit_kernel<3><<<gT, thr, 0, stream>>>(saWk, Wkh, Wkm, Wkl, DM_, DM_);
  tsplit_kernel<1><<<gT, thr, 0, stream>>>(saWv, Wvh, nullptr, nullptr, DM_, DM_);
  tsplit_kernel<1><<<gT, thr, 0, stream>>>(saWo, Woh, nullptr, nullptr, DM_, DM_);
  rsplit_kernel<3><<<n8 / 256, thr, 0, stream>>>(x, xh, xm, xl, n8);
  {
    FJobs J = {};
    J.j[0] = { {xh, xm, xl}, {Wqh, Wqm, Wql}, sabq, bufQ, nullptr, 0 };
    J.j[1] = { {xh, xm, xl}, {Wkh, Wkm, Wkl}, sabk, bufK, nullptr, 0 };
    gemm_fused<3><<<dim3(8, 32, 2), thr, 0, stream>>>(J, DM_, DM_);
  }
  {
    FJobs J = {};
    J.j[0] = { {xh, nullptr, nullptr}, {Wvh, nullptr, nullptr}, sabv, bufV, nullptr, 0 };
    gemm_fused<1><<<dim3(8, 32, 1), thr, 0, stream>>>(J, DM_, DM_);
  }
  idx_kernel<<<gIdx, thr, 0, stream>>>(kb1a, kb1b, idxb);
  qks_m_kernel<<<1024, thr, 0, stream>>>(bufQ, bufK, idxb, Mbuf);
  topk_kernel<<<B_ * H_, thr, 0, stream>>>(Mbuf, Mtop);
  attn_score<<<B_ * H_ * KS_, thr, 0, stream>>>(bufQ, bufK, Mtop, Pg, 1);
  attn_pv<<<B_ * H_ * KS_, thr, 0, stream>>>(bufV, Pg, Opart, Dpart);
  attn_reduce<<<B_ * H_ * U_, dim3(64), 0, stream>>>(Opart, Dpart, ctxr);
  cumsum_kernel<<<B_ * H_, thr, 0, stream>>>(bufV, bufC);
  scatter_kernel<<<B_ * H_ * U_, dim3(64), 0, stream>>>(ctxr, Mtop, bufC);
  rsplit_kernel<1><<<n8 / 256, thr, 0, stream>>>(bufC, bCh, nullptr, nullptr, n8);
  {
    FJobs J = {};
    J.j[0] = { {bCh, nullptr, nullptr}, {Woh, nullptr, nullptr}, sabo, tmp, nullptr, 0 };
    gemm_fused<1><<<dim3(8, 32, 1), thr, 0, stream>>>(J, DM_, DM_);
  }
  ln_kernel<<<MROWS_, thr, 0, stream>>>(x, tmp, l1g, l1b, xcur, xh, xm, xl);

  // ============ cross attention (unmasked) ============
  tsplit_kernel<3><<<gT, thr, 0, stream>>>(caWq, Wqh, Wqm, Wql, DM_, DM_);
  tsplit_kernel<3><<<gT, thr, 0, stream>>>(caWk, Wkh, Wkm, Wkl, DM_, DM_);
  tsplit_kernel<1><<<gT, thr, 0, stream>>>(caWv, Wvh, nullptr, nullptr, DM_, DM_);
  tsplit_kernel<1><<<gT, thr, 0, stream>>>(caWo, Woh, nullptr, nullptr, DM_, DM_);
  rsplit_kernel<3><<<n8 / 256, thr, 0, stream>>>(enc, eh, em, el, n8);
  {
    FJobs J = {};
    J.j[0] = { {xh, xm, xl}, {Wqh, Wqm, Wql}, cabq, bufQ, nullptr, 0 };
    J.j[1] = { {eh, em, el}, {Wkh, Wkm, Wkl}, cabk, bufK, nullptr, 0 };
    gemm_fused<3><<<dim3(8, 32, 2), thr, 0, stream>>>(J, DM_, DM_);
  }
  {
    FJobs J = {};
    J.j[0] = { {eh, nullptr, nullptr}, {Wvh, nullptr, nullptr}, cabv, bufV, nullptr, 0 };
    gemm_fused<1><<<dim3(8, 32, 1), thr, 0, stream>>>(J, DM_, DM_);
  }
  idx_kernel<<<gIdx, thr, 0, stream>>>(kb2a, kb2b, idxb);
  qks_m_kernel<<<1024, thr, 0, stream>>>(bufQ, bufK, idxb, Mbuf);
  topk_kernel<<<B_ * H_, thr, 0, stream>>>(Mbuf, Mtop);
  attn_score<<<B_ * H_ * KS_, thr, 0, stream>>>(bufQ, bufK, Mtop, Pg, 0);
  attn_pv<<<B_ * H_ * KS_, thr, 0, stream>>>(bufV, Pg, Opart, Dpart);
  attn_reduce<<<B_ * H_ * U_, dim3(64), 0, stream>>>(Opart, Dpart, ctxr);
  vmean_kernel<<<B_ * H_, thr, 0, stream>>>(bufV, vm);
  fill_kernel<<<(int)(SL / 256), thr, 0, stream>>>(vm, bufC);
  scatter_kernel<<<B_ * H_ * U_, dim3(64), 0, stream>>>(ctxr, Mtop, bufC);
  rsplit_kernel<1><<<n8 / 256, thr, 0, stream>>>(bufC, bCh, nullptr, nullptr, n8);
  {
    FJobs J = {};
    J.j[0] = { {bCh, nullptr, nullptr}, {Woh, nullptr, nullptr}, cabo, tmp, nullptr, 0 };
    gemm_fused<1><<<dim3(8, 32, 1), thr, 0, stream>>>(J, DM_, DM_);
  }
  ln_kernel<<<MROWS_, thr, 0, stream>>>(xcur, tmp, l2g, l2b, xcur, xh, nullptr, nullptr);

  // ============ FFN ============
  tsplit_kernel<1><<<dim3(64, 16), thr, 0, stream>>>(fW1, f1h, nullptr, nullptr, DM_, FF_);
  tsplit_kernel<1><<<dim3(16, 64), thr, 0, stream>>>(fW2, f2h, nullptr, nullptr, FF_, DM_);
  {
    FJobs J = {};
    J.j[0] = { {xh, nullptr, nullptr}, {f1h, nullptr, nullptr}, fb1, nullptr, hidh, 1 };
    gemm_fused<1><<<dim3(32, 32, 1), thr, 0, stream>>>(J, DM_, FF_);
  }
  {
    FJobs J = {};
    J.j[0] = { {hidh, nullptr, nullptr}, {f2h, nullptr, nullptr}, fb2, tmp, nullptr, 0 };
    gemm_fused<1><<<dim3(8, 32, 1), thr, 0, stream>>>(J, FF_, DM_);
  }
  ln_kernel<<<MROWS_, thr, 0, stream>>>(xcur, tmp, l3g, l3b, (float*)d_out,
                                        nullptr, nullptr, nullptr);
}

// Round 21
// 793.125 us; speedup vs baseline: 1.4913x; 1.1842x over previous
//
#include <hip/hip_runtime.h>
#include <cstdint>
#include <cstddef>

// Informer ProbSparse decoder layer.
// GEMMs: split-once bf16 limbs + FUSED multi-limb bf16 GEMM (global_load_lds,
// per-K-step staging of all limbs; 6 pairings share staged tiles). XOR chunk
// swizzle (src-side, rule #21) kills the 8-way ds_read bank conflict; XCD
// swizzle for L2 locality. Q/K: 6 pairings (~f32); V/O/FFN: 1 (rne bf16).
// Attention: 3-kernel k-split; attn_pv at KSP_=16 splits (round-21: the
// 256-block version ran 1 wave/SIMD -> zero latency hiding, 107us).
#define B_     4
#define L_     1024
#define DM_    1024
#define H_     16
#define DH_    64
#define U_     35
#define FF_    4096
#define MROWS_ 4096
#define IDXN_  35840
#define KS_    4            // k-splits for attn_score
#define KSP_   16           // k-splits for attn_pv

typedef __attribute__((ext_vector_type(8))) short bf16x8;
typedef __attribute__((ext_vector_type(4))) float f32x4;

// ---------------- Threefry-2x32-20 (exact JAX semantics) ----------------
__host__ __device__ inline void tf2x32(uint32_t k0, uint32_t k1,
                                       uint32_t x0, uint32_t x1,
                                       uint32_t& y0, uint32_t& y1) {
  const uint32_t ks2 = k0 ^ k1 ^ 0x1BD11BDAu;
  uint32_t v0 = x0 + k0, v1 = x1 + k1;
#define ROTL_(x,d) (((x)<<(d))|((x)>>(32-(d))))
#define RND_(r) { v0 += v1; v1 = ROTL_(v1,(r)); v1 ^= v0; }
  RND_(13) RND_(15) RND_(26) RND_(6)   v0 += k1;  v1 += ks2 + 1u;
  RND_(17) RND_(29) RND_(16) RND_(24)  v0 += ks2; v1 += k0  + 2u;
  RND_(13) RND_(15) RND_(26) RND_(6)   v0 += k0;  v1 += k1  + 3u;
  RND_(17) RND_(29) RND_(16) RND_(24)  v0 += k1;  v1 += ks2 + 4u;
  RND_(13) RND_(15) RND_(26) RND_(6)   v0 += ks2; v1 += k0  + 5u;
#undef RND_
#undef ROTL_
  y0 = v0; y1 = v1;
}

__global__ void idx_kernel(uint32_t k0, uint32_t k1, int* __restrict__ idx) {
  const int i = blockIdx.x * 256 + threadIdx.x;
  if (i >= IDXN_) return;
  uint32_t y0, y1;
  tf2x32(k0, k1, 0u, (uint32_t)i, y0, y1);
  idx[i] = (int)((y0 ^ y1) & 1023u);
}

// ---------------- bf16 helpers --------------------------------------------
__device__ __forceinline__ uint32_t f32bits(float x) {
  union { float f; uint32_t u; } c; c.f = x; return c.u;
}
__device__ __forceinline__ float bitsf32(uint32_t u) {
  union { uint32_t u; float f; } c; c.u = u; return c.f;
}
__device__ __forceinline__ uint32_t bf16rne(float x) {
  const uint32_t u = f32bits(x);
  return (u + 0x7FFFu + ((u >> 16) & 1u)) >> 16;
}
__device__ __forceinline__ float bf16tof(uint32_t h) { return bitsf32(h << 16); }

__device__ __forceinline__ void split3(float x, uint32_t& h, uint32_t& m, uint32_t& l) {
  h = bf16rne(x); const float r  = x - bf16tof(h);
  m = bf16rne(r); const float r2 = r - bf16tof(m);
  l = bf16rne(r2);
}

// ---------------- async global -> LDS (16B per lane) ----------------------
__device__ __forceinline__ void gload16(const void* g, void* l) {
  __builtin_amdgcn_global_load_lds(
      (const __attribute__((address_space(1))) void*)g,
      (__attribute__((address_space(3))) void*)l, 16, 0, 0);
}

// ---------------- transpose-split: W (KxN f32) -> W^T limbs (NxK bf16) ----
template<int LIMBS>
__global__ __launch_bounds__(256) void tsplit_kernel(
    const float* __restrict__ W, short* __restrict__ Th,
    short* __restrict__ Tm, short* __restrict__ Tl, int K, int N)
{
  __shared__ float tile[64][65];
  const int n0 = blockIdx.x * 64, k0 = blockIdx.y * 64;
  const int t = threadIdx.x;
  const int r = t >> 2, c0 = (t & 3) * 16;
  const float* src = W + (size_t)(k0 + r) * N + n0 + c0;
  const float4 v0 = *(const float4*)src;
  const float4 v1 = *(const float4*)(src + 4);
  const float4 v2 = *(const float4*)(src + 8);
  const float4 v3 = *(const float4*)(src + 12);
  float* tr = &tile[r][c0];
  tr[0]=v0.x; tr[1]=v0.y; tr[2]=v0.z; tr[3]=v0.w;
  tr[4]=v1.x; tr[5]=v1.y; tr[6]=v1.z; tr[7]=v1.w;
  tr[8]=v2.x; tr[9]=v2.y; tr[10]=v2.z; tr[11]=v2.w;
  tr[12]=v3.x; tr[13]=v3.y; tr[14]=v3.z; tr[15]=v3.w;
  __syncthreads();
  uint32_t ph[8], pm[8], pl[8];
#pragma unroll
  for (int j = 0; j < 16; j += 2) {
    uint32_t h0,m0,l0,h1,m1,l1;
    split3(tile[c0 + j][r], h0, m0, l0);
    split3(tile[c0 + j + 1][r], h1, m1, l1);
    ph[j>>1] = h0 | (h1 << 16);
    pm[j>>1] = m0 | (m1 << 16);
    pl[j>>1] = l0 | (l1 << 16);
  }
  const size_t ob = (size_t)(n0 + r) * K + k0 + c0;
  *(uint4*)(Th + ob)     = make_uint4(ph[0], ph[1], ph[2], ph[3]);
  *(uint4*)(Th + ob + 8) = make_uint4(ph[4], ph[5], ph[6], ph[7]);
  if (LIMBS == 3) {
    *(uint4*)(Tm + ob)     = make_uint4(pm[0], pm[1], pm[2], pm[3]);
    *(uint4*)(Tm + ob + 8) = make_uint4(pm[4], pm[5], pm[6], pm[7]);
    *(uint4*)(Tl + ob)     = make_uint4(pl[0], pl[1], pl[2], pl[3]);
    *(uint4*)(Tl + ob + 8) = make_uint4(pl[4], pl[5], pl[6], pl[7]);
  }
}

// ---------------- row split: X (f32) -> limbs (bf16), elementwise ---------
template<int LIMBS>
__global__ void rsplit_kernel(const float* __restrict__ X, short* __restrict__ Th,
                              short* __restrict__ Tm, short* __restrict__ Tl, int n8)
{
  const int i = blockIdx.x * 256 + threadIdx.x;
  if (i >= n8) return;
  const float4 a = ((const float4*)X)[2*i], b = ((const float4*)X)[2*i+1];
  const float v[8] = {a.x,a.y,a.z,a.w,b.x,b.y,b.z,b.w};
  uint32_t ph[4], pm[4], pl[4];
#pragma unroll
  for (int j = 0; j < 4; ++j) {
    uint32_t h0,m0,l0,h1,m1,l1;
    split3(v[2*j], h0, m0, l0);
    split3(v[2*j+1], h1, m1, l1);
    ph[j] = h0 | (h1 << 16); pm[j] = m0 | (m1 << 16); pl[j] = l0 | (l1 << 16);
  }
  ((uint4*)Th)[i] = make_uint4(ph[0], ph[1], ph[2], ph[3]);
  if (LIMBS == 3) {
    ((uint4*)Tm)[i] = make_uint4(pm[0], pm[1], pm[2], pm[3]);
    ((uint4*)Tl)[i] = make_uint4(pl[0], pl[1], pl[2], pl[3]);
  }
}

// ---------------- fused multi-limb bf16 GEMM (round-16 verified) ----------
struct FJob {
  const short* A[3];
  const short* B[3];
  const float* bias;
  float* C;       // nullable
  short* Ch;      // nullable: rne-bf16 of output
  int relu;
};
struct FJobs { FJob j[3]; };

template<int NL>
__global__ __launch_bounds__(256, 2) void gemm_fused(FJobs jobs, int K, int N)
{
  __shared__ short As[NL][4096] __attribute__((aligned(16)));
  __shared__ short Bs[NL][4096] __attribute__((aligned(16)));
  const int z = blockIdx.z;
  const int nwg  = gridDim.x * gridDim.y;
  const int flat = blockIdx.y * gridDim.x + blockIdx.x;
  const int swz  = (flat & 7) * (nwg >> 3) + (flat >> 3);
  const int bn = (swz % gridDim.x) * 128;
  const int bm = (swz / gridDim.x) * 128;

  const int t = threadIdx.x, lane = t & 63;
  const int wid = t >> 6, wr = wid >> 1, wc = wid & 1;
  const int l15 = lane & 15, kg = lane >> 4;
  const int srow = t >> 2;
  const int sc   = ((t & 3) ^ ((srow + (srow >> 2)) & 3)) * 8;

  int aoff[4], boff[4];
#pragma unroll
  for (int m = 0; m < 4; ++m) {
    const int ra = wr * 64 + m * 16 + l15;
    aoff[m] = ra * 32 + ((kg ^ ((ra + (ra >> 2)) & 3)) << 3);
    const int rb = wc * 64 + m * 16 + l15;
    boff[m] = rb * 32 + ((kg ^ ((rb + (rb >> 2)) & 3)) << 3);
  }

  f32x4 acc[4][4];
#pragma unroll
  for (int m = 0; m < 4; ++m)
#pragma unroll
    for (int n = 0; n < 4; ++n) acc[m][n] = (f32x4){0.f,0.f,0.f,0.f};

  const size_t aofs0 = (size_t)(bm + srow) * K + sc;
  const size_t bofs0 = (size_t)(bn + srow) * K + sc;
  const size_t half  = (size_t)64 * K;

  for (int kk = 0; kk < K; kk += 32) {
    __syncthreads();
#pragma unroll
    for (int l = 0; l < NL; ++l) {
      gload16(jobs.j[z].A[l] + aofs0 + kk,        &As[l][t * 8]);
      gload16(jobs.j[z].A[l] + aofs0 + half + kk, &As[l][2048 + t * 8]);
      gload16(jobs.j[z].B[l] + bofs0 + kk,        &Bs[l][t * 8]);
      gload16(jobs.j[z].B[l] + bofs0 + half + kk, &Bs[l][2048 + t * 8]);
    }
    __syncthreads();
    if (NL == 1) {
      bf16x8 a[4], b[4];
#pragma unroll
      for (int m = 0; m < 4; ++m) a[m] = *(const bf16x8*)&As[0][aoff[m]];
#pragma unroll
      for (int n = 0; n < 4; ++n) b[n] = *(const bf16x8*)&Bs[0][boff[n]];
#pragma unroll
      for (int m = 0; m < 4; ++m)
#pragma unroll
        for (int n = 0; n < 4; ++n)
          acc[m][n] = __builtin_amdgcn_mfma_f32_16x16x32_bf16(a[m], b[n], acc[m][n], 0, 0, 0);
    } else {
      bf16x8 a0[4], a1[4], a2[4], b[4];
#pragma unroll
      for (int m = 0; m < 4; ++m) {
        a0[m] = *(const bf16x8*)&As[0][aoff[m]];
        a1[m] = *(const bf16x8*)&As[1][aoff[m]];
        a2[m] = *(const bf16x8*)&As[2][aoff[m]];
      }
#pragma unroll
      for (int n = 0; n < 4; ++n) b[n] = *(const bf16x8*)&Bs[0][boff[n]];
#pragma unroll
      for (int m = 0; m < 4; ++m)
#pragma unroll
        for (int n = 0; n < 4; ++n) {
          acc[m][n] = __builtin_amdgcn_mfma_f32_16x16x32_bf16(a0[m], b[n], acc[m][n], 0, 0, 0);
          acc[m][n] = __builtin_amdgcn_mfma_f32_16x16x32_bf16(a1[m], b[n], acc[m][n], 0, 0, 0);
          acc[m][n] = __builtin_amdgcn_mfma_f32_16x16x32_bf16(a2[m], b[n], acc[m][n], 0, 0, 0);
        }
#pragma unroll
      for (int n = 0; n < 4; ++n) b[n] = *(const bf16x8*)&Bs[1][boff[n]];
#pragma unroll
      for (int m = 0; m < 4; ++m)
#pragma unroll
        for (int n = 0; n < 4; ++n) {
          acc[m][n] = __builtin_amdgcn_mfma_f32_16x16x32_bf16(a0[m], b[n], acc[m][n], 0, 0, 0);
          acc[m][n] = __builtin_amdgcn_mfma_f32_16x16x32_bf16(a1[m], b[n], acc[m][n], 0, 0, 0);
        }
#pragma unroll
      for (int n = 0; n < 4; ++n) b[n] = *(const bf16x8*)&Bs[2][boff[n]];
#pragma unroll
      for (int m = 0; m < 4; ++m)
#pragma unroll
        for (int n = 0; n < 4; ++n)
          acc[m][n] = __builtin_amdgcn_mfma_f32_16x16x32_bf16(a0[m], b[n], acc[m][n], 0, 0, 0);
    }
  }

  const float* bias = jobs.j[z].bias;
  float* C  = jobs.j[z].C;
  short* Ch = jobs.j[z].Ch;
  const int relu = jobs.j[z].relu;
  float bv[4];
#pragma unroll
  for (int n = 0; n < 4; ++n) bv[n] = bias[bn + wc*64 + n*16 + l15];
#pragma unroll
  for (int m = 0; m < 4; ++m) {
    const int row0 = bm + wr*64 + m*16 + kg*4;
#pragma unroll
    for (int n = 0; n < 4; ++n) {
      const int col = bn + wc*64 + n*16 + l15;
#pragma unroll
      for (int q = 0; q < 4; ++q) {
        float o = acc[m][n][q] + bv[n];
        if (relu) o = fmaxf(o, 0.f);
        const size_t off = (size_t)(row0 + q) * N + col;
        if (C)  C[off]  = o;
        if (Ch) Ch[off] = (short)bf16rne(o);
      }
    }
  }
}

// ---------------- sampled QK^T -> M scores (round-20 verified) ------------
__global__ __launch_bounds__(256, 2) void qks_m_kernel(
    const float* __restrict__ Q, const float* __restrict__ K,
    const int* __restrict__ idx, float* __restrict__ Mout)
{
  __shared__ int sidx[64 * U_];
  const int p = blockIdx.x;                       // 0..1023
  const int g  = (p & 7) + (((p >> 3) & 7) << 3); // bh group -> XCD g%8
  const int q16 = p >> 6;                         // 0..15
  const int l0 = q16 * 64;
  const int tid = threadIdx.x;
  for (int i = tid; i < 64 * U_; i += 256) sidx[i] = idx[l0 * U_ + i];
  __syncthreads();

  const int ll = tid >> 2, dq = tid & 3;          // dq = d-quarter (16 floats)
  const int l = l0 + ll;
  const int h = g & (H_ - 1), b = g >> 4;
  const size_t rowb = (size_t)(b * L_) * DM_ + h * DH_;
  const float* qrow = Q + rowb + (size_t)l * DM_ + dq * 4;
  float4 qv[4];
#pragma unroll
  for (int jj = 0; jj < 4; ++jj) qv[jj] = *(const float4*)(qrow + jj * 16);

  const int* ip = &sidx[ll * U_];
  float mx = -__builtin_inff();
  float sm = 0.f;
#pragma unroll 5
  for (int s = 0; s < U_; ++s) {
    const float* krow = K + rowb + (size_t)ip[s] * DM_ + dq * 4;
    const float4 k0 = *(const float4*)(krow);
    const float4 k1 = *(const float4*)(krow + 16);
    const float4 k2 = *(const float4*)(krow + 32);
    const float4 k3 = *(const float4*)(krow + 48);
    float a0 = 0.f, a1 = 0.f, a2 = 0.f, a3 = 0.f;
    a0 = fmaf(qv[0].x, k0.x, a0); a0 = fmaf(qv[0].y, k0.y, a0);
    a0 = fmaf(qv[0].z, k0.z, a0); a0 = fmaf(qv[0].w, k0.w, a0);
    a1 = fmaf(qv[1].x, k1.x, a1); a1 = fmaf(qv[1].y, k1.y, a1);
    a1 = fmaf(qv[1].z, k1.z, a1); a1 = fmaf(qv[1].w, k1.w, a1);
    a2 = fmaf(qv[2].x, k2.x, a2); a2 = fmaf(qv[2].y, k2.y, a2);
    a2 = fmaf(qv[2].z, k2.z, a2); a2 = fmaf(qv[2].w, k2.w, a2);
    a3 = fmaf(qv[3].x, k3.x, a3); a3 = fmaf(qv[3].y, k3.y, a3);
    a3 = fmaf(qv[3].z, k3.z, a3); a3 = fmaf(qv[3].w, k3.w, a3);
    float a = (a0 + a1) + (a2 + a3);
    a += __shfl_xor(a, 1, 64);
    a += __shfl_xor(a, 2, 64);
    mx = fmaxf(mx, a);
    sm += a;
  }
  if (dq == 0) Mout[g * L_ + l] = mx - sm * (1.0f / 1024.0f);
}

// ---------------- top-35 indices per (b,h) --------------------------------
__global__ __launch_bounds__(256) void topk_kernel(
    const float* __restrict__ M, int* __restrict__ Mtop)
{
  const int bh  = blockIdx.x;
  const int tid = threadIdx.x;
  __shared__ float vals[L_];
  __shared__ float rv[256];
  __shared__ int   ri[256];
  for (int i = tid; i < L_; i += 256) vals[i] = M[(size_t)bh * L_ + i];
  __syncthreads();
  for (int t = 0; t < U_; ++t) {
    float best = -__builtin_inff();
    int   bi   = L_;
    for (int i = tid; i < L_; i += 256) {
      const float v = vals[i];
      if (v > best) { best = v; bi = i; }
    }
    rv[tid] = best; ri[tid] = bi;
    __syncthreads();
    for (int s = 128; s > 0; s >>= 1) {
      if (tid < s) {
        if (rv[tid+s] > rv[tid] || (rv[tid+s] == rv[tid] && ri[tid+s] < ri[tid])) {
          rv[tid] = rv[tid+s]; ri[tid] = ri[tid+s];
        }
      }
      __syncthreads();
    }
    if (tid == 0) { Mtop[bh * U_ + t] = ri[0]; vals[ri[0]] = -__builtin_inff(); }
    __syncthreads();
  }
}

// ---------------- attention: 3-kernel k-split -----------------------------
template<int UBASE, int UCNT>
__device__ __forceinline__ void score_group(
    const float* __restrict__ kp, const float* qs, const int* rowsL,
    uint32_t* __restrict__ prow, const int k, const int masked)
{
  float s[UCNT];
#pragma unroll
  for (int ug = 0; ug < UCNT; ++ug) s[ug] = 0.f;
#pragma unroll
  for (int dc = 0; dc < 64; dc += 16) {
    const float4 k0 = *(const float4*)(kp + dc);
    const float4 k1 = *(const float4*)(kp + dc + 4);
    const float4 k2 = *(const float4*)(kp + dc + 8);
    const float4 k3 = *(const float4*)(kp + dc + 12);
#pragma unroll
    for (int ug = 0; ug < UCNT; ++ug) {
      const float4* qp = (const float4*)&qs[(UBASE + ug) * 64 + dc];
      const float4 q0 = qp[0], q1 = qp[1], q2 = qp[2], q3 = qp[3];
      float acc = s[ug];
      acc = fmaf(q0.x, k0.x, acc); acc = fmaf(q0.y, k0.y, acc);
      acc = fmaf(q0.z, k0.z, acc); acc = fmaf(q0.w, k0.w, acc);
      acc = fmaf(q1.x, k1.x, acc); acc = fmaf(q1.y, k1.y, acc);
      acc = fmaf(q1.z, k1.z, acc); acc = fmaf(q1.w, k1.w, acc);
      acc = fmaf(q2.x, k2.x, acc); acc = fmaf(q2.y, k2.y, acc);
      acc = fmaf(q2.z, k2.z, acc); acc = fmaf(q2.w, k2.w, acc);
      acc = fmaf(q3.x, k3.x, acc); acc = fmaf(q3.y, k3.y, acc);
      acc = fmaf(q3.z, k3.z, acc); acc = fmaf(q3.w, k3.w, acc);
      s[ug] = acc;
    }
  }
#pragma unroll
  for (int ug = 0; ug < UCNT; ++ug) {
    float v = s[ug] * 0.125f;
    if (masked && k > rowsL[UBASE + ug]) v = -__builtin_inff();
    s[ug] = expf(v);
  }
#pragma unroll
  for (int j = 0; j < UCNT / 2; ++j)
    prow[UBASE / 2 + j] = bf16rne(s[2 * j]) | (bf16rne(s[2 * j + 1]) << 16);
  if (UCNT & 1)
    prow[UBASE / 2 + UCNT / 2] = bf16rne(s[UCNT - 1]);
}

__global__ __launch_bounds__(256) void attn_score(
    const float* __restrict__ Q, const float* __restrict__ K,
    const int* __restrict__ Mtop, uint32_t* __restrict__ Pg, int masked)
{
  __shared__ float qs[U_ * DH_];
  __shared__ int   rowsL[U_ + 1];
  const int bh = blockIdx.x >> 2, ks = blockIdx.x & 3;
  const int h = bh & (H_ - 1), b = bh >> 4;
  const int tid = threadIdx.x;
  const size_t kvbase = (size_t)(b * L_) * DM_ + h * DH_;

  if (tid < U_) rowsL[tid] = Mtop[bh * U_ + tid];
  __syncthreads();
  for (int i = tid; i < U_ * DH_; i += 256)
    qs[i] = Q[kvbase + (size_t)rowsL[i >> 6] * DM_ + (i & 63)];
  __syncthreads();

  const int k = ks * 256 + tid;
  const float* kp = K + kvbase + (size_t)k * DM_;
  uint32_t* prow = Pg + (size_t)bh * (L_ * 18) + (size_t)k * 18;
  score_group<0, 12>(kp, qs, rowsL, prow, k, masked);
  score_group<12, 12>(kp, qs, rowsL, prow, k, masked);
  score_group<24, 11>(kp, qs, rowsL, prow, k, masked);
}

// pv: grid (64*KSP_) x 256thr. XCD-affinity map (block i -> XCD i%8):
// xcd=p&7, idx=p>>3, bh=xcd+8*(idx&7), ks=idx>>3 -- bijective; each bh's 16
// blocks pinned to one XCD (V/P rows L2-resident). 64 k per block; 4
// blocks/CU -> 4 waves/SIMD (round-20 had 1 wave/SIMD, zero latency hiding).
__global__ __launch_bounds__(256) void attn_pv(
    const float* __restrict__ V, const uint32_t* __restrict__ Pg,
    float* __restrict__ Opart, float* __restrict__ Dpart)
{
  __shared__ uint32_t Pl[64 * 18];     // 4.6 KB
  const int p = blockIdx.x;
  const int xcd = p & 7, idx2 = p >> 3;
  const int bh = xcd + ((idx2 & 7) << 3);
  const int ks = idx2 >> 3;            // 0..15
  const int h = bh & (H_ - 1), b = bh >> 4;
  const int tid = threadIdx.x, lane = tid & 63, wid = tid >> 6;
  const size_t kvbase = (size_t)(b * L_) * DM_ + h * DH_;

  const uint32_t* ps = Pg + (size_t)bh * (L_ * 18) + (size_t)(ks * 64) * 18;
  for (int i = tid; i < 64 * 18; i += 256) Pl[i] = ps[i];
  __syncthreads();

  float acc[9], dd[9];
#pragma unroll
  for (int j = 0; j < 9; ++j) { acc[j] = 0.f; dd[j] = 0.f; }

  const float* vp = V + kvbase + (size_t)(ks * 64) * DM_ + lane;
  const int widh = wid >> 1;
  const int hi   = wid & 1;
#pragma unroll 8
  for (int kk = 0; kk < 64; ++kk) {
    const float v0 = vp[(size_t)kk * DM_];
    const uint32_t* pr = &Pl[kk * 18];
#pragma unroll
    for (int j = 0; j < 9; ++j) {
      if (wid + 4 * j < U_) {
        const uint32_t w = pr[widh + 2 * j];
        const float p2 = hi ? bitsf32(w & 0xFFFF0000u) : bitsf32(w << 16);
        acc[j] = fmaf(p2, v0, acc[j]);
        dd[j] += p2;
      }
    }
  }
  const int pb = (ks * 64 + bh) * U_;
#pragma unroll
  for (int j = 0; j < 9; ++j) {
    const int u = wid + 4 * j;
    if (u < U_) {
      Opart[(size_t)(pb + u) * 64 + lane] = acc[j];
      if (lane == 0) Dpart[pb + u] = dd[j];
    }
  }
}

__global__ void attn_reduce(const float* __restrict__ Opart,
                            const float* __restrict__ Dpart,
                            float* __restrict__ ctx_rows)
{
  const int bhu = blockIdx.x;
  const int bh = bhu / U_, u = bhu % U_;
  const int lane = threadIdx.x;
  float o = 0.f, dd = 0.f;
#pragma unroll
  for (int ks = 0; ks < KSP_; ++ks) {
    o  += Opart[(size_t)((ks * 64 + bh) * U_ + u) * 64 + lane];
    dd += Dpart[(ks * 64 + bh) * U_ + u];
  }
  ctx_rows[(size_t)bhu * 64 + lane] = o / dd;
}

// ---------------- cumsum / vmean / fill / scatter -------------------------
__global__ __launch_bounds__(256) void cumsum_kernel(
    const float* __restrict__ V, float* __restrict__ C)
{
  const int bh = blockIdx.x;
  const int h = bh & (H_ - 1), b = bh >> 4;
  const int d = threadIdx.x & 63, qq = threadIdx.x >> 6;
  __shared__ float chs[4][DH_];
  const size_t base = (size_t)b * L_ * DM_ + h * DH_ + d;
  float acc = 0.f;
  const int l0 = qq * 256;
  for (int l = l0; l < l0 + 256; ++l) acc += V[base + (size_t)l * DM_];
  chs[qq][d] = acc;
  __syncthreads();
  float off = 0.f;
  for (int j = 0; j < qq; ++j) off += chs[j][d];
  acc = off;
  for (int l = l0; l < l0 + 256; ++l) {
    acc += V[base + (size_t)l * DM_];
    C[base + (size_t)l * DM_] = acc;
  }
}

__global__ __launch_bounds__(256) void vmean_kernel(
    const float* __restrict__ V, float* __restrict__ vm)
{
  const int bh = blockIdx.x;
  const int h = bh & (H_ - 1), b = bh >> 4;
  const int d = threadIdx.x & 63, qq = threadIdx.x >> 6;
  __shared__ float chs[4][DH_];
  const size_t base = (size_t)b * L_ * DM_ + h * DH_ + d;
  float acc = 0.f;
  for (int l = qq * 256; l < qq * 256 + 256; ++l) acc += V[base + (size_t)l * DM_];
  chs[qq][d] = acc;
  __syncthreads();
  if (qq == 0)
    vm[bh * DH_ + d] = (chs[0][d] + chs[1][d] + chs[2][d] + chs[3][d]) * (1.0f / 1024.0f);
}

__global__ void fill_kernel(const float* __restrict__ vm, float* __restrict__ C)
{
  const size_t i = (size_t)blockIdx.x * 256 + threadIdx.x;
  const int d = (int)(i & 63);
  const int h = (int)((i >> 6) & (H_ - 1));
  const int b = (int)(i >> 20);
  C[i] = vm[(b * H_ + h) * DH_ + d];
}

__global__ void scatter_kernel(const float* __restrict__ ctx_rows,
                               const int* __restrict__ Mtop, float* __restrict__ C)
{
  const int bhu = blockIdx.x;
  const int u  = bhu % U_;
  const int bh = bhu / U_;
  const int h = bh & (H_ - 1), b = bh >> 4;
  const int row = Mtop[bh * U_ + u];
  C[(size_t)(b * L_ + row) * DM_ + h * DH_ + threadIdx.x] =
      ctx_rows[(size_t)bhu * DH_ + threadIdx.x];
}

// ---------------- LayerNorm(xa + xb), optional limb outputs ---------------
__global__ __launch_bounds__(256) void ln_kernel(
    const float* __restrict__ xa, const float* __restrict__ xb,
    const float* __restrict__ g, const float* __restrict__ bt,
    float* __restrict__ out, short* __restrict__ oh,
    short* __restrict__ om, short* __restrict__ ol)
{
  const int row = blockIdx.x;
  const int tid = threadIdx.x;
  __shared__ float v[DM_];
  __shared__ float red[256];
  float s = 0.f;
  for (int i = tid; i < DM_; i += 256) {
    const float t = xa[(size_t)row * DM_ + i] + xb[(size_t)row * DM_ + i];
    v[i] = t; s += t;
  }
  red[tid] = s; __syncthreads();
  for (int st = 128; st > 0; st >>= 1) { if (tid < st) red[tid] += red[tid+st]; __syncthreads(); }
  const float mean = red[0] * (1.0f / DM_);
  __syncthreads();
  float s2 = 0.f;
  for (int i = tid; i < DM_; i += 256) { const float dd = v[i] - mean; s2 += dd * dd; }
  red[tid] = s2; __syncthreads();
  for (int st = 128; st > 0; st >>= 1) { if (tid < st) red[tid] += red[tid+st]; __syncthreads(); }
  const float rstd = rsqrtf(red[0] * (1.0f / DM_) + 1e-5f);
  __syncthreads();
  for (int i = tid; i < DM_; i += 256) {
    const size_t idx = (size_t)row * DM_ + i;
    const float o = (v[i] - mean) * rstd * g[i] + bt[i];
    out[idx] = o;
    if (oh) {
      const uint32_t h = bf16rne(o);
      oh[idx] = (short)h;
      if (om) {
        const float r = o - bf16tof(h);
        const uint32_t m = bf16rne(r);
        om[idx] = (short)m;
        ol[idx] = (short)bf16rne(r - bf16tof(m));
      }
    }
  }
}

// ---------------- host orchestration --------------------------------------
extern "C" void kernel_launch(void* const* d_in, const int* in_sizes, int n_in,
                              void* d_out, int out_size, void* d_ws, size_t ws_size,
                              hipStream_t stream)
{
  (void)in_sizes; (void)n_in; (void)out_size; (void)ws_size;
  const float* x    = (const float*)d_in[0];
  const float* enc  = (const float*)d_in[1];
  const float* saWq = (const float*)d_in[2];  const float* sabq = (const float*)d_in[3];
  const float* saWk = (const float*)d_in[4];  const float* sabk = (const float*)d_in[5];
  const float* saWv = (const float*)d_in[6];  const float* sabv = (const float*)d_in[7];
  const float* saWo = (const float*)d_in[8];  const float* sabo = (const float*)d_in[9];
  const float* caWq = (const float*)d_in[10]; const float* cabq = (const float*)d_in[11];
  const float* caWk = (const float*)d_in[12]; const float* cabk = (const float*)d_in[13];
  const float* caWv = (const float*)d_in[14]; const float* cabv = (const float*)d_in[15];
  const float* caWo = (const float*)d_in[16]; const float* cabo = (const float*)d_in[17];
  const float* fW1  = (const float*)d_in[18]; const float* fb1  = (const float*)d_in[19];
  const float* fW2  = (const float*)d_in[20]; const float* fb2  = (const float*)d_in[21];
  const float* l1g  = (const float*)d_in[22]; const float* l1b  = (const float*)d_in[23];
  const float* l2g  = (const float*)d_in[24]; const float* l2b  = (const float*)d_in[25];
  const float* l3g  = (const float*)d_in[26]; const float* l3b  = (const float*)d_in[27];

  float* ws = (float*)d_ws;
  const size_t SL = (size_t)MROWS_ * DM_;       // 4M floats
  float* bufQ = ws;
  float* bufK = ws + SL;
  float* bufV = ws + 2 * SL;
  float* bufC = ws + 3 * SL;
  float* xcur = ws + 4 * SL;
  float* tmp  = ws + 5 * SL;
  float* smallp = ws + 6 * SL;
  int*   idxb = (int*)smallp;
  float* Mbuf = smallp + 36864;
  int*   Mtop = (int*)(smallp + 36864 + 65536);
  float* ctxr = smallp + 36864 + 65536 + 2304;
  float* vm   = ctxr + 143360;

  // attention scratch overlaid on bufC (dead until cumsum/fill):
  uint32_t* Pg    = (uint32_t*)bufC;                     // 64*1024*18 u32
  float*    Opart = bufC + 1179648;                      // KSP_*64*35*64 f32
  float*    Dpart = Opart + (size_t)KSP_ * 64 * U_ * 64; // KSP_*64*35 f32

  const size_t M1 = 1024u * 1024u;
  short* wreg = (short*)(ws + 6 * SL + 262144);
  short* areg = wreg + 8 * M1;
  short* Wqh = wreg;          short* Wqm = wreg + 1*M1; short* Wql = wreg + 2*M1;
  short* Wkh = wreg + 3*M1;   short* Wkm = wreg + 4*M1; short* Wkl = wreg + 5*M1;
  short* Wvh = wreg + 6*M1;   short* Woh = wreg + 7*M1;
  short* f1h = wreg;          short* f2h = wreg + 4*M1;
  short* xh = areg;           short* xm = areg + 4*M1;  short* xl = areg + 8*M1;
  short* eh = areg + 12*M1;   short* em = areg + 16*M1; short* el = areg + 20*M1;
  short* bCh = areg + 12*M1;
  short* hidh = (short*)bufQ;

  // --- JAX partitionable-threefry key ladder (verified round 3) ---
  uint32_t k1a, k1b, k2a, k2b;
  tf2x32(0u, 42u, 0u, 0u, k1a, k1b);
  tf2x32(0u, 42u, 0u, 1u, k2a, k2b);
  uint32_t kb1a, kb1b, kb2a, kb2b;
  tf2x32(k1a, k1b, 0u, 1u, kb1a, kb1b);
  tf2x32(k2a, k2b, 0u, 1u, kb2a, kb2b);

  const dim3 thr(256);
  const int gIdx = (IDXN_ + 255) / 256;
  const int n8 = (int)(SL / 8);
  const dim3 gT(16, 16);

  // ============ self attention (masked) ============
  tsplit_kernel<3><<<gT, thr, 0, stream>>>(saWq, Wqh, Wqm, Wql, DM_, DM_);
  tsplit_kernel<3><<<gT, thr, 0, stream>>>(saWk, Wkh, Wkm, Wkl, DM_, DM_);
  tsplit_kernel<1><<<gT, thr, 0, stream>>>(saWv, Wvh, nullptr, nullptr, DM_, DM_);
  tsplit_kernel<1><<<gT, thr, 0, stream>>>(saWo, Woh, nullptr, nullptr, DM_, DM_);
  rsplit_kernel<3><<<n8 / 256, thr, 0, stream>>>(x, xh, xm, xl, n8);
  {
    FJobs J = {};
    J.j[0] = { {xh, xm, xl}, {Wqh, Wqm, Wql}, sabq, bufQ, nullptr, 0 };
    J.j[1] = { {xh, xm, xl}, {Wkh, Wkm, Wkl}, sabk, bufK, nullptr, 0 };
    gemm_fused<3><<<dim3(8, 32, 2), thr, 0, stream>>>(J, DM_, DM_);
  }
  {
    FJobs J = {};
    J.j[0] = { {xh, nullptr, nullptr}, {Wvh, nullptr, nullptr}, sabv, bufV, nullptr, 0 };
    gemm_fused<1><<<dim3(8, 32, 1), thr, 0, stream>>>(J, DM_, DM_);
  }
  idx_kernel<<<gIdx, thr, 0, stream>>>(kb1a, kb1b, idxb);
  qks_m_kernel<<<1024, thr, 0, stream>>>(bufQ, bufK, idxb, Mbuf);
  topk_kernel<<<B_ * H_, thr, 0, stream>>>(Mbuf, Mtop);
  attn_score<<<B_ * H_ * KS_, thr, 0, stream>>>(bufQ, bufK, Mtop, Pg, 1);
  attn_pv<<<B_ * H_ * KSP_, thr, 0, stream>>>(bufV, Pg, Opart, Dpart);
  attn_reduce<<<B_ * H_ * U_, dim3(64), 0, stream>>>(Opart, Dpart, ctxr);
  cumsum_kernel<<<B_ * H_, thr, 0, stream>>>(bufV, bufC);
  scatter_kernel<<<B_ * H_ * U_, dim3(64), 0, stream>>>(ctxr, Mtop, bufC);
  rsplit_kernel<1><<<n8 / 256, thr, 0, stream>>>(bufC, bCh, nullptr, nullptr, n8);
  {
    FJobs J = {};
    J.j[0] = { {bCh, nullptr, nullptr}, {Woh, nullptr, nullptr}, sabo, tmp, nullptr, 0 };
    gemm_fused<1><<<dim3(8, 32, 1), thr, 0, stream>>>(J, DM_, DM_);
  }
  ln_kernel<<<MROWS_, thr, 0, stream>>>(x, tmp, l1g, l1b, xcur, xh, xm, xl);

  // ============ cross attention (unmasked) ============
  tsplit_kernel<3><<<gT, thr, 0, stream>>>(caWq, Wqh, Wqm, Wql, DM_, DM_);
  tsplit_kernel<3><<<gT, thr, 0, stream>>>(caWk, Wkh, Wkm, Wkl, DM_, DM_);
  tsplit_kernel<1><<<gT, thr, 0, stream>>>(caWv, Wvh, nullptr, nullptr, DM_, DM_);
  tsplit_kernel<1><<<gT, thr, 0, stream>>>(caWo, Woh, nullptr, nullptr, DM_, DM_);
  rsplit_kernel<3><<<n8 / 256, thr, 0, stream>>>(enc, eh, em, el, n8);
  {
    FJobs J = {};
    J.j[0] = { {xh, xm, xl}, {Wqh, Wqm, Wql}, cabq, bufQ, nullptr, 0 };
    J.j[1] = { {eh, em, el}, {Wkh, Wkm, Wkl}, cabk, bufK, nullptr, 0 };
    gemm_fused<3><<<dim3(8, 32, 2), thr, 0, stream>>>(J, DM_, DM_);
  }
  {
    FJobs J = {};
    J.j[0] = { {eh, nullptr, nullptr}, {Wvh, nullptr, nullptr}, cabv, bufV, nullptr, 0 };
    gemm_fused<1><<<dim3(8, 32, 1), thr, 0, stream>>>(J, DM_, DM_);
  }
  idx_kernel<<<gIdx, thr, 0, stream>>>(kb2a, kb2b, idxb);
  qks_m_kernel<<<1024, thr, 0, stream>>>(bufQ, bufK, idxb, Mbuf);
  topk_kernel<<<B_ * H_, thr, 0, stream>>>(Mbuf, Mtop);
  attn_score<<<B_ * H_ * KS_, thr, 0, stream>>>(bufQ, bufK, Mtop, Pg, 0);
  attn_pv<<<B_ * H_ * KSP_, thr, 0, stream>>>(bufV, Pg, Opart, Dpart);
  attn_reduce<<<B_ * H_ * U_, dim3(64), 0, stream>>>(Opart, Dpart, ctxr);
  vmean_kernel<<<B_ * H_, thr, 0, stream>>>(bufV, vm);
  fill_kernel<<<(int)(SL / 256), thr, 0, stream>>>(vm, bufC);
  scatter_kernel<<<B_ * H_ * U_, dim3(64), 0, stream>>>(ctxr, Mtop, bufC);
  rsplit_kernel<1><<<n8 / 256, thr, 0, stream>>>(bufC, bCh, nullptr, nullptr, n8);
  {
    FJobs J = {};
    J.j[0] = { {bCh, nullptr, nullptr}, {Woh, nullptr, nullptr}, cabo, tmp, nullptr, 0 };
    gemm_fused<1><<<dim3(8, 32, 1), thr, 0, stream>>>(J, DM_, DM_);
  }
  ln_kernel<<<MROWS_, thr, 0, stream>>>(xcur, tmp, l2g, l2b, xcur, xh, nullptr, nullptr);

  // ============ FFN ============
  tsplit_kernel<1><<<dim3(64, 16), thr, 0, stream>>>(fW1, f1h, nullptr, nullptr, DM_, FF_);
  tsplit_kernel<1><<<dim3(16, 64), thr, 0, stream>>>(fW2, f2h, nullptr, nullptr, FF_, DM_);
  {
    FJobs J = {};
    J.j[0] = { {xh, nullptr, nullptr}, {f1h, nullptr, nullptr}, fb1, nullptr, hidh, 1 };
    gemm_fused<1><<<dim3(32, 32, 1), thr, 0, stream>>>(J, DM_, FF_);
  }
  {
    FJobs J = {};
    J.j[0] = { {hidh, nullptr, nullptr}, {f2h, nullptr, nullptr}, fb2, tmp, nullptr, 0 };
    gemm_fused<1><<<dim3(8, 32, 1), thr, 0, stream>>>(J, FF_, DM_);
  }
  ln_kernel<<<MROWS_, thr, 0, stream>>>(xcur, tmp, l3g, l3b, (float*)d_out,
                                        nullptr, nullptr, nullptr);
}

// Round 22
// 787.794 us; speedup vs baseline: 1.5014x; 1.0068x over previous
//
#include <hip/hip_runtime.h>
#include <cstdint>
#include <cstddef>

// Informer ProbSparse decoder layer.
// GEMMs: split-once bf16 limbs + FUSED multi-limb bf16 GEMM (global_load_lds,
// per-K-step staging of all limbs; 6 pairings share staged tiles). XOR chunk
// swizzle (src-side, rule #21) + XCD swizzle. Q/K: 6 pairings (~f32);
// V/O/FFN: 1 (rne bf16). Attention: 3-kernel k-split; attn_score and attn_pv
// both 4-lane-cooperative with XCD affinity (rounds 20-22).
#define B_     4
#define L_     1024
#define DM_    1024
#define H_     16
#define DH_    64
#define U_     35
#define FF_    4096
#define MROWS_ 4096
#define IDXN_  35840
#define KSC_   16           // k-splits for attn_score
#define KSP_   16           // k-splits for attn_pv

typedef __attribute__((ext_vector_type(8))) short bf16x8;
typedef __attribute__((ext_vector_type(4))) float f32x4;

// ---------------- Threefry-2x32-20 (exact JAX semantics) ----------------
__host__ __device__ inline void tf2x32(uint32_t k0, uint32_t k1,
                                       uint32_t x0, uint32_t x1,
                                       uint32_t& y0, uint32_t& y1) {
  const uint32_t ks2 = k0 ^ k1 ^ 0x1BD11BDAu;
  uint32_t v0 = x0 + k0, v1 = x1 + k1;
#define ROTL_(x,d) (((x)<<(d))|((x)>>(32-(d))))
#define RND_(r) { v0 += v1; v1 = ROTL_(v1,(r)); v1 ^= v0; }
  RND_(13) RND_(15) RND_(26) RND_(6)   v0 += k1;  v1 += ks2 + 1u;
  RND_(17) RND_(29) RND_(16) RND_(24)  v0 += ks2; v1 += k0  + 2u;
  RND_(13) RND_(15) RND_(26) RND_(6)   v0 += k0;  v1 += k1  + 3u;
  RND_(17) RND_(29) RND_(16) RND_(24)  v0 += k1;  v1 += ks2 + 4u;
  RND_(13) RND_(15) RND_(26) RND_(6)   v0 += ks2; v1 += k0  + 5u;
#undef RND_
#undef ROTL_
  y0 = v0; y1 = v1;
}

__global__ void idx_kernel(uint32_t k0, uint32_t k1, int* __restrict__ idx) {
  const int i = blockIdx.x * 256 + threadIdx.x;
  if (i >= IDXN_) return;
  uint32_t y0, y1;
  tf2x32(k0, k1, 0u, (uint32_t)i, y0, y1);
  idx[i] = (int)((y0 ^ y1) & 1023u);
}

// ---------------- bf16 helpers --------------------------------------------
__device__ __forceinline__ uint32_t f32bits(float x) {
  union { float f; uint32_t u; } c; c.f = x; return c.u;
}
__device__ __forceinline__ float bitsf32(uint32_t u) {
  union { uint32_t u; float f; } c; c.u = u; return c.f;
}
__device__ __forceinline__ uint32_t bf16rne(float x) {
  const uint32_t u = f32bits(x);
  return (u + 0x7FFFu + ((u >> 16) & 1u)) >> 16;
}
__device__ __forceinline__ float bf16tof(uint32_t h) { return bitsf32(h << 16); }

__device__ __forceinline__ void split3(float x, uint32_t& h, uint32_t& m, uint32_t& l) {
  h = bf16rne(x); const float r  = x - bf16tof(h);
  m = bf16rne(r); const float r2 = r - bf16tof(m);
  l = bf16rne(r2);
}

// ---------------- async global -> LDS (16B per lane) ----------------------
__device__ __forceinline__ void gload16(const void* g, void* l) {
  __builtin_amdgcn_global_load_lds(
      (const __attribute__((address_space(1))) void*)g,
      (__attribute__((address_space(3))) void*)l, 16, 0, 0);
}

// ---------------- transpose-split: W (KxN f32) -> W^T limbs (NxK bf16) ----
template<int LIMBS>
__global__ __launch_bounds__(256) void tsplit_kernel(
    const float* __restrict__ W, short* __restrict__ Th,
    short* __restrict__ Tm, short* __restrict__ Tl, int K, int N)
{
  __shared__ float tile[64][65];
  const int n0 = blockIdx.x * 64, k0 = blockIdx.y * 64;
  const int t = threadIdx.x;
  const int r = t >> 2, c0 = (t & 3) * 16;
  const float* src = W + (size_t)(k0 + r) * N + n0 + c0;
  const float4 v0 = *(const float4*)src;
  const float4 v1 = *(const float4*)(src + 4);
  const float4 v2 = *(const float4*)(src + 8);
  const float4 v3 = *(const float4*)(src + 12);
  float* tr = &tile[r][c0];
  tr[0]=v0.x; tr[1]=v0.y; tr[2]=v0.z; tr[3]=v0.w;
  tr[4]=v1.x; tr[5]=v1.y; tr[6]=v1.z; tr[7]=v1.w;
  tr[8]=v2.x; tr[9]=v2.y; tr[10]=v2.z; tr[11]=v2.w;
  tr[12]=v3.x; tr[13]=v3.y; tr[14]=v3.z; tr[15]=v3.w;
  __syncthreads();
  uint32_t ph[8], pm[8], pl[8];
#pragma unroll
  for (int j = 0; j < 16; j += 2) {
    uint32_t h0,m0,l0,h1,m1,l1;
    split3(tile[c0 + j][r], h0, m0, l0);
    split3(tile[c0 + j + 1][r], h1, m1, l1);
    ph[j>>1] = h0 | (h1 << 16);
    pm[j>>1] = m0 | (m1 << 16);
    pl[j>>1] = l0 | (l1 << 16);
  }
  const size_t ob = (size_t)(n0 + r) * K + k0 + c0;
  *(uint4*)(Th + ob)     = make_uint4(ph[0], ph[1], ph[2], ph[3]);
  *(uint4*)(Th + ob + 8) = make_uint4(ph[4], ph[5], ph[6], ph[7]);
  if (LIMBS == 3) {
    *(uint4*)(Tm + ob)     = make_uint4(pm[0], pm[1], pm[2], pm[3]);
    *(uint4*)(Tm + ob + 8) = make_uint4(pm[4], pm[5], pm[6], pm[7]);
    *(uint4*)(Tl + ob)     = make_uint4(pl[0], pl[1], pl[2], pl[3]);
    *(uint4*)(Tl + ob + 8) = make_uint4(pl[4], pl[5], pl[6], pl[7]);
  }
}

// ---------------- row split: X (f32) -> limbs (bf16), elementwise ---------
template<int LIMBS>
__global__ void rsplit_kernel(const float* __restrict__ X, short* __restrict__ Th,
                              short* __restrict__ Tm, short* __restrict__ Tl, int n8)
{
  const int i = blockIdx.x * 256 + threadIdx.x;
  if (i >= n8) return;
  const float4 a = ((const float4*)X)[2*i], b = ((const float4*)X)[2*i+1];
  const float v[8] = {a.x,a.y,a.z,a.w,b.x,b.y,b.z,b.w};
  uint32_t ph[4], pm[4], pl[4];
#pragma unroll
  for (int j = 0; j < 4; ++j) {
    uint32_t h0,m0,l0,h1,m1,l1;
    split3(v[2*j], h0, m0, l0);
    split3(v[2*j+1], h1, m1, l1);
    ph[j] = h0 | (h1 << 16); pm[j] = m0 | (m1 << 16); pl[j] = l0 | (l1 << 16);
  }
  ((uint4*)Th)[i] = make_uint4(ph[0], ph[1], ph[2], ph[3]);
  if (LIMBS == 3) {
    ((uint4*)Tm)[i] = make_uint4(pm[0], pm[1], pm[2], pm[3]);
    ((uint4*)Tl)[i] = make_uint4(pl[0], pl[1], pl[2], pl[3]);
  }
}

// ---------------- fused multi-limb bf16 GEMM ------------------------------
// (round-22: launch_bounds (256,3) -- 48KB LDS permits 3 blocks/CU for NL=3;
// round-21 measured Occupancy 18% at (256,2), MfmaUtil 48%.)
struct FJob {
  const short* A[3];
  const short* B[3];
  const float* bias;
  float* C;       // nullable
  short* Ch;      // nullable: rne-bf16 of output
  int relu;
};
struct FJobs { FJob j[3]; };

template<int NL>
__global__ __launch_bounds__(256, 3) void gemm_fused(FJobs jobs, int K, int N)
{
  __shared__ short As[NL][4096] __attribute__((aligned(16)));
  __shared__ short Bs[NL][4096] __attribute__((aligned(16)));
  const int z = blockIdx.z;
  const int nwg  = gridDim.x * gridDim.y;
  const int flat = blockIdx.y * gridDim.x + blockIdx.x;
  const int swz  = (flat & 7) * (nwg >> 3) + (flat >> 3);
  const int bn = (swz % gridDim.x) * 128;
  const int bm = (swz / gridDim.x) * 128;

  const int t = threadIdx.x, lane = t & 63;
  const int wid = t >> 6, wr = wid >> 1, wc = wid & 1;
  const int l15 = lane & 15, kg = lane >> 4;
  const int srow = t >> 2;
  const int sc   = ((t & 3) ^ ((srow + (srow >> 2)) & 3)) * 8;

  int aoff[4], boff[4];
#pragma unroll
  for (int m = 0; m < 4; ++m) {
    const int ra = wr * 64 + m * 16 + l15;
    aoff[m] = ra * 32 + ((kg ^ ((ra + (ra >> 2)) & 3)) << 3);
    const int rb = wc * 64 + m * 16 + l15;
    boff[m] = rb * 32 + ((kg ^ ((rb + (rb >> 2)) & 3)) << 3);
  }

  f32x4 acc[4][4];
#pragma unroll
  for (int m = 0; m < 4; ++m)
#pragma unroll
    for (int n = 0; n < 4; ++n) acc[m][n] = (f32x4){0.f,0.f,0.f,0.f};

  const size_t aofs0 = (size_t)(bm + srow) * K + sc;
  const size_t bofs0 = (size_t)(bn + srow) * K + sc;
  const size_t half  = (size_t)64 * K;

  for (int kk = 0; kk < K; kk += 32) {
    __syncthreads();
#pragma unroll
    for (int l = 0; l < NL; ++l) {
      gload16(jobs.j[z].A[l] + aofs0 + kk,        &As[l][t * 8]);
      gload16(jobs.j[z].A[l] + aofs0 + half + kk, &As[l][2048 + t * 8]);
      gload16(jobs.j[z].B[l] + bofs0 + kk,        &Bs[l][t * 8]);
      gload16(jobs.j[z].B[l] + bofs0 + half + kk, &Bs[l][2048 + t * 8]);
    }
    __syncthreads();
    if (NL == 1) {
      bf16x8 a[4], b[4];
#pragma unroll
      for (int m = 0; m < 4; ++m) a[m] = *(const bf16x8*)&As[0][aoff[m]];
#pragma unroll
      for (int n = 0; n < 4; ++n) b[n] = *(const bf16x8*)&Bs[0][boff[n]];
#pragma unroll
      for (int m = 0; m < 4; ++m)
#pragma unroll
        for (int n = 0; n < 4; ++n)
          acc[m][n] = __builtin_amdgcn_mfma_f32_16x16x32_bf16(a[m], b[n], acc[m][n], 0, 0, 0);
    } else {
      bf16x8 a0[4], a1[4], a2[4], b[4];
#pragma unroll
      for (int m = 0; m < 4; ++m) {
        a0[m] = *(const bf16x8*)&As[0][aoff[m]];
        a1[m] = *(const bf16x8*)&As[1][aoff[m]];
        a2[m] = *(const bf16x8*)&As[2][aoff[m]];
      }
#pragma unroll
      for (int n = 0; n < 4; ++n) b[n] = *(const bf16x8*)&Bs[0][boff[n]];
#pragma unroll
      for (int m = 0; m < 4; ++m)
#pragma unroll
        for (int n = 0; n < 4; ++n) {
          acc[m][n] = __builtin_amdgcn_mfma_f32_16x16x32_bf16(a0[m], b[n], acc[m][n], 0, 0, 0);
          acc[m][n] = __builtin_amdgcn_mfma_f32_16x16x32_bf16(a1[m], b[n], acc[m][n], 0, 0, 0);
          acc[m][n] = __builtin_amdgcn_mfma_f32_16x16x32_bf16(a2[m], b[n], acc[m][n], 0, 0, 0);
        }
#pragma unroll
      for (int n = 0; n < 4; ++n) b[n] = *(const bf16x8*)&Bs[1][boff[n]];
#pragma unroll
      for (int m = 0; m < 4; ++m)
#pragma unroll
        for (int n = 0; n < 4; ++n) {
          acc[m][n] = __builtin_amdgcn_mfma_f32_16x16x32_bf16(a0[m], b[n], acc[m][n], 0, 0, 0);
          acc[m][n] = __builtin_amdgcn_mfma_f32_16x16x32_bf16(a1[m], b[n], acc[m][n], 0, 0, 0);
        }
#pragma unroll
      for (int n = 0; n < 4; ++n) b[n] = *(const bf16x8*)&Bs[2][boff[n]];
#pragma unroll
      for (int m = 0; m < 4; ++m)
#pragma unroll
        for (int n = 0; n < 4; ++n)
          acc[m][n] = __builtin_amdgcn_mfma_f32_16x16x32_bf16(a0[m], b[n], acc[m][n], 0, 0, 0);
    }
  }

  const float* bias = jobs.j[z].bias;
  float* C  = jobs.j[z].C;
  short* Ch = jobs.j[z].Ch;
  const int relu = jobs.j[z].relu;
  float bv[4];
#pragma unroll
  for (int n = 0; n < 4; ++n) bv[n] = bias[bn + wc*64 + n*16 + l15];
#pragma unroll
  for (int m = 0; m < 4; ++m) {
    const int row0 = bm + wr*64 + m*16 + kg*4;
#pragma unroll
    for (int n = 0; n < 4; ++n) {
      const int col = bn + wc*64 + n*16 + l15;
#pragma unroll
      for (int q = 0; q < 4; ++q) {
        float o = acc[m][n][q] + bv[n];
        if (relu) o = fmaxf(o, 0.f);
        const size_t off = (size_t)(row0 + q) * N + col;
        if (C)  C[off]  = o;
        if (Ch) Ch[off] = (short)bf16rne(o);
      }
    }
  }
}

// ---------------- sampled QK^T -> M scores (round-20 verified) ------------
__global__ __launch_bounds__(256, 2) void qks_m_kernel(
    const float* __restrict__ Q, const float* __restrict__ K,
    const int* __restrict__ idx, float* __restrict__ Mout)
{
  __shared__ int sidx[64 * U_];
  const int p = blockIdx.x;                       // 0..1023
  const int g  = (p & 7) + (((p >> 3) & 7) << 3); // bh group -> XCD g%8
  const int q16 = p >> 6;                         // 0..15
  const int l0 = q16 * 64;
  const int tid = threadIdx.x;
  for (int i = tid; i < 64 * U_; i += 256) sidx[i] = idx[l0 * U_ + i];
  __syncthreads();

  const int ll = tid >> 2, dq = tid & 3;          // dq = d-quarter (16 floats)
  const int l = l0 + ll;
  const int h = g & (H_ - 1), b = g >> 4;
  const size_t rowb = (size_t)(b * L_) * DM_ + h * DH_;
  const float* qrow = Q + rowb + (size_t)l * DM_ + dq * 4;
  float4 qv[4];
#pragma unroll
  for (int jj = 0; jj < 4; ++jj) qv[jj] = *(const float4*)(qrow + jj * 16);

  const int* ip = &sidx[ll * U_];
  float mx = -__builtin_inff();
  float sm = 0.f;
#pragma unroll 5
  for (int s = 0; s < U_; ++s) {
    const float* krow = K + rowb + (size_t)ip[s] * DM_ + dq * 4;
    const float4 k0 = *(const float4*)(krow);
    const float4 k1 = *(const float4*)(krow + 16);
    const float4 k2 = *(const float4*)(krow + 32);
    const float4 k3 = *(const float4*)(krow + 48);
    float a0 = 0.f, a1 = 0.f, a2 = 0.f, a3 = 0.f;
    a0 = fmaf(qv[0].x, k0.x, a0); a0 = fmaf(qv[0].y, k0.y, a0);
    a0 = fmaf(qv[0].z, k0.z, a0); a0 = fmaf(qv[0].w, k0.w, a0);
    a1 = fmaf(qv[1].x, k1.x, a1); a1 = fmaf(qv[1].y, k1.y, a1);
    a1 = fmaf(qv[1].z, k1.z, a1); a1 = fmaf(qv[1].w, k1.w, a1);
    a2 = fmaf(qv[2].x, k2.x, a2); a2 = fmaf(qv[2].y, k2.y, a2);
    a2 = fmaf(qv[2].z, k2.z, a2); a2 = fmaf(qv[2].w, k2.w, a2);
    a3 = fmaf(qv[3].x, k3.x, a3); a3 = fmaf(qv[3].y, k3.y, a3);
    a3 = fmaf(qv[3].z, k3.z, a3); a3 = fmaf(qv[3].w, k3.w, a3);
    float a = (a0 + a1) + (a2 + a3);
    a += __shfl_xor(a, 1, 64);
    a += __shfl_xor(a, 2, 64);
    mx = fmaxf(mx, a);
    sm += a;
  }
  if (dq == 0) Mout[g * L_ + l] = mx - sm * (1.0f / 1024.0f);
}

// ---------------- top-35 indices per (b,h) --------------------------------
__global__ __launch_bounds__(256) void topk_kernel(
    const float* __restrict__ M, int* __restrict__ Mtop)
{
  const int bh  = blockIdx.x;
  const int tid = threadIdx.x;
  __shared__ float vals[L_];
  __shared__ float rv[256];
  __shared__ int   ri[256];
  for (int i = tid; i < L_; i += 256) vals[i] = M[(size_t)bh * L_ + i];
  __syncthreads();
  for (int t = 0; t < U_; ++t) {
    float best = -__builtin_inff();
    int   bi   = L_;
    for (int i = tid; i < L_; i += 256) {
      const float v = vals[i];
      if (v > best) { best = v; bi = i; }
    }
    rv[tid] = best; ri[tid] = bi;
    __syncthreads();
    for (int s = 128; s > 0; s >>= 1) {
      if (tid < s) {
        if (rv[tid+s] > rv[tid] || (rv[tid+s] == rv[tid] && ri[tid+s] < ri[tid])) {
          rv[tid] = rv[tid+s]; ri[tid] = ri[tid+s];
        }
      }
      __syncthreads();
    }
    if (tid == 0) { Mtop[bh * U_ + t] = ri[0]; vals[ri[0]] = -__builtin_inff(); }
    __syncthreads();
  }
}

// ---------------- attention: 3-kernel k-split -----------------------------
// score (round-22): 4-lane-cooperative rows, same pattern as qks_m/attn_pv.
// Old form: thread k loaded its OWN K row -> each float4 instr = 64 scattered
// cache lines (TA-bound). New: lane dq of each 4-group owns d-quarter dq of
// the SAME row (contiguous 64B/group, 16 lines/instr). Per u: 16-FMA partial
// + 2 shuffles; pk[18] built with compile-time indices (rule #20), written by
// lane 0. Grid 64*KSC_ with XCD-affinity map (64 k-rows per block).
__global__ __launch_bounds__(256) void attn_score(
    const float* __restrict__ Q, const float* __restrict__ K,
    const int* __restrict__ Mtop, uint32_t* __restrict__ Pg, int masked)
{
  __shared__ float qs[U_ * DH_];
  __shared__ int   rowsL[U_ + 1];
  const int p = blockIdx.x;
  const int xcd = p & 7, idx2 = p >> 3;
  const int bh = xcd + ((idx2 & 7) << 3);
  const int ks = idx2 >> 3;                 // 0..KSC_-1
  const int h = bh & (H_ - 1), b = bh >> 4;
  const int tid = threadIdx.x;
  const size_t kvbase = (size_t)(b * L_) * DM_ + h * DH_;

  if (tid < U_) rowsL[tid] = Mtop[bh * U_ + tid];
  __syncthreads();
  for (int i = tid; i < U_ * DH_; i += 256)
    qs[i] = Q[kvbase + (size_t)rowsL[i >> 6] * DM_ + (i & 63)];
  __syncthreads();

  const int grp = tid >> 2, dq = tid & 3;
  const int k = ks * 64 + grp;
  const float* kp = K + kvbase + (size_t)k * DM_ + dq * 16;
  const float4 kv0 = *(const float4*)(kp);
  const float4 kv1 = *(const float4*)(kp + 4);
  const float4 kv2 = *(const float4*)(kp + 8);
  const float4 kv3 = *(const float4*)(kp + 12);

#define DOT_EXP_U(uu, out)                                                  \
  {                                                                         \
    const float4* qp = (const float4*)&qs[(uu) * 64 + dq * 16];             \
    const float4 q0 = qp[0], q1 = qp[1], q2 = qp[2], q3 = qp[3];            \
    float x0 = 0.f, x1 = 0.f;                                               \
    x0 = fmaf(q0.x, kv0.x, x0); x0 = fmaf(q0.y, kv0.y, x0);                 \
    x0 = fmaf(q0.z, kv0.z, x0); x0 = fmaf(q0.w, kv0.w, x0);                 \
    x1 = fmaf(q1.x, kv1.x, x1); x1 = fmaf(q1.y, kv1.y, x1);                 \
    x1 = fmaf(q1.z, kv1.z, x1); x1 = fmaf(q1.w, kv1.w, x1);                 \
    x0 = fmaf(q2.x, kv2.x, x0); x0 = fmaf(q2.y, kv2.y, x0);                 \
    x0 = fmaf(q2.z, kv2.z, x0); x0 = fmaf(q2.w, kv2.w, x0);                 \
    x1 = fmaf(q3.x, kv3.x, x1); x1 = fmaf(q3.y, kv3.y, x1);                 \
    x1 = fmaf(q3.z, kv3.z, x1); x1 = fmaf(q3.w, kv3.w, x1);                 \
    float a = x0 + x1;                                                      \
    a += __shfl_xor(a, 1, 64);                                              \
    a += __shfl_xor(a, 2, 64);                                              \
    float v = a * 0.125f;                                                   \
    if (masked && k > rowsL[(uu)]) v = -__builtin_inff();                   \
    out = expf(v);                                                          \
  }

  uint32_t pk[18];
#pragma unroll
  for (int j = 0; j < 17; ++j) {
    float e0, e1;
    DOT_EXP_U(2 * j, e0);
    DOT_EXP_U(2 * j + 1, e1);
    pk[j] = bf16rne(e0) | (bf16rne(e1) << 16);
  }
  {
    float e;
    DOT_EXP_U(34, e);
    pk[17] = bf16rne(e);
  }
#undef DOT_EXP_U

  if (dq == 0) {
    uint32_t* prow = Pg + (size_t)bh * (L_ * 18) + (size_t)k * 18;
#pragma unroll
    for (int j = 0; j < 18; ++j) prow[j] = pk[j];
  }
}

// pv (round-21 verified): grid 64*KSP_, XCD-affinity, 64 k per block.
__global__ __launch_bounds__(256) void attn_pv(
    const float* __restrict__ V, const uint32_t* __restrict__ Pg,
    float* __restrict__ Opart, float* __restrict__ Dpart)
{
  __shared__ uint32_t Pl[64 * 18];
  const int p = blockIdx.x;
  const int xcd = p & 7, idx2 = p >> 3;
  const int bh = xcd + ((idx2 & 7) << 3);
  const int ks = idx2 >> 3;
  const int h = bh & (H_ - 1), b = bh >> 4;
  const int tid = threadIdx.x, lane = tid & 63, wid = tid >> 6;
  const size_t kvbase = (size_t)(b * L_) * DM_ + h * DH_;

  const uint32_t* ps = Pg + (size_t)bh * (L_ * 18) + (size_t)(ks * 64) * 18;
  for (int i = tid; i < 64 * 18; i += 256) Pl[i] = ps[i];
  __syncthreads();

  float acc[9], dd[9];
#pragma unroll
  for (int j = 0; j < 9; ++j) { acc[j] = 0.f; dd[j] = 0.f; }

  const float* vp = V + kvbase + (size_t)(ks * 64) * DM_ + lane;
  const int widh = wid >> 1;
  const int hi   = wid & 1;
#pragma unroll 8
  for (int kk = 0; kk < 64; ++kk) {
    const float v0 = vp[(size_t)kk * DM_];
    const uint32_t* pr = &Pl[kk * 18];
#pragma unroll
    for (int j = 0; j < 9; ++j) {
      if (wid + 4 * j < U_) {
        const uint32_t w = pr[widh + 2 * j];
        const float p2 = hi ? bitsf32(w & 0xFFFF0000u) : bitsf32(w << 16);
        acc[j] = fmaf(p2, v0, acc[j]);
        dd[j] += p2;
      }
    }
  }
  const int pb = (ks * 64 + bh) * U_;
#pragma unroll
  for (int j = 0; j < 9; ++j) {
    const int u = wid + 4 * j;
    if (u < U_) {
      Opart[(size_t)(pb + u) * 64 + lane] = acc[j];
      if (lane == 0) Dpart[pb + u] = dd[j];
    }
  }
}

__global__ void attn_reduce(const float* __restrict__ Opart,
                            const float* __restrict__ Dpart,
                            float* __restrict__ ctx_rows)
{
  const int bhu = blockIdx.x;
  const int bh = bhu / U_, u = bhu % U_;
  const int lane = threadIdx.x;
  float o = 0.f, dd = 0.f;
#pragma unroll
  for (int ks = 0; ks < KSP_; ++ks) {
    o  += Opart[(size_t)((ks * 64 + bh) * U_ + u) * 64 + lane];
    dd += Dpart[(ks * 64 + bh) * U_ + u];
  }
  ctx_rows[(size_t)bhu * 64 + lane] = o / dd;
}

// ---------------- cumsum / vmean / fill / scatter -------------------------
__global__ __launch_bounds__(256) void cumsum_kernel(
    const float* __restrict__ V, float* __restrict__ C)
{
  const int bh = blockIdx.x;
  const int h = bh & (H_ - 1), b = bh >> 4;
  const int d = threadIdx.x & 63, qq = threadIdx.x >> 6;
  __shared__ float chs[4][DH_];
  const size_t base = (size_t)b * L_ * DM_ + h * DH_ + d;
  float acc = 0.f;
  const int l0 = qq * 256;
  for (int l = l0; l < l0 + 256; ++l) acc += V[base + (size_t)l * DM_];
  chs[qq][d] = acc;
  __syncthreads();
  float off = 0.f;
  for (int j = 0; j < qq; ++j) off += chs[j][d];
  acc = off;
  for (int l = l0; l < l0 + 256; ++l) {
    acc += V[base + (size_t)l * DM_];
    C[base + (size_t)l * DM_] = acc;
  }
}

__global__ __launch_bounds__(256) void vmean_kernel(
    const float* __restrict__ V, float* __restrict__ vm)
{
  const int bh = blockIdx.x;
  const int h = bh & (H_ - 1), b = bh >> 4;
  const int d = threadIdx.x & 63, qq = threadIdx.x >> 6;
  __shared__ float chs[4][DH_];
  const size_t base = (size_t)b * L_ * DM_ + h * DH_ + d;
  float acc = 0.f;
  for (int l = qq * 256; l < qq * 256 + 256; ++l) acc += V[base + (size_t)l * DM_];
  chs[qq][d] = acc;
  __syncthreads();
  if (qq == 0)
    vm[bh * DH_ + d] = (chs[0][d] + chs[1][d] + chs[2][d] + chs[3][d]) * (1.0f / 1024.0f);
}

__global__ void fill_kernel(const float* __restrict__ vm, float* __restrict__ C)
{
  const size_t i = (size_t)blockIdx.x * 256 + threadIdx.x;
  const int d = (int)(i & 63);
  const int h = (int)((i >> 6) & (H_ - 1));
  const int b = (int)(i >> 20);
  C[i] = vm[(b * H_ + h) * DH_ + d];
}

__global__ void scatter_kernel(const float* __restrict__ ctx_rows,
                               const int* __restrict__ Mtop, float* __restrict__ C)
{
  const int bhu = blockIdx.x;
  const int u  = bhu % U_;
  const int bh = bhu / U_;
  const int h = bh & (H_ - 1), b = bh >> 4;
  const int row = Mtop[bh * U_ + u];
  C[(size_t)(b * L_ + row) * DM_ + h * DH_ + threadIdx.x] =
      ctx_rows[(size_t)bhu * DH_ + threadIdx.x];
}

// ---------------- LayerNorm(xa + xb), optional limb outputs ---------------
__global__ __launch_bounds__(256) void ln_kernel(
    const float* __restrict__ xa, const float* __restrict__ xb,
    const float* __restrict__ g, const float* __restrict__ bt,
    float* __restrict__ out, short* __restrict__ oh,
    short* __restrict__ om, short* __restrict__ ol)
{
  const int row = blockIdx.x;
  const int tid = threadIdx.x;
  __shared__ float v[DM_];
  __shared__ float red[256];
  float s = 0.f;
  for (int i = tid; i < DM_; i += 256) {
    const float t = xa[(size_t)row * DM_ + i] + xb[(size_t)row * DM_ + i];
    v[i] = t; s += t;
  }
  red[tid] = s; __syncthreads();
  for (int st = 128; st > 0; st >>= 1) { if (tid < st) red[tid] += red[tid+st]; __syncthreads(); }
  const float mean = red[0] * (1.0f / DM_);
  __syncthreads();
  float s2 = 0.f;
  for (int i = tid; i < DM_; i += 256) { const float dd = v[i] - mean; s2 += dd * dd; }
  red[tid] = s2; __syncthreads();
  for (int st = 128; st > 0; st >>= 1) { if (tid < st) red[tid] += red[tid+st]; __syncthreads(); }
  const float rstd = rsqrtf(red[0] * (1.0f / DM_) + 1e-5f);
  __syncthreads();
  for (int i = tid; i < DM_; i += 256) {
    const size_t idx = (size_t)row * DM_ + i;
    const float o = (v[i] - mean) * rstd * g[i] + bt[i];
    out[idx] = o;
    if (oh) {
      const uint32_t h = bf16rne(o);
      oh[idx] = (short)h;
      if (om) {
        const float r = o - bf16tof(h);
        const uint32_t m = bf16rne(r);
        om[idx] = (short)m;
        ol[idx] = (short)bf16rne(r - bf16tof(m));
      }
    }
  }
}

// ---------------- host orchestration --------------------------------------
extern "C" void kernel_launch(void* const* d_in, const int* in_sizes, int n_in,
                              void* d_out, int out_size, void* d_ws, size_t ws_size,
                              hipStream_t stream)
{
  (void)in_sizes; (void)n_in; (void)out_size; (void)ws_size;
  const float* x    = (const float*)d_in[0];
  const float* enc  = (const float*)d_in[1];
  const float* saWq = (const float*)d_in[2];  const float* sabq = (const float*)d_in[3];
  const float* saWk = (const float*)d_in[4];  const float* sabk = (const float*)d_in[5];
  const float* saWv = (const float*)d_in[6];  const float* sabv = (const float*)d_in[7];
  const float* saWo = (const float*)d_in[8];  const float* sabo = (const float*)d_in[9];
  const float* caWq = (const float*)d_in[10]; const float* cabq = (const float*)d_in[11];
  const float* caWk = (const float*)d_in[12]; const float* cabk = (const float*)d_in[13];
  const float* caWv = (const float*)d_in[14]; const float* cabv = (const float*)d_in[15];
  const float* caWo = (const float*)d_in[16]; const float* cabo = (const float*)d_in[17];
  const float* fW1  = (const float*)d_in[18]; const float* fb1  = (const float*)d_in[19];
  const float* fW2  = (const float*)d_in[20]; const float* fb2  = (const float*)d_in[21];
  const float* l1g  = (const float*)d_in[22]; const float* l1b  = (const float*)d_in[23];
  const float* l2g  = (const float*)d_in[24]; const float* l2b  = (const float*)d_in[25];
  const float* l3g  = (const float*)d_in[26]; const float* l3b  = (const float*)d_in[27];

  float* ws = (float*)d_ws;
  const size_t SL = (size_t)MROWS_ * DM_;       // 4M floats
  float* bufQ = ws;
  float* bufK = ws + SL;
  float* bufV = ws + 2 * SL;
  float* bufC = ws + 3 * SL;
  float* xcur = ws + 4 * SL;
  float* tmp  = ws + 5 * SL;
  float* smallp = ws + 6 * SL;
  int*   idxb = (int*)smallp;
  float* Mbuf = smallp + 36864;
  int*   Mtop = (int*)(smallp + 36864 + 65536);
  float* ctxr = smallp + 36864 + 65536 + 2304;
  float* vm   = ctxr + 143360;

  // attention scratch overlaid on bufC (dead until cumsum/fill):
  uint32_t* Pg    = (uint32_t*)bufC;                     // 64*1024*18 u32
  float*    Opart = bufC + 1179648;                      // KSP_*64*35*64 f32
  float*    Dpart = Opart + (size_t)KSP_ * 64 * U_ * 64; // KSP_*64*35 f32

  const size_t M1 = 1024u * 1024u;
  short* wreg = (short*)(ws + 6 * SL + 262144);
  short* areg = wreg + 8 * M1;
  short* Wqh = wreg;          short* Wqm = wreg + 1*M1; short* Wql = wreg + 2*M1;
  short* Wkh = wreg + 3*M1;   short* Wkm = wreg + 4*M1; short* Wkl = wreg + 5*M1;
  short* Wvh = wreg + 6*M1;   short* Woh = wreg + 7*M1;
  short* f1h = wreg;          short* f2h = wreg + 4*M1;
  short* xh = areg;           short* xm = areg + 4*M1;  short* xl = areg + 8*M1;
  short* eh = areg + 12*M1;   short* em = areg + 16*M1; short* el = areg + 20*M1;
  short* bCh = areg + 12*M1;
  short* hidh = (short*)bufQ;

  // --- JAX partitionable-threefry key ladder (verified round 3) ---
  uint32_t k1a, k1b, k2a, k2b;
  tf2x32(0u, 42u, 0u, 0u, k1a, k1b);
  tf2x32(0u, 42u, 0u, 1u, k2a, k2b);
  uint32_t kb1a, kb1b, kb2a, kb2b;
  tf2x32(k1a, k1b, 0u, 1u, kb1a, kb1b);
  tf2x32(k2a, k2b, 0u, 1u, kb2a, kb2b);

  const dim3 thr(256);
  const int gIdx = (IDXN_ + 255) / 256;
  const int n8 = (int)(SL / 8);
  const dim3 gT(16, 16);

  // ============ self attention (masked) ============
  tsplit_kernel<3><<<gT, thr, 0, stream>>>(saWq, Wqh, Wqm, Wql, DM_, DM_);
  tsplit_kernel<3><<<gT, thr, 0, stream>>>(saWk, Wkh, Wkm, Wkl, DM_, DM_);
  tsplit_kernel<1><<<gT, thr, 0, stream>>>(saWv, Wvh, nullptr, nullptr, DM_, DM_);
  tsplit_kernel<1><<<gT, thr, 0, stream>>>(saWo, Woh, nullptr, nullptr, DM_, DM_);
  rsplit_kernel<3><<<n8 / 256, thr, 0, stream>>>(x, xh, xm, xl, n8);
  {
    FJobs J = {};
    J.j[0] = { {xh, xm, xl}, {Wqh, Wqm, Wql}, sabq, bufQ, nullptr, 0 };
    J.j[1] = { {xh, xm, xl}, {Wkh, Wkm, Wkl}, sabk, bufK, nullptr, 0 };
    gemm_fused<3><<<dim3(8, 32, 2), thr, 0, stream>>>(J, DM_, DM_);
  }
  {
    FJobs J = {};
    J.j[0] = { {xh, nullptr, nullptr}, {Wvh, nullptr, nullptr}, sabv, bufV, nullptr, 0 };
    gemm_fused<1><<<dim3(8, 32, 1), thr, 0, stream>>>(J, DM_, DM_);
  }
  idx_kernel<<<gIdx, thr, 0, stream>>>(kb1a, kb1b, idxb);
  qks_m_kernel<<<1024, thr, 0, stream>>>(bufQ, bufK, idxb, Mbuf);
  topk_kernel<<<B_ * H_, thr, 0, stream>>>(Mbuf, Mtop);
  attn_score<<<B_ * H_ * KSC_, thr, 0, stream>>>(bufQ, bufK, Mtop, Pg, 1);
  attn_pv<<<B_ * H_ * KSP_, thr, 0, stream>>>(bufV, Pg, Opart, Dpart);
  attn_reduce<<<B_ * H_ * U_, dim3(64), 0, stream>>>(Opart, Dpart, ctxr);
  cumsum_kernel<<<B_ * H_, thr, 0, stream>>>(bufV, bufC);
  scatter_kernel<<<B_ * H_ * U_, dim3(64), 0, stream>>>(ctxr, Mtop, bufC);
  rsplit_kernel<1><<<n8 / 256, thr, 0, stream>>>(bufC, bCh, nullptr, nullptr, n8);
  {
    FJobs J = {};
    J.j[0] = { {bCh, nullptr, nullptr}, {Woh, nullptr, nullptr}, sabo, tmp, nullptr, 0 };
    gemm_fused<1><<<dim3(8, 32, 1), thr, 0, stream>>>(J, DM_, DM_);
  }
  ln_kernel<<<MROWS_, thr, 0, stream>>>(x, tmp, l1g, l1b, xcur, xh, xm, xl);

  // ============ cross attention (unmasked) ============
  tsplit_kernel<3><<<gT, thr, 0, stream>>>(caWq, Wqh, Wqm, Wql, DM_, DM_);
  tsplit_kernel<3><<<gT, thr, 0, stream>>>(caWk, Wkh, Wkm, Wkl, DM_, DM_);
  tsplit_kernel<1><<<gT, thr, 0, stream>>>(caWv, Wvh, nullptr, nullptr, DM_, DM_);
  tsplit_kernel<1><<<gT, thr, 0, stream>>>(caWo, Woh, nullptr, nullptr, DM_, DM_);
  rsplit_kernel<3><<<n8 / 256, thr, 0, stream>>>(enc, eh, em, el, n8);
  {
    FJobs J = {};
    J.j[0] = { {xh, xm, xl}, {Wqh, Wqm, Wql}, cabq, bufQ, nullptr, 0 };
    J.j[1] = { {eh, em, el}, {Wkh, Wkm, Wkl}, cabk, bufK, nullptr, 0 };
    gemm_fused<3><<<dim3(8, 32, 2), thr, 0, stream>>>(J, DM_, DM_);
  }
  {
    FJobs J = {};
    J.j[0] = { {eh, nullptr, nullptr}, {Wvh, nullptr, nullptr}, cabv, bufV, nullptr, 0 };
    gemm_fused<1><<<dim3(8, 32, 1), thr, 0, stream>>>(J, DM_, DM_);
  }
  idx_kernel<<<gIdx, thr, 0, stream>>>(kb2a, kb2b, idxb);
  qks_m_kernel<<<1024, thr, 0, stream>>>(bufQ, bufK, idxb, Mbuf);
  topk_kernel<<<B_ * H_, thr, 0, stream>>>(Mbuf, Mtop);
  attn_score<<<B_ * H_ * KSC_, thr, 0, stream>>>(bufQ, bufK, Mtop, Pg, 0);
  attn_pv<<<B_ * H_ * KSP_, thr, 0, stream>>>(bufV, Pg, Opart, Dpart);
  attn_reduce<<<B_ * H_ * U_, dim3(64), 0, stream>>>(Opart, Dpart, ctxr);
  vmean_kernel<<<B_ * H_, thr, 0, stream>>>(bufV, vm);
  fill_kernel<<<(int)(SL / 256), thr, 0, stream>>>(vm, bufC);
  scatter_kernel<<<B_ * H_ * U_, dim3(64), 0, stream>>>(ctxr, Mtop, bufC);
  rsplit_kernel<1><<<n8 / 256, thr, 0, stream>>>(bufC, bCh, nullptr, nullptr, n8);
  {
    FJobs J = {};
    J.j[0] = { {bCh, nullptr, nullptr}, {Woh, nullptr, nullptr}, cabo, tmp, nullptr, 0 };
    gemm_fused<1><<<dim3(8, 32, 1), thr, 0, stream>>>(J, DM_, DM_);
  }
  ln_kernel<<<MROWS_, thr, 0, stream>>>(xcur, tmp, l2g, l2b, xcur, xh, nullptr, nullptr);

  // ============ FFN ============
  tsplit_kernel<1><<<dim3(64, 16), thr, 0, stream>>>(fW1, f1h, nullptr, nullptr, DM_, FF_);
  tsplit_kernel<1><<<dim3(16, 64), thr, 0, stream>>>(fW2, f2h, nullptr, nullptr, FF_, DM_);
  {
    FJobs J = {};
    J.j[0] = { {xh, nullptr, nullptr}, {f1h, nullptr, nullptr}, fb1, nullptr, hidh, 1 };
    gemm_fused<1><<<dim3(32, 32, 1), thr, 0, stream>>>(J, DM_, FF_);
  }
  {
    FJobs J = {};
    J.j[0] = { {hidh, nullptr, nullptr}, {f2h, nullptr, nullptr}, fb2, tmp, nullptr, 0 };
    gemm_fused<1><<<dim3(8, 32, 1), thr, 0, stream>>>(J, FF_, DM_);
  }
  ln_kernel<<<MROWS_, thr, 0, stream>>>(xcur, tmp, l3g, l3b, (float*)d_out,
                                        nullptr, nullptr, nullptr);
}